// Round 1
// baseline (466.807 us; speedup 1.0000x reference)
//
#include <hip/hip_runtime.h>
#include <math.h>

#define BB 64
#define TT 512
#define OBSD 115
#define DMD 128
#define DSD 8
#define NLD 3
#define EMBD 16
#define NAD 19
#define H1D 256
#define NTOK (BB*TT)
#define SSEG 32
#define TSEG (TT/SSEG)   // 16

typedef unsigned short ushort_t;
typedef __attribute__((ext_vector_type(8))) short short8;
typedef __attribute__((ext_vector_type(4))) float f32x4;

__device__ __forceinline__ float silu_f(float x){ return x / (1.f + __expf(-x)); }
__device__ __forceinline__ float softplus_f(float x){
  return fmaxf(x, 0.f) + log1pf(__expf(-fabsf(x)));
}
__device__ __forceinline__ ushort_t f2bf(float x){
  unsigned u = __float_as_uint(x);
  unsigned r = (u + 0x7fffu + ((u >> 16) & 1u)) >> 16;
  return (ushort_t)r;
}
__device__ __forceinline__ float b2f(ushort_t x){
  return __uint_as_float(((unsigned)x) << 16);
}
#define MFMA(a,b,c) __builtin_amdgcn_mfma_f32_16x16x32_bf16((a),(b),(c),0,0,0)
#define LOG2E 1.44269504f

// LN stats over 32 tokens, D cols, stride SV floats (SV%32==8 -> conflict-free).
template<int D, int SV>
__device__ __forceinline__ void ln32(const float* s_val, float* s_mr, int tid){
  const int t = tid >> 3, part = tid & 7;
  float s = 0.f, s2 = 0.f;
  #pragma unroll
  for (int j = part; j < D; j += 8){ float v = s_val[t*SV + j]; s += v; s2 = fmaf(v, v, s2); }
  s += __shfl_xor(s, 1, 64); s2 += __shfl_xor(s2, 1, 64);
  s += __shfl_xor(s, 2, 64); s2 += __shfl_xor(s2, 2, 64);
  s += __shfl_xor(s, 4, 64); s2 += __shfl_xor(s2, 4, 64);
  if (part == 0){
    float m = s * (1.f/(float)D);
    s_mr[t*2] = m;
    s_mr[t*2+1] = rsqrtf(s2 * (1.f/(float)D) - m*m + 1e-5f);
  }
}

// ---------------- k_prep ----------------
struct PJob { const float* src; ushort_t* dst; int N; int K; int Kpad; int rowofs; int Nw; };
struct PJobs { PJob j[20]; };

__global__ __launch_bounds__(256) void k_prep(PJobs P){
  const int job = blockIdx.x >> 2;
  const int sub = blockIdx.x & 3;
  PJob pj = P.j[job];
  const int elems = pj.Nw * pj.Kpad;
  for (int idx = sub*256 + threadIdx.x; idx < elems; idx += 4*256){
    int n = idx / pj.Kpad;
    int k = idx - n*pj.Kpad;
    float v = (n < pj.N && k < pj.K) ? pj.src[(size_t)n*pj.K + k] : 0.f;
    pj.dst[(size_t)(pj.rowofs + n)*pj.Kpad + k] = f2bf(v);
  }
}

// ---------------- k_enc1: e1(bf16) = silu(LN(obs @ w1.T + b1)) ----------------
__global__ __launch_bounds__(256) void k_enc1(
    const float* __restrict__ obs, const ushort_t* __restrict__ w1b,
    const float* __restrict__ b1, const float* __restrict__ g1,
    const float* __restrict__ bb1, ushort_t* __restrict__ e1)
{
  __shared__ __align__(16) char sm[34048];
  float*    s_val = (float*)sm;          // 32x264 f32
  ushort_t* s_a   = (ushort_t*)sm;       // 32x136 bf16 (aliases; dead after af load)
  float*    s_mr  = (float*)(sm + 33792);
  const int tok0 = blockIdx.x * 32;
  const int tid = threadIdx.x;
  const int lane = tid & 63, w = tid >> 6;
  const int q = lane >> 4, cn = lane & 15;
  const int m0 = (w & 1) * 16, nh = w >> 1;

  for (int e = tid; e < 32*16; e += 256){
    int t = e >> 4, kc = e & 15;
    const float* op = obs + (size_t)(tok0 + t)*OBSD;
    short8 v;
    #pragma unroll
    for (int j = 0; j < 8; j++){
      int k = kc*8 + j;
      v[j] = (short)f2bf(k < OBSD ? op[k] : 0.f);
    }
    *(short8*)&s_a[t*136 + kc*8] = v;
  }
  __syncthreads();

  short8 af[4];
  #pragma unroll
  for (int ks = 0; ks < 4; ks++)
    af[ks] = *(const short8*)&s_a[(m0 + cn)*136 + ks*32 + q*8];
  __syncthreads();

  #pragma unroll
  for (int nt = 0; nt < 8; nt++){
    const int n0 = (nh*8 + nt) * 16;
    f32x4 acc = {0.f,0.f,0.f,0.f};
    #pragma unroll
    for (int ks = 0; ks < 4; ks++){
      short8 bf = *(const short8*)&w1b[(size_t)(n0 + cn)*128 + ks*32 + q*8];
      acc = MFMA(af[ks], bf, acc);
    }
    float bias = b1[n0 + cn];
    #pragma unroll
    for (int r = 0; r < 4; r++)
      s_val[(m0 + q*4 + r)*264 + n0 + cn] = acc[r] + bias;
  }
  __syncthreads();

  ln32<256,264>(s_val, s_mr, tid);
  __syncthreads();
  for (int e = tid; e < 32*256; e += 256){
    int t = e >> 8, c = e & 255;
    float v = (s_val[t*264 + c] - s_mr[t*2]) * s_mr[t*2+1] * g1[c] + bb1[c];
    e1[(size_t)(tok0 + t)*256 + c] = f2bf(silu_f(v));
  }
}

// ------- k_enc2p: enc2+proj+LN(l0)+wig/wdbc(l0)+phaseA(l0) — 32 tok (=2 segments) -------
__global__ __launch_bounds__(256) void k_enc2p(
    const ushort_t* __restrict__ e1, const ushort_t* __restrict__ w2b,
    const float* __restrict__ b2, const float* __restrict__ g2,
    const float* __restrict__ bb2,
    const float* __restrict__ emb, const int* __restrict__ pact,
    const ushort_t* __restrict__ pwb, const float* __restrict__ pb,
    const float* __restrict__ pg, const float* __restrict__ pbb,
    float* __restrict__ X,
    const float* __restrict__ lng, const float* __restrict__ lnb,
    const ushort_t* __restrict__ wigb, const ushort_t* __restrict__ wdbcb,
    const float* __restrict__ bdt,
    ushort_t* __restrict__ XINb, ushort_t* __restrict__ Zb,
    ushort_t* __restrict__ DTb, ushort_t* __restrict__ BTu, ushort_t* __restrict__ CTu,
    const float* __restrict__ alog0,
    float* __restrict__ HLOC, float* __restrict__ PPR)
{
  __shared__ __align__(16) char sm[28928];
  float*    s_val = (float*)sm;                 // 32x136 f32
  ushort_t* s_xin = (ushort_t*)sm;              // aliases s_val after dead
  ushort_t* s_dt  = (ushort_t*)(sm + 8704);     // aliases s_val tail
  ushort_t* s_a   = (ushort_t*)(sm + 17408);    // 32x168 bf16
  ushort_t* s_btc = (ushort_t*)(sm + 28160);    // 32x8
  float*    s_mr  = (float*)(sm + 28672);

  const int tok0 = blockIdx.x * 32;
  const int bidx = blockIdx.x >> 4;
  const int ch   = blockIdx.x & 15;
  const int tid = threadIdx.x;
  const int lane = tid & 63, w = tid >> 6;
  const int q = lane >> 4, cn = lane & 15;
  const int m0 = (w & 1) * 16, nh = w >> 1;

  for (int e = tid; e < 32*32; e += 256){
    int t = e >> 5, k = e & 31;
    float v = 0.f;
    if (k < EMBD){ int a = pact[tok0 + t]; v = emb[(size_t)a*EMBD + k]; }
    s_a[t*168 + 128 + k] = f2bf(v);
  }
  {
    short8 af[8];
    #pragma unroll
    for (int ks = 0; ks < 8; ks++)
      af[ks] = *(const short8*)&e1[(size_t)(tok0 + m0 + cn)*256 + ks*32 + q*8];
    #pragma unroll
    for (int nt = 0; nt < 4; nt++){
      const int n0 = (nh*4 + nt) * 16;
      f32x4 acc = {0.f,0.f,0.f,0.f};
      #pragma unroll
      for (int ks = 0; ks < 8; ks++){
        short8 bf = *(const short8*)&w2b[(size_t)(n0 + cn)*256 + ks*32 + q*8];
        acc = MFMA(af[ks], bf, acc);
      }
      float bias = b2[n0 + cn];
      #pragma unroll
      for (int r = 0; r < 4; r++)
        s_val[(m0 + q*4 + r)*136 + n0 + cn] = acc[r] + bias;
    }
  }
  __syncthreads();

  ln32<128,136>(s_val, s_mr, tid);
  __syncthreads();
  for (int e = tid; e < 32*128; e += 256){
    int t = e >> 7, c = e & 127;
    float v = (s_val[t*136 + c] - s_mr[t*2]) * s_mr[t*2+1] * g2[c] + bb2[c];
    s_a[t*168 + c] = f2bf(v);
  }
  __syncthreads();

  {
    short8 af2[5];
    #pragma unroll
    for (int ks = 0; ks < 5; ks++)
      af2[ks] = *(const short8*)&s_a[(m0 + cn)*168 + ks*32 + q*8];
    #pragma unroll
    for (int nt = 0; nt < 4; nt++){
      const int n0 = (nh*4 + nt) * 16;
      f32x4 acc = {0.f,0.f,0.f,0.f};
      #pragma unroll
      for (int ks = 0; ks < 5; ks++){
        short8 bf = *(const short8*)&pwb[(size_t)(n0 + cn)*160 + ks*32 + q*8];
        acc = MFMA(af2[ks], bf, acc);
      }
      float bias = pb[n0 + cn];
      #pragma unroll
      for (int r = 0; r < 4; r++)
        s_val[(m0 + q*4 + r)*136 + n0 + cn] = acc[r] + bias;
    }
  }
  __syncthreads();

  ln32<128,136>(s_val, s_mr, tid);
  __syncthreads();
  for (int e = tid; e < 32*128; e += 256){
    int t = e >> 7, c = e & 127;
    float v = (s_val[t*136 + c] - s_mr[t*2]) * s_mr[t*2+1] * pg[c] + pbb[c];
    v = silu_f(v);
    X[(size_t)tok0*128 + e] = v;
    s_val[t*136 + c] = v;
  }
  __syncthreads();

  ln32<128,136>(s_val, s_mr, tid);
  __syncthreads();
  for (int e = tid; e < 32*128; e += 256){
    int t = e >> 7, c = e & 127;
    float v = (s_val[t*136 + c] - s_mr[t*2]) * s_mr[t*2+1] * lng[c] + lnb[c];
    s_a[t*168 + c] = f2bf(v);
  }
  __syncthreads();   // s_val DEAD; s_xin/s_dt may be written

  // wig GEMM
  {
    short8 af[4];
    #pragma unroll
    for (int ks = 0; ks < 4; ks++)
      af[ks] = *(const short8*)&s_a[(m0 + cn)*168 + ks*32 + q*8];
    #pragma unroll
    for (int nt = 0; nt < 8; nt++){
      const int n0 = (nh*8 + nt) * 16;
      f32x4 acc = {0.f,0.f,0.f,0.f};
      #pragma unroll
      for (int ks = 0; ks < 4; ks++){
        short8 bf = *(const short8*)&wigb[(size_t)(n0 + cn)*128 + ks*32 + q*8];
        acc = MFMA(af[ks], bf, acc);
      }
      if (n0 < 128){
        #pragma unroll
        for (int r = 0; r < 4; r++){
          int tr = m0 + q*4 + r;
          ushort_t bb = f2bf(acc[r]);
          XINb[(size_t)(tok0 + tr)*128 + n0 + cn] = bb;
          s_xin[tr*136 + n0 + cn] = bb;
        }
      } else {
        #pragma unroll
        for (int r = 0; r < 4; r++){
          int tr = m0 + q*4 + r;
          Zb[(size_t)(tok0 + tr)*128 + (n0 - 128) + cn] = f2bf(acc[r]);
        }
      }
    }
  }
  __syncthreads();

  // wdbc GEMM (also fills s_dt / s_btc for phase A)
  {
    short8 af2[4];
    #pragma unroll
    for (int ks = 0; ks < 4; ks++)
      af2[ks] = *(const short8*)&s_xin[(m0 + cn)*136 + ks*32 + q*8];
    for (int nt = nh; nt < 9; nt += 2){
      const int n0 = nt * 16;
      f32x4 acc = {0.f,0.f,0.f,0.f};
      #pragma unroll
      for (int ks = 0; ks < 4; ks++){
        short8 bf = *(const short8*)&wdbcb[(size_t)(n0 + cn)*128 + ks*32 + q*8];
        acc = MFMA(af2[ks], bf, acc);
      }
      const int col = n0 + cn;
      if (col < 128){
        float bd = bdt[col];
        #pragma unroll
        for (int r = 0; r < 4; r++){
          int tr = m0 + q*4 + r;
          ushort_t dv = f2bf(softplus_f(acc[r] + bd));
          DTb[(size_t)(tok0 + tr)*128 + col] = dv;
          s_dt[tr*136 + col] = dv;
        }
      } else if (col < 136){
        #pragma unroll
        for (int r = 0; r < 4; r++){
          int tr = m0 + q*4 + r;
          ushort_t bb = f2bf(acc[r]);
          BTu[(size_t)(tok0 + tr)*8 + (col - 128)] = bb;
          s_btc[tr*8 + (col - 128)] = bb;
        }
      } else {
        #pragma unroll
        for (int r = 0; r < 4; r++)
          CTu[(size_t)(tok0 + m0 + q*4 + r)*8 + (col - 136)] = f2bf(acc[r]);
      }
    }
  }
  __syncthreads();

  // phase A (layer 0): two 16-token segments per block, thread=(d, half)
  {
    const int d = tid & 127, half = tid >> 7;
    float A2c[8], hh[8], pp[8];
    #pragma unroll
    for (int s = 0; s < 8; s++){
      A2c[s] = -__expf(alog0[d*8 + s]) * LOG2E;
      hh[s] = 0.f; pp[s] = 1.f;
    }
    const int t0 = half * 16;
    #pragma unroll 4
    for (int tt = 0; tt < 16; tt++){
      const int t = t0 + tt;
      float dt = b2f(s_dt[t*136 + d]);
      float wv = dt * b2f(s_xin[t*136 + d]);
      #pragma unroll
      for (int s = 0; s < 8; s++){
        float dA = exp2f(dt * A2c[s]);
        hh[s] = fmaf(dA, hh[s], wv * b2f(s_btc[t*8 + s]));
        pp[s] *= dA;
      }
    }
    const size_t o = ((size_t)bidx*SSEG + ch*2 + half)*1024 + d*8;
    #pragma unroll
    for (int s = 0; s < 8; s++){ HLOC[o+s] = hh[s]; PPR[o+s] = pp[s]; }
  }
}

// LDS layout per segment-slice (bytes), TSEG=16 tokens:
//  0     : s_dtS (4096) ; 4096: s_xiS (4096)      [staging; dead after z-apply]
//  0     : s_x f32 16x130 (8320) [aliases staging] ; s_xin 16x136 bf16 aliases s_x
//  8320  : s_a bf16 16x136 (4352)
//  12672 : s_bt (256) ; 12928: s_ct (256) ; 13184: s_mr (128)
#define SMS 13440

// ======== phase B (inline carry, z from global) + wout GEMM + X residual + LN stats ========
// Runs on a 128-thread half-block with its own sm slice; segment = TSEG=16 tokens.
__device__ __forceinline__ void phaseB_post(
    const ushort_t* DTb, const ushort_t* XINb, const ushort_t* Zb,
    const ushort_t* BTu, const ushort_t* CTu,
    const float* __restrict__ alog, const float* __restrict__ h0g,
    const float* __restrict__ HLi, const float* __restrict__ PPi,
    const float* __restrict__ dpar, const ushort_t* __restrict__ woutb,
    float* __restrict__ X, char* sm, int b, int sg, int tid)
{
  ushort_t* s_dtS = (ushort_t*)sm;
  ushort_t* s_xiS = (ushort_t*)(sm + 4096);
  float*    s_x   = (float*)sm;
  ushort_t* s_a   = (ushort_t*)(sm + 8320);
  ushort_t* s_bt  = (ushort_t*)(sm + 12672);
  ushort_t* s_ct  = (ushort_t*)(sm + 12928);
  float*    s_mr  = (float*)(sm + 13184);

  const int d = tid;
  const int w = tid >> 6, lane = tid & 63, q = lane >> 4, cn = lane & 15;
  const size_t segtok = (size_t)b*TT + sg*TSEG;

  {
    const uint4* gdt = (const uint4*)(DTb + segtok*128);
    const uint4* gxi = (const uint4*)(XINb + segtok*128);
    #pragma unroll
    for (int i = 0; i < 2; i++){
      ((uint4*)s_dtS)[tid + i*128] = gdt[tid + i*128];
      ((uint4*)s_xiS)[tid + i*128] = gxi[tid + i*128];
    }
    if (tid < 64){
      ((unsigned*)s_bt)[tid] = ((const unsigned*)(BTu + segtok*8))[tid];
      ((unsigned*)s_ct)[tid] = ((const unsigned*)(CTu + segtok*8))[tid];
    }
  }
  float A2[8], h[8];
  #pragma unroll
  for (int s = 0; s < 8; s++){
    A2[s] = -__expf(alog[d*8 + s]) * LOG2E;
    h[s] = h0g[(size_t)b*1024 + d*8 + s];
  }
  for (int ch = 0; ch < sg; ch++){
    const size_t o = ((size_t)b*SSEG + ch)*1024 + d*8;
    float4 hl0 = *(const float4*)(HLi + o);
    float4 hl1 = *(const float4*)(HLi + o + 4);
    float4 pp0 = *(const float4*)(PPi + o);
    float4 pp1 = *(const float4*)(PPi + o + 4);
    h[0]=fmaf(pp0.x,h[0],hl0.x); h[1]=fmaf(pp0.y,h[1],hl0.y);
    h[2]=fmaf(pp0.z,h[2],hl0.z); h[3]=fmaf(pp0.w,h[3],hl0.w);
    h[4]=fmaf(pp1.x,h[4],hl1.x); h[5]=fmaf(pp1.y,h[5],hl1.y);
    h[6]=fmaf(pp1.z,h[6],hl1.z); h[7]=fmaf(pp1.w,h[7],hl1.w);
  }
  __syncthreads();

  // scan: y only
  #pragma unroll 4
  for (int t = 0; t < TSEG; t++){
    float dt = b2f(s_dtS[t*128 + d]);
    float xi = b2f(s_xiS[t*128 + d]);
    float wv = dt * xi;
    float y = 0.f;
    #pragma unroll
    for (int s = 0; s < 8; s++){
      float dA = exp2f(dt * A2[s]);
      h[s] = fmaf(dA, h[s], wv * b2f(s_bt[t*8 + s]));
      y = fmaf(h[s], b2f(s_ct[t*8 + s]), y);
    }
    s_a[t*136 + d] = f2bf(y);
  }
  __syncthreads();

  // z-apply: ssm = y*silu(z) + xi*dp
  {
    const int c0 = (tid & 15)*8, trow = tid >> 4;
    float dpv[8];
    #pragma unroll
    for (int j = 0; j < 8; j++) dpv[j] = dpar[c0 + j];
    #pragma unroll
    for (int i = 0; i < 2; i++){
      const int t = trow + i*8;
      uint4 zb = ((const uint4*)(Zb + segtok*128))[tid + i*128];
      const ushort_t* zp = (const ushort_t*)&zb;
      #pragma unroll
      for (int j = 0; j < 8; j++){
        float y  = b2f(s_a[t*136 + c0 + j]);
        float xi = b2f(s_xiS[t*128 + c0 + j]);
        float ssm = y * silu_f(b2f(zp[j])) + xi * dpv[j];
        s_a[t*136 + c0 + j] = f2bf(ssm);
      }
    }
  }
  __syncthreads();   // s_dtS/s_xiS dead beyond this point -> s_x may be written

  // wout GEMM (16x128 @ 128^T) + residual -> s_x + X
  {
    short8 af[4];
    #pragma unroll
    for (int ks = 0; ks < 4; ks++)
      af[ks] = *(const short8*)&s_a[cn*136 + ks*32 + q*8];
    for (int nt = w; nt < 8; nt += 2){
      const int n0 = nt * 16;
      short8 bf[4];
      #pragma unroll
      for (int ks = 0; ks < 4; ks++)
        bf[ks] = *(const short8*)&woutb[(size_t)(n0+cn)*128 + ks*32 + q*8];
      f32x4 acc = {0.f,0.f,0.f,0.f};
      #pragma unroll
      for (int ks = 0; ks < 4; ks++) acc = MFMA(af[ks], bf[ks], acc);
      #pragma unroll
      for (int r = 0; r < 4; r++){
        const int tr = q*4 + r;
        const size_t g = (segtok + tr)*128 + n0 + cn;
        float xn = X[g] + acc[r];
        X[g] = xn;
        s_x[tr*130 + n0 + cn] = xn;
      }
    }
  }
  __syncthreads();

  // LN stats (8 thr/token)
  {
    const int t = tid >> 3, part = tid & 7;
    float s = 0.f, s2 = 0.f;
    const float* row = s_x + t*130 + part*16;
    #pragma unroll
    for (int j = 0; j < 16; j++){ float v = row[j]; s += v; s2 = fmaf(v, v, s2); }
    s  += __shfl_xor(s, 1, 64);  s2 += __shfl_xor(s2, 1, 64);
    s  += __shfl_xor(s, 2, 64);  s2 += __shfl_xor(s2, 2, 64);
    s  += __shfl_xor(s, 4, 64);  s2 += __shfl_xor(s2, 4, 64);
    if (part == 0){
      float m = s * (1.f/128.f);
      s_mr[t*2] = m;
      s_mr[t*2+1] = rsqrtf(s2 * (1.f/128.f) - m*m + 1e-5f);
    }
  }
  __syncthreads();
}

// ---- k_scan2p: 256 thr = 2 independent segment slices; grid BB*SSEG/2 ----
__global__ __launch_bounds__(256) void k_scan2p(
    ushort_t* DTb, ushort_t* XINb, ushort_t* Zb,
    ushort_t* BTu, ushort_t* CTu,
    const float* __restrict__ alog, const float* __restrict__ h0g,
    const float* __restrict__ HLi, const float* __restrict__ PPi,
    const float* __restrict__ dpar, const ushort_t* __restrict__ woutb,
    float* __restrict__ X,
    const float* __restrict__ lng, const float* __restrict__ lnb,
    const ushort_t* __restrict__ wigb, const ushort_t* __restrict__ wdbcb,
    const float* __restrict__ bdt,
    const float* __restrict__ alogn,
    float* __restrict__ HLo, float* __restrict__ PPo)
{
  __shared__ __align__(16) char sm_all[2*SMS];
  const int sub = threadIdx.x >> 7;
  char* sm = sm_all + sub*SMS;
  const int tid = threadIdx.x & 127;

  float*    s_x  = (float*)sm;
  ushort_t* s_xin= (ushort_t*)sm;
  ushort_t* s_a  = (ushort_t*)(sm + 8320);
  ushort_t* s_bt = (ushort_t*)(sm + 12672);
  float*    s_mr = (float*)(sm + 13184);

  const int b = blockIdx.x >> 4;
  const int sg = (blockIdx.x & 15)*2 + sub;
  const int w = tid >> 6, lane = tid & 63, q = lane >> 4, cn = lane & 15;
  const size_t segtok = (size_t)b*TT + sg*TSEG;

  phaseB_post(DTb, XINb, Zb, BTu, CTu, alog, h0g, HLi, PPi, dpar, woutb, X, sm, b, sg, tid);

  // normalize -> s_a bf16 (s_a disjoint from s_x now)
  {
    float g = lng[tid], c0v = lnb[tid];
    #pragma unroll
    for (int t = 0; t < TSEG; t++){
      float v = (s_x[t*130 + tid] - s_mr[t*2]) * s_mr[t*2+1] * g + c0v;
      s_a[t*136 + tid] = f2bf(v);
    }
  }
  __syncthreads();

  // wig GEMM (reads s_a; writes s_xin which aliases dead s_x)
  {
    short8 af[4];
    #pragma unroll
    for (int ks = 0; ks < 4; ks++)
      af[ks] = *(const short8*)&s_a[cn*136 + ks*32 + q*8];
    for (int nt = w; nt < 16; nt += 2){
      const int n0 = nt * 16;
      short8 bf[4];
      #pragma unroll
      for (int ks = 0; ks < 4; ks++)
        bf[ks] = *(const short8*)&wigb[(size_t)(n0+cn)*128 + ks*32 + q*8];
      f32x4 acc = {0.f,0.f,0.f,0.f};
      #pragma unroll
      for (int ks = 0; ks < 4; ks++) acc = MFMA(af[ks], bf[ks], acc);
      if (n0 < 128){
        #pragma unroll
        for (int r = 0; r < 4; r++){
          const int tr = q*4 + r;
          ushort_t bb = f2bf(acc[r]);
          XINb[(segtok + tr)*128 + n0 + cn] = bb;
          s_xin[tr*136 + n0 + cn] = bb;
        }
      } else {
        #pragma unroll
        for (int r = 0; r < 4; r++){
          const int tr = q*4 + r;
          Zb[(segtok + tr)*128 + (n0-128) + cn] = f2bf(acc[r]);
        }
      }
    }
  }
  __syncthreads();

  // wdbc GEMM (fills s_a=next-dt, s_bt=next-bt)
  {
    short8 af2[4];
    #pragma unroll
    for (int ks = 0; ks < 4; ks++)
      af2[ks] = *(const short8*)&s_xin[cn*136 + ks*32 + q*8];
    for (int nt = w; nt < 9; nt += 2){
      const int n0 = nt * 16;
      short8 bf[4];
      #pragma unroll
      for (int ks = 0; ks < 4; ks++)
        bf[ks] = *(const short8*)&wdbcb[(size_t)(n0+cn)*128 + ks*32 + q*8];
      const int col = n0 + cn;
      f32x4 acc = {0.f,0.f,0.f,0.f};
      #pragma unroll
      for (int ks = 0; ks < 4; ks++) acc = MFMA(af2[ks], bf[ks], acc);
      if (col < 128){
        float bd = bdt[col];
        #pragma unroll
        for (int r = 0; r < 4; r++){
          const int tr = q*4 + r;
          ushort_t dv = f2bf(softplus_f(acc[r] + bd));
          DTb[(segtok + tr)*128 + col] = dv;
          s_a[tr*136 + col] = dv;
        }
      } else if (col < 136){
        #pragma unroll
        for (int r = 0; r < 4; r++){
          const int tr = q*4 + r;
          ushort_t bb = f2bf(acc[r]);
          BTu[(segtok + tr)*8 + (col-128)] = bb;
          s_bt[tr*8 + (col-128)] = bb;
        }
      } else {
        #pragma unroll
        for (int r = 0; r < 4; r++)
          CTu[(segtok + q*4 + r)*8 + (col-136)] = f2bf(acc[r]);
      }
    }
  }
  __syncthreads();

  // phase A (next layer) over this segment
  {
    float A2n[8], hh[8], pp[8];
    #pragma unroll
    for (int s = 0; s < 8; s++){
      A2n[s] = -__expf(alogn[tid*8 + s]) * LOG2E;
      hh[s] = 0.f; pp[s] = 1.f;
    }
    #pragma unroll 4
    for (int t = 0; t < TSEG; t++){
      float dt = b2f(s_a[t*136 + tid]);
      float wv = dt * b2f(s_xin[t*136 + tid]);
      #pragma unroll
      for (int s = 0; s < 8; s++){
        float dA = exp2f(dt * A2n[s]);
        hh[s] = fmaf(dA, hh[s], wv * b2f(s_bt[t*8 + s]));
        pp[s] *= dA;
      }
    }
    const size_t o = ((size_t)b*SSEG + sg)*1024 + tid*8;
    #pragma unroll
    for (int s = 0; s < 8; s++){ HLo[o+s] = hh[s]; PPo[o+s] = pp[s]; }
  }
}

// ---- k_scan2h: 256 thr = 2 segment slices; phaseB+post+LNfn+head ----
__global__ __launch_bounds__(256) void k_scan2h(
    const ushort_t* DTb, const ushort_t* XINb, const ushort_t* Zb,
    const ushort_t* BTu, const ushort_t* CTu,
    const float* __restrict__ alog, const float* __restrict__ h0g,
    const float* __restrict__ HLi, const float* __restrict__ PPi,
    const float* __restrict__ dpar, const ushort_t* __restrict__ woutb,
    float* __restrict__ X,
    const float* __restrict__ fng, const float* __restrict__ fnb,
    const ushort_t* __restrict__ pw1b, const float* __restrict__ pb1,
    const float* __restrict__ pg, const float* __restrict__ pbb,
    const ushort_t* __restrict__ pw2b, const float* __restrict__ pb2,
    float* __restrict__ out)
{
  __shared__ __align__(16) char sm_all[2*SMS];
  const int sub = threadIdx.x >> 7;
  char* sm = sm_all + sub*SMS;
  const int tid = threadIdx.x & 127;

  float*    s_x  = (float*)sm;
  ushort_t* s_a  = (ushort_t*)(sm + 8320);
  float*    s_mr = (float*)(sm + 13184);

  const int b = blockIdx.x >> 4;
  const int sg = (blockIdx.x & 15)*2 + sub;
  const int w = tid >> 6, lane = tid & 63, q = lane >> 4, cn = lane & 15;
  const size_t segtok = (size_t)b*TT + sg*TSEG;

  phaseB_post((ushort_t*)DTb, (ushort_t*)XINb, (ushort_t*)Zb,
              (ushort_t*)BTu, (ushort_t*)CTu, alog, h0g, HLi, PPi,
              dpar, woutb, X, sm, b, sg, tid);

  // LN_fn -> s_a bf16
  {
    float g = fng[tid], c0v = fnb[tid];
    #pragma unroll
    for (int t = 0; t < TSEG; t++){
      float v = (s_x[t*130 + tid] - s_mr[t*2]) * s_mr[t*2+1] * g + c0v;
      s_a[t*136 + tid] = f2bf(v);
    }
  }
  __syncthreads();

  // pw1 GEMM -> s_x (+bias); s_a disjoint from s_x
  {
    short8 af[4];
    #pragma unroll
    for (int ks = 0; ks < 4; ks++)
      af[ks] = *(const short8*)&s_a[cn*136 + ks*32 + q*8];
    for (int nt = w; nt < 8; nt += 2){
      const int n0 = nt * 16;
      short8 bf[4];
      #pragma unroll
      for (int ks = 0; ks < 4; ks++)
        bf[ks] = *(const short8*)&pw1b[(size_t)(n0+cn)*128 + ks*32 + q*8];
      float bias = pb1[n0 + cn];
      f32x4 acc = {0.f,0.f,0.f,0.f};
      #pragma unroll
      for (int ks = 0; ks < 4; ks++) acc = MFMA(af[ks], bf[ks], acc);
      #pragma unroll
      for (int r = 0; r < 4; r++)
        s_x[(q*4 + r)*130 + n0 + cn] = acc[r] + bias;
    }
  }
  __syncthreads();

  // LN stats (8 thr/token)
  {
    const int t = tid >> 3, part = tid & 7;
    float s = 0.f, s2 = 0.f;
    const float* row = s_x + t*130 + part*16;
    #pragma unroll
    for (int j = 0; j < 16; j++){ float v = row[j]; s += v; s2 = fmaf(v, v, s2); }
    s  += __shfl_xor(s, 1, 64);  s2 += __shfl_xor(s2, 1, 64);
    s  += __shfl_xor(s, 2, 64);  s2 += __shfl_xor(s2, 2, 64);
    s  += __shfl_xor(s, 4, 64);  s2 += __shfl_xor(s2, 4, 64);
    if (part == 0){
      float m = s * (1.f/128.f);
      s_mr[t*2] = m;
      s_mr[t*2+1] = rsqrtf(s2 * (1.f/128.f) - m*m + 1e-5f);
    }
  }
  __syncthreads();
  {
    float g = pg[tid], c0v = pbb[tid];
    #pragma unroll
    for (int t = 0; t < TSEG; t++){
      float v = (s_x[t*130 + tid] - s_mr[t*2]) * s_mr[t*2+1] * g + c0v;
      s_a[t*136 + tid] = f2bf(silu_f(v));
    }
  }
  __syncthreads();

  // pw2 GEMM
  {
    short8 af[4];
    #pragma unroll
    for (int ks = 0; ks < 4; ks++)
      af[ks] = *(const short8*)&s_a[cn*136 + ks*32 + q*8];
    const int n0 = w * 16;
    short8 bf[4];
    #pragma unroll
    for (int ks = 0; ks < 4; ks++)
      bf[ks] = *(const short8*)&pw2b[(size_t)(n0+cn)*128 + ks*32 + q*8];
    const int col = n0 + cn;
    f32x4 acc = {0.f,0.f,0.f,0.f};
    #pragma unroll
    for (int ks = 0; ks < 4; ks++) acc = MFMA(af[ks], bf[ks], acc);
    if (col < NAD){
      float bias = pb2[col];
      #pragma unroll
      for (int r = 0; r < 4; r++)
        out[(segtok + q*4 + r)*NAD + col] = acc[r] + bias;
    }
  }
}

extern "C" void kernel_launch(void* const* d_in, const int* in_sizes, int n_in,
                              void* d_out, int out_size, void* d_ws, size_t ws_size,
                              hipStream_t stream) {
  const float* obs    = (const float*)d_in[0];
  const float* h0     = (const float*)d_in[1];
  const float* enc_w1 = (const float*)d_in[2];
  const float* enc_b1 = (const float*)d_in[3];
  const float* enc_g1 = (const float*)d_in[4];
  const float* enc_bb1= (const float*)d_in[5];
  const float* enc_w2 = (const float*)d_in[6];
  const float* enc_b2 = (const float*)d_in[7];
  const float* enc_g2 = (const float*)d_in[8];
  const float* enc_bb2= (const float*)d_in[9];
  const float* emb    = (const float*)d_in[10];
  const float* proj_w = (const float*)d_in[11];
  const float* proj_b = (const float*)d_in[12];
  const float* proj_g = (const float*)d_in[13];
  const float* proj_bb= (const float*)d_in[14];
  const float* m_ln_g = (const float*)d_in[15];
  const float* m_ln_b = (const float*)d_in[16];
  const float* m_w_ig = (const float*)d_in[17];
  const float* m_w_dt = (const float*)d_in[18];
  const float* m_b_dt = (const float*)d_in[19];
  const float* m_a_log= (const float*)d_in[20];
  const float* m_w_b  = (const float*)d_in[21];
  const float* m_w_c  = (const float*)d_in[22];
  const float* m_d    = (const float*)d_in[23];
  const float* m_w_out= (const float*)d_in[24];
  const float* fn_g   = (const float*)d_in[25];
  const float* fn_b   = (const float*)d_in[26];
  const float* pol_w1 = (const float*)d_in[27];
  const float* pol_b1 = (const float*)d_in[28];
  const float* pol_g  = (const float*)d_in[29];
  const float* pol_bb = (const float*)d_in[30];
  const float* pol_w2 = (const float*)d_in[31];
  const float* pol_b2 = (const float*)d_in[32];
  const int*   pact   = (const int*)d_in[33];

  float* ws  = (float*)d_ws;
  float* X    = ws;
  float* HLA  = X + (size_t)NTOK*128;
  float* PPA  = HLA + (size_t)BB*SSEG*1024;
  ushort_t* E1 = (ushort_t*)(PPA + (size_t)BB*SSEG*1024);
  // HLB/PPB alias E1 (E1 dead after k_enc2p; HLB first written by scan layer 0,
  // which is stream-ordered after k_enc2p). 2*BB*SSEG*1024 f32 == NTOK*256 bf16 bytes.
  float* HLB  = (float*)E1;
  float* PPB  = HLB + (size_t)BB*SSEG*1024;
  ushort_t* XINb = E1   + (size_t)NTOK*256;
  ushort_t* Zb   = XINb + (size_t)NTOK*128;
  ushort_t* DTb  = Zb   + (size_t)NTOK*128;
  ushort_t* BTu  = DTb  + (size_t)NTOK*128;
  ushort_t* CTu  = BTu  + (size_t)NTOK*8;

  ushort_t* W1B   = CTu   + (size_t)NTOK*8;
  ushort_t* W2B   = W1B   + 256*128;
  ushort_t* PWB   = W2B   + 128*256;
  ushort_t* WIGB  = PWB   + 128*160;
  ushort_t* WDBCB = WIGB  + 3*256*128;
  ushort_t* WOUTB = WDBCB + 3*144*128;
  ushort_t* PW1B  = WOUTB + 3*128*128;
  ushort_t* PW2B  = PW1B  + 128*128;

  PJobs P;
  int nj = 0;
  auto add = [&](const float* src, ushort_t* dst, int N, int K, int Kpad, int rowofs, int Nw){
    P.j[nj].src = src; P.j[nj].dst = dst; P.j[nj].N = N; P.j[nj].K = K;
    P.j[nj].Kpad = Kpad; P.j[nj].rowofs = rowofs; P.j[nj].Nw = Nw; nj++;
  };
  add(enc_w1, W1B, 256, 115, 128, 0, 256);
  add(enc_w2, W2B, 128, 256, 256, 0, 128);
  add(proj_w, PWB, 128, 144, 160, 0, 128);
  for (int l = 0; l < NLD; l++)
    add(m_w_ig + (size_t)l*256*128, WIGB + (size_t)l*256*128, 256, 128, 128, 0, 256);
  for (int l = 0; l < NLD; l++){
    add(m_w_dt + (size_t)l*128*128, WDBCB + (size_t)l*144*128, 128, 128, 128, 0,   128);
    add(m_w_b  + (size_t)l*8*128,   WDBCB + (size_t)l*144*128,   8, 128, 128, 128,   8);
    add(m_w_c  + (size_t)l*8*128,   WDBCB + (size_t)l*144*128,   8, 128, 128, 136,   8);
  }
  for (int l = 0; l < NLD; l++)
    add(m_w_out + (size_t)l*128*128, WOUTB + (size_t)l*128*128, 128, 128, 128, 0, 128);
  add(pol_w1, PW1B, 128, 128, 128, 0, 128);
  add(pol_w2, PW2B,  19, 128, 128, 0,  32);

  k_prep<<<20*4, 256, 0, stream>>>(P);
  k_enc1<<<NTOK/32, 256, 0, stream>>>(obs, W1B, enc_b1, enc_g1, enc_bb1, E1);
  k_enc2p<<<NTOK/32, 256, 0, stream>>>(E1, W2B, enc_b2, enc_g2, enc_bb2,
      emb, pact, PWB, proj_b, proj_g, proj_bb, X,
      m_ln_g, m_ln_b, WIGB, WDBCB, m_b_dt,
      XINb, Zb, DTb, BTu, CTu,
      m_a_log, HLA, PPA);

  const int scangrid = BB*SSEG/2;   // 1024 blocks x 256 thr
  // layer 0: reads A, writes B
  k_scan2p<<<scangrid, 256, 0, stream>>>(DTb, XINb, Zb, BTu, CTu,
      m_a_log, h0, HLA, PPA, m_d, WOUTB, X,
      m_ln_g + 128, m_ln_b + 128,
      WIGB + (size_t)256*128, WDBCB + (size_t)144*128, m_b_dt + 128,
      m_a_log + 1024, HLB, PPB);
  // layer 1: reads B, writes A
  k_scan2p<<<scangrid, 256, 0, stream>>>(DTb, XINb, Zb, BTu, CTu,
      m_a_log + 1024, h0 + (size_t)BB*1024, HLB, PPB, m_d + 128,
      WOUTB + (size_t)128*128, X,
      m_ln_g + 256, m_ln_b + 256,
      WIGB + (size_t)2*256*128, WDBCB + (size_t)2*144*128, m_b_dt + 256,
      m_a_log + 2048, HLA, PPA);
  // layer 2: reads A
  k_scan2h<<<scangrid, 256, 0, stream>>>(DTb, XINb, Zb, BTu, CTu,
      m_a_log + 2048, h0 + (size_t)2*BB*1024, HLA, PPA, m_d + 256,
      WOUTB + (size_t)2*128*128, X,
      fn_g, fn_b, PW1B, pol_b1, pol_g, pol_bb, PW2B, pol_b2,
      (float*)d_out);
}

// Round 2
// 421.822 us; speedup vs baseline: 1.1066x; 1.1066x over previous
//
#include <hip/hip_runtime.h>
#include <math.h>

#define BB 64
#define TT 512
#define OBSD 115
#define DMD 128
#define DSD 8
#define NLD 3
#define EMBD 16
#define NAD 19
#define H1D 256
#define NTOK (BB*TT)
#define SSEG 32
#define TSEG (TT/SSEG)   // 16

typedef unsigned short ushort_t;
typedef __attribute__((ext_vector_type(8))) short short8;
typedef __attribute__((ext_vector_type(4))) float f32x4;

__device__ __forceinline__ float silu_f(float x){ return x / (1.f + __expf(-x)); }
__device__ __forceinline__ float softplus_f(float x){
  return fmaxf(x, 0.f) + log1pf(__expf(-fabsf(x)));
}
__device__ __forceinline__ ushort_t f2bf(float x){
  unsigned u = __float_as_uint(x);
  unsigned r = (u + 0x7fffu + ((u >> 16) & 1u)) >> 16;
  return (ushort_t)r;
}
__device__ __forceinline__ float b2f(ushort_t x){
  return __uint_as_float(((unsigned)x) << 16);
}
#define MFMA(a,b,c) __builtin_amdgcn_mfma_f32_16x16x32_bf16((a),(b),(c),0,0,0)
#define LOG2E 1.44269504f

// LN stats over 32 tokens, D cols, stride SV floats (SV%32==8 -> conflict-free).
template<int D, int SV>
__device__ __forceinline__ void ln32(const float* s_val, float* s_mr, int tid){
  const int t = tid >> 3, part = tid & 7;
  float s = 0.f, s2 = 0.f;
  #pragma unroll
  for (int j = part; j < D; j += 8){ float v = s_val[t*SV + j]; s += v; s2 = fmaf(v, v, s2); }
  s += __shfl_xor(s, 1, 64); s2 += __shfl_xor(s2, 1, 64);
  s += __shfl_xor(s, 2, 64); s2 += __shfl_xor(s2, 2, 64);
  s += __shfl_xor(s, 4, 64); s2 += __shfl_xor(s2, 4, 64);
  if (part == 0){
    float m = s * (1.f/(float)D);
    s_mr[t*2] = m;
    s_mr[t*2+1] = rsqrtf(s2 * (1.f/(float)D) - m*m + 1e-5f);
  }
}

// ---------------- k_prep ----------------
struct PJob { const float* src; ushort_t* dst; int N; int K; int Kpad; int rowofs; int Nw; };
struct PJobs { PJob j[20]; };

__global__ __launch_bounds__(256) void k_prep(PJobs P){
  const int job = blockIdx.x >> 2;
  const int sub = blockIdx.x & 3;
  PJob pj = P.j[job];
  const int elems = pj.Nw * pj.Kpad;
  for (int idx = sub*256 + threadIdx.x; idx < elems; idx += 4*256){
    int n = idx / pj.Kpad;
    int k = idx - n*pj.Kpad;
    float v = (n < pj.N && k < pj.K) ? pj.src[(size_t)n*pj.K + k] : 0.f;
    pj.dst[(size_t)(pj.rowofs + n)*pj.Kpad + k] = f2bf(v);
  }
}

// ---------------- k_enc1: e1(bf16) = silu(LN(obs @ w1.T + b1)) ----------------
__global__ __launch_bounds__(256) void k_enc1(
    const float* __restrict__ obs, const ushort_t* __restrict__ w1b,
    const float* __restrict__ b1, const float* __restrict__ g1,
    const float* __restrict__ bb1, ushort_t* __restrict__ e1)
{
  __shared__ __align__(16) char sm[34048];
  float*    s_val = (float*)sm;          // 32x264 f32
  ushort_t* s_a   = (ushort_t*)sm;       // 32x136 bf16 (aliases; dead after af load)
  float*    s_mr  = (float*)(sm + 33792);
  const int tok0 = blockIdx.x * 32;
  const int tid = threadIdx.x;
  const int lane = tid & 63, w = tid >> 6;
  const int q = lane >> 4, cn = lane & 15;
  const int m0 = (w & 1) * 16, nh = w >> 1;

  for (int e = tid; e < 32*16; e += 256){
    int t = e >> 4, kc = e & 15;
    const float* op = obs + (size_t)(tok0 + t)*OBSD;
    short8 v;
    #pragma unroll
    for (int j = 0; j < 8; j++){
      int k = kc*8 + j;
      v[j] = (short)f2bf(k < OBSD ? op[k] : 0.f);
    }
    *(short8*)&s_a[t*136 + kc*8] = v;
  }
  __syncthreads();

  short8 af[4];
  #pragma unroll
  for (int ks = 0; ks < 4; ks++)
    af[ks] = *(const short8*)&s_a[(m0 + cn)*136 + ks*32 + q*8];
  __syncthreads();

  #pragma unroll
  for (int nt = 0; nt < 8; nt++){
    const int n0 = (nh*8 + nt) * 16;
    f32x4 acc = {0.f,0.f,0.f,0.f};
    #pragma unroll
    for (int ks = 0; ks < 4; ks++){
      short8 bf = *(const short8*)&w1b[(size_t)(n0 + cn)*128 + ks*32 + q*8];
      acc = MFMA(af[ks], bf, acc);
    }
    float bias = b1[n0 + cn];
    #pragma unroll
    for (int r = 0; r < 4; r++)
      s_val[(m0 + q*4 + r)*264 + n0 + cn] = acc[r] + bias;
  }
  __syncthreads();

  ln32<256,264>(s_val, s_mr, tid);
  __syncthreads();
  for (int e = tid; e < 32*256; e += 256){
    int t = e >> 8, c = e & 255;
    float v = (s_val[t*264 + c] - s_mr[t*2]) * s_mr[t*2+1] * g1[c] + bb1[c];
    e1[(size_t)(tok0 + t)*256 + c] = f2bf(silu_f(v));
  }
}

// ------- k_enc2p: enc2+proj+LN(l0)+wig/wdbc(l0)+phaseA(l0) — 32 tok (=2 segments) -------
__global__ __launch_bounds__(256) void k_enc2p(
    const ushort_t* __restrict__ e1, const ushort_t* __restrict__ w2b,
    const float* __restrict__ b2, const float* __restrict__ g2,
    const float* __restrict__ bb2,
    const float* __restrict__ emb, const int* __restrict__ pact,
    const ushort_t* __restrict__ pwb, const float* __restrict__ pb,
    const float* __restrict__ pg, const float* __restrict__ pbb,
    float* __restrict__ X,
    const float* __restrict__ lng, const float* __restrict__ lnb,
    const ushort_t* __restrict__ wigb, const ushort_t* __restrict__ wdbcb,
    const float* __restrict__ bdt,
    ushort_t* __restrict__ XINb, ushort_t* __restrict__ Zb,
    ushort_t* __restrict__ DTb, ushort_t* __restrict__ BTu, ushort_t* __restrict__ CTu,
    const float* __restrict__ alog0,
    float* __restrict__ HLOC, float* __restrict__ PPR)
{
  __shared__ __align__(16) char sm[28928];
  float*    s_val = (float*)sm;                 // 32x136 f32
  ushort_t* s_xin = (ushort_t*)sm;              // aliases s_val after dead
  ushort_t* s_dt  = (ushort_t*)(sm + 8704);     // aliases s_val tail
  ushort_t* s_a   = (ushort_t*)(sm + 17408);    // 32x168 bf16
  ushort_t* s_btc = (ushort_t*)(sm + 28160);    // 32x8
  float*    s_mr  = (float*)(sm + 28672);

  const int tok0 = blockIdx.x * 32;
  const int bidx = blockIdx.x >> 4;
  const int ch   = blockIdx.x & 15;
  const int tid = threadIdx.x;
  const int lane = tid & 63, w = tid >> 6;
  const int q = lane >> 4, cn = lane & 15;
  const int m0 = (w & 1) * 16, nh = w >> 1;

  for (int e = tid; e < 32*32; e += 256){
    int t = e >> 5, k = e & 31;
    float v = 0.f;
    if (k < EMBD){ int a = pact[tok0 + t]; v = emb[(size_t)a*EMBD + k]; }
    s_a[t*168 + 128 + k] = f2bf(v);
  }
  {
    short8 af[8];
    #pragma unroll
    for (int ks = 0; ks < 8; ks++)
      af[ks] = *(const short8*)&e1[(size_t)(tok0 + m0 + cn)*256 + ks*32 + q*8];
    #pragma unroll
    for (int nt = 0; nt < 4; nt++){
      const int n0 = (nh*4 + nt) * 16;
      f32x4 acc = {0.f,0.f,0.f,0.f};
      #pragma unroll
      for (int ks = 0; ks < 8; ks++){
        short8 bf = *(const short8*)&w2b[(size_t)(n0 + cn)*256 + ks*32 + q*8];
        acc = MFMA(af[ks], bf, acc);
      }
      float bias = b2[n0 + cn];
      #pragma unroll
      for (int r = 0; r < 4; r++)
        s_val[(m0 + q*4 + r)*136 + n0 + cn] = acc[r] + bias;
    }
  }
  __syncthreads();

  ln32<128,136>(s_val, s_mr, tid);
  __syncthreads();
  for (int e = tid; e < 32*128; e += 256){
    int t = e >> 7, c = e & 127;
    float v = (s_val[t*136 + c] - s_mr[t*2]) * s_mr[t*2+1] * g2[c] + bb2[c];
    s_a[t*168 + c] = f2bf(v);
  }
  __syncthreads();

  {
    short8 af2[5];
    #pragma unroll
    for (int ks = 0; ks < 5; ks++)
      af2[ks] = *(const short8*)&s_a[(m0 + cn)*168 + ks*32 + q*8];
    #pragma unroll
    for (int nt = 0; nt < 4; nt++){
      const int n0 = (nh*4 + nt) * 16;
      f32x4 acc = {0.f,0.f,0.f,0.f};
      #pragma unroll
      for (int ks = 0; ks < 5; ks++){
        short8 bf = *(const short8*)&pwb[(size_t)(n0 + cn)*160 + ks*32 + q*8];
        acc = MFMA(af2[ks], bf, acc);
      }
      float bias = pb[n0 + cn];
      #pragma unroll
      for (int r = 0; r < 4; r++)
        s_val[(m0 + q*4 + r)*136 + n0 + cn] = acc[r] + bias;
    }
  }
  __syncthreads();

  ln32<128,136>(s_val, s_mr, tid);
  __syncthreads();
  for (int e = tid; e < 32*128; e += 256){
    int t = e >> 7, c = e & 127;
    float v = (s_val[t*136 + c] - s_mr[t*2]) * s_mr[t*2+1] * pg[c] + pbb[c];
    v = silu_f(v);
    X[(size_t)tok0*128 + e] = v;
    s_val[t*136 + c] = v;
  }
  __syncthreads();

  ln32<128,136>(s_val, s_mr, tid);
  __syncthreads();
  for (int e = tid; e < 32*128; e += 256){
    int t = e >> 7, c = e & 127;
    float v = (s_val[t*136 + c] - s_mr[t*2]) * s_mr[t*2+1] * lng[c] + lnb[c];
    s_a[t*168 + c] = f2bf(v);
  }
  __syncthreads();   // s_val DEAD; s_xin/s_dt may be written

  // wig GEMM
  {
    short8 af[4];
    #pragma unroll
    for (int ks = 0; ks < 4; ks++)
      af[ks] = *(const short8*)&s_a[(m0 + cn)*168 + ks*32 + q*8];
    #pragma unroll
    for (int nt = 0; nt < 8; nt++){
      const int n0 = (nh*8 + nt) * 16;
      f32x4 acc = {0.f,0.f,0.f,0.f};
      #pragma unroll
      for (int ks = 0; ks < 4; ks++){
        short8 bf = *(const short8*)&wigb[(size_t)(n0 + cn)*128 + ks*32 + q*8];
        acc = MFMA(af[ks], bf, acc);
      }
      if (n0 < 128){
        #pragma unroll
        for (int r = 0; r < 4; r++){
          int tr = m0 + q*4 + r;
          ushort_t bb = f2bf(acc[r]);
          XINb[(size_t)(tok0 + tr)*128 + n0 + cn] = bb;
          s_xin[tr*136 + n0 + cn] = bb;
        }
      } else {
        #pragma unroll
        for (int r = 0; r < 4; r++){
          int tr = m0 + q*4 + r;
          Zb[(size_t)(tok0 + tr)*128 + (n0 - 128) + cn] = f2bf(acc[r]);
        }
      }
    }
  }
  __syncthreads();

  // wdbc GEMM (also fills s_dt / s_btc for phase A)
  {
    short8 af2[4];
    #pragma unroll
    for (int ks = 0; ks < 4; ks++)
      af2[ks] = *(const short8*)&s_xin[(m0 + cn)*136 + ks*32 + q*8];
    for (int nt = nh; nt < 9; nt += 2){
      const int n0 = nt * 16;
      f32x4 acc = {0.f,0.f,0.f,0.f};
      #pragma unroll
      for (int ks = 0; ks < 4; ks++){
        short8 bf = *(const short8*)&wdbcb[(size_t)(n0 + cn)*128 + ks*32 + q*8];
        acc = MFMA(af2[ks], bf, acc);
      }
      const int col = n0 + cn;
      if (col < 128){
        float bd = bdt[col];
        #pragma unroll
        for (int r = 0; r < 4; r++){
          int tr = m0 + q*4 + r;
          ushort_t dv = f2bf(softplus_f(acc[r] + bd));
          DTb[(size_t)(tok0 + tr)*128 + col] = dv;
          s_dt[tr*136 + col] = dv;
        }
      } else if (col < 136){
        #pragma unroll
        for (int r = 0; r < 4; r++){
          int tr = m0 + q*4 + r;
          ushort_t bb = f2bf(acc[r]);
          BTu[(size_t)(tok0 + tr)*8 + (col - 128)] = bb;
          s_btc[tr*8 + (col - 128)] = bb;
        }
      } else {
        #pragma unroll
        for (int r = 0; r < 4; r++)
          CTu[(size_t)(tok0 + m0 + q*4 + r)*8 + (col - 136)] = f2bf(acc[r]);
      }
    }
  }
  __syncthreads();

  // phase A (layer 0): two 16-token segments per block, thread=(d, half)
  {
    const int d = tid & 127, half = tid >> 7;
    float A2c[8], hh[8], pp[8];
    #pragma unroll
    for (int s = 0; s < 8; s++){
      A2c[s] = -__expf(alog0[d*8 + s]) * LOG2E;
      hh[s] = 0.f; pp[s] = 1.f;
    }
    const int t0 = half * 16;
    #pragma unroll 4
    for (int tt = 0; tt < 16; tt++){
      const int t = t0 + tt;
      float dt = b2f(s_dt[t*136 + d]);
      float wv = dt * b2f(s_xin[t*136 + d]);
      #pragma unroll
      for (int s = 0; s < 8; s++){
        float dA = exp2f(dt * A2c[s]);
        hh[s] = fmaf(dA, hh[s], wv * b2f(s_btc[t*8 + s]));
        pp[s] *= dA;
      }
    }
    const size_t o = ((size_t)bidx*SSEG + ch*2 + half)*1024 + d*8;
    #pragma unroll
    for (int s = 0; s < 8; s++){ HLOC[o+s] = hh[s]; PPR[o+s] = pp[s]; }
  }
}

// ---- k_carry: HL[b,ch] := exclusive prefix h_in for chunk ch (in place) ----
// thread = (b, j) with j = d*8+s; 64*1024 threads.
__global__ __launch_bounds__(256) void k_carry(
    float* __restrict__ HL, const float* __restrict__ PP,
    const float* __restrict__ h0g)
{
  const int idx = blockIdx.x*256 + threadIdx.x;
  float h = h0g[idx];
  size_t o = (size_t)(idx >> 10) * (SSEG*1024) + (idx & 1023);
  #pragma unroll 4
  for (int ch = 0; ch < SSEG; ch++){
    float hl = HL[o];
    float pp = PP[o];
    HL[o] = h;
    h = fmaf(pp, h, hl);
    o += 1024;
  }
}

// ======== block-wide phase B over 32 tokens (2 segments) + wout + residual + LN stats ====
// LDS layout (bytes):
//  0     : s_dtS 32x128 bf16 (8192) ; 8192: s_xiS (8192)   [staging; dead after z-apply]
//  s_x   : f32 32x130 (16640) aliases [0,16640)            [wout output; tail clobbers s_a row0]
//  s_xin : bf16 32x136 (8704) aliases [0,8704)             [wig output]
//  s_dt2 : bf16 32x136 (8704) at [8704,17408)              [wdbc output; s_a dead]
//  16384 : s_a bf16 32x136 (8704) -> [16384,25088)
//  25088 : s_bt (512) [later s_btc2] ; 25600: s_ct (512) ; 26112: s_mr (256)
#define SMB 26368

__device__ __forceinline__ void phaseB32(
    const ushort_t* DTb, const ushort_t* XINb, const ushort_t* Zb,
    const ushort_t* BTu, const ushort_t* CTu,
    const float* __restrict__ alog, const float* __restrict__ HLpre,
    const float* __restrict__ dpar, const ushort_t* __restrict__ woutb,
    float* __restrict__ X, char* sm, int b, int pair, int tid)
{
  ushort_t* s_dtS = (ushort_t*)sm;
  ushort_t* s_xiS = (ushort_t*)(sm + 8192);
  float*    s_x   = (float*)sm;
  ushort_t* s_a   = (ushort_t*)(sm + 16384);
  ushort_t* s_bt  = (ushort_t*)(sm + 25088);
  ushort_t* s_ct  = (ushort_t*)(sm + 25600);
  float*    s_mr  = (float*)(sm + 26112);

  const int lane = tid & 63, w = tid >> 6, q = lane >> 4, cn = lane & 15;
  const int m0 = (w & 1) * 16, nh = w >> 1;
  const int d = tid & 127, half = tid >> 7;
  const size_t segtok = (size_t)b*TT + pair*32;

  // stage 32 tokens of dt/xin/bt/ct
  {
    const uint4* gdt = (const uint4*)(DTb + segtok*128);
    const uint4* gxi = (const uint4*)(XINb + segtok*128);
    #pragma unroll
    for (int i = 0; i < 2; i++){
      ((uint4*)s_dtS)[tid + i*256] = gdt[tid + i*256];
      ((uint4*)s_xiS)[tid + i*256] = gxi[tid + i*256];
    }
    if (tid < 128){
      ((unsigned*)s_bt)[tid] = ((const unsigned*)(BTu + segtok*8))[tid];
      ((unsigned*)s_ct)[tid] = ((const unsigned*)(CTu + segtok*8))[tid];
    }
  }
  float A2[8], h[8];
  {
    const size_t o = ((size_t)b*SSEG + pair*2 + half)*1024 + d*8;
    float4 h0v = *(const float4*)(HLpre + o);
    float4 h1v = *(const float4*)(HLpre + o + 4);
    h[0]=h0v.x; h[1]=h0v.y; h[2]=h0v.z; h[3]=h0v.w;
    h[4]=h1v.x; h[5]=h1v.y; h[6]=h1v.z; h[7]=h1v.w;
    #pragma unroll
    for (int s = 0; s < 8; s++) A2[s] = -__expf(alog[d*8 + s]) * LOG2E;
  }
  __syncthreads();

  // scan: thread=(d,half) over its 16 tokens; y -> s_a
  #pragma unroll 4
  for (int tt = 0; tt < 16; tt++){
    const int t = half*16 + tt;
    float dt = b2f(s_dtS[t*128 + d]);
    float xi = b2f(s_xiS[t*128 + d]);
    float wv = dt * xi;
    float y = 0.f;
    #pragma unroll
    for (int s = 0; s < 8; s++){
      float dA = exp2f(dt * A2[s]);
      h[s] = fmaf(dA, h[s], wv * b2f(s_bt[t*8 + s]));
      y = fmaf(h[s], b2f(s_ct[t*8 + s]), y);
    }
    s_a[t*136 + d] = f2bf(y);
  }
  __syncthreads();

  // z-apply: ssm = y*silu(z) + xi*dp  (256 thr over 32 tokens)
  {
    const int c0 = (tid & 15)*8, trow = tid >> 4;
    float dpv[8];
    #pragma unroll
    for (int j = 0; j < 8; j++) dpv[j] = dpar[c0 + j];
    #pragma unroll
    for (int i = 0; i < 2; i++){
      const int t = trow + i*16;
      uint4 zb = ((const uint4*)(Zb + segtok*128))[tid + i*256];
      const ushort_t* zp = (const ushort_t*)&zb;
      #pragma unroll
      for (int j = 0; j < 8; j++){
        float y  = b2f(s_a[t*136 + c0 + j]);
        float xi = b2f(s_xiS[t*128 + c0 + j]);
        float ssm = y * silu_f(b2f(zp[j])) + xi * dpv[j];
        s_a[t*136 + c0 + j] = f2bf(ssm);
      }
    }
  }
  __syncthreads();   // staging dead; s_x writable after af loads below

  // wout GEMM (M=32, block-wide) + residual -> s_x + X
  {
    short8 af[4];
    #pragma unroll
    for (int ks = 0; ks < 4; ks++)
      af[ks] = *(const short8*)&s_a[(m0 + cn)*136 + ks*32 + q*8];
    __syncthreads();   // all af in regs before s_x tail clobbers s_a row0
    #pragma unroll
    for (int i = 0; i < 4; i++){
      const int n0 = (nh*4 + i) * 16;
      short8 bf[4];
      #pragma unroll
      for (int ks = 0; ks < 4; ks++)
        bf[ks] = *(const short8*)&woutb[(size_t)(n0+cn)*128 + ks*32 + q*8];
      f32x4 acc = {0.f,0.f,0.f,0.f};
      #pragma unroll
      for (int ks = 0; ks < 4; ks++) acc = MFMA(af[ks], bf[ks], acc);
      #pragma unroll
      for (int r = 0; r < 4; r++){
        const int tr = m0 + q*4 + r;
        const size_t g = (segtok + tr)*128 + n0 + cn;
        float xn = X[g] + acc[r];
        X[g] = xn;
        s_x[tr*130 + n0 + cn] = xn;
      }
    }
  }
  __syncthreads();

  // LN stats (8 thr/token over 32 tokens)
  {
    const int t = tid >> 3, part = tid & 7;
    float s = 0.f, s2 = 0.f;
    const float* row = s_x + t*130 + part*16;
    #pragma unroll
    for (int j = 0; j < 16; j++){ float v = row[j]; s += v; s2 = fmaf(v, v, s2); }
    s  += __shfl_xor(s, 1, 64);  s2 += __shfl_xor(s2, 1, 64);
    s  += __shfl_xor(s, 2, 64);  s2 += __shfl_xor(s2, 2, 64);
    s  += __shfl_xor(s, 4, 64);  s2 += __shfl_xor(s2, 4, 64);
    if (part == 0){
      float m = s * (1.f/128.f);
      s_mr[t*2] = m;
      s_mr[t*2+1] = rsqrtf(s2 * (1.f/128.f) - m*m + 1e-5f);
    }
  }
  __syncthreads();
}

// ---- k_scan2p: 32-token block; phaseB+post, LN, wig, wdbc, phaseA(next) ----
__global__ __launch_bounds__(256, 4) void k_scan2p(
    ushort_t* DTb, ushort_t* XINb, ushort_t* Zb,
    ushort_t* BTu, ushort_t* CTu,
    const float* __restrict__ alog, const float* __restrict__ HLpre,
    const float* __restrict__ dpar, const ushort_t* __restrict__ woutb,
    float* __restrict__ X,
    const float* __restrict__ lng, const float* __restrict__ lnb,
    const ushort_t* __restrict__ wigb, const ushort_t* __restrict__ wdbcb,
    const float* __restrict__ bdt,
    const float* __restrict__ alogn,
    float* __restrict__ HLo, float* __restrict__ PPo)
{
  __shared__ __align__(16) char sm[SMB];
  const int tid = threadIdx.x;
  float*    s_x   = (float*)sm;
  ushort_t* s_xin = (ushort_t*)sm;
  ushort_t* s_dt2 = (ushort_t*)(sm + 8704);
  ushort_t* s_a   = (ushort_t*)(sm + 16384);
  ushort_t* s_btc = (ushort_t*)(sm + 25088);
  float*    s_mr  = (float*)(sm + 26112);

  const int b = blockIdx.x >> 4;
  const int pair = blockIdx.x & 15;
  const int lane = tid & 63, w = tid >> 6, q = lane >> 4, cn = lane & 15;
  const int m0 = (w & 1) * 16, nh = w >> 1;
  const int d = tid & 127, half = tid >> 7;
  const size_t segtok = (size_t)b*TT + pair*32;

  phaseB32(DTb, XINb, Zb, BTu, CTu, alog, HLpre, dpar, woutb, X, sm, b, pair, tid);

  // normalize -> s_a (x31 preloaded: s_a row0 aliases s_x row31 tail)
  {
    float g = lng[d], c0v = lnb[d];
    float x31 = s_x[31*130 + d];
    __syncthreads();
    #pragma unroll
    for (int tt = 0; tt < 16; tt++){
      const int t = half*16 + tt;
      float xv = (t == 31) ? x31 : s_x[t*130 + d];
      float v = (xv - s_mr[t*2]) * s_mr[t*2+1] * g + c0v;
      s_a[t*136 + d] = f2bf(v);
    }
  }
  __syncthreads();

  // wig GEMM (M=32, N=256); writes s_xin (aliases dead s_x) + XINb/Zb
  {
    short8 af[4];
    #pragma unroll
    for (int ks = 0; ks < 4; ks++)
      af[ks] = *(const short8*)&s_a[(m0 + cn)*136 + ks*32 + q*8];
    #pragma unroll
    for (int i = 0; i < 8; i++){
      const int n0 = (nh*8 + i) * 16;
      short8 bf[4];
      #pragma unroll
      for (int ks = 0; ks < 4; ks++)
        bf[ks] = *(const short8*)&wigb[(size_t)(n0+cn)*128 + ks*32 + q*8];
      f32x4 acc = {0.f,0.f,0.f,0.f};
      #pragma unroll
      for (int ks = 0; ks < 4; ks++) acc = MFMA(af[ks], bf[ks], acc);
      if (n0 < 128){
        #pragma unroll
        for (int r = 0; r < 4; r++){
          const int tr = m0 + q*4 + r;
          ushort_t bb = f2bf(acc[r]);
          XINb[(segtok + tr)*128 + n0 + cn] = bb;
          s_xin[tr*136 + n0 + cn] = bb;
        }
      } else {
        #pragma unroll
        for (int r = 0; r < 4; r++){
          const int tr = m0 + q*4 + r;
          Zb[(segtok + tr)*128 + (n0-128) + cn] = f2bf(acc[r]);
        }
      }
    }
  }
  __syncthreads();

  // wdbc GEMM (M=32, N=144); fills s_dt2 / s_btc
  {
    short8 af2[4];
    #pragma unroll
    for (int ks = 0; ks < 4; ks++)
      af2[ks] = *(const short8*)&s_xin[(m0 + cn)*136 + ks*32 + q*8];
    for (int nt = nh; nt < 9; nt += 2){
      const int n0 = nt * 16;
      short8 bf[4];
      #pragma unroll
      for (int ks = 0; ks < 4; ks++)
        bf[ks] = *(const short8*)&wdbcb[(size_t)(n0+cn)*128 + ks*32 + q*8];
      f32x4 acc = {0.f,0.f,0.f,0.f};
      #pragma unroll
      for (int ks = 0; ks < 4; ks++) acc = MFMA(af2[ks], bf[ks], acc);
      const int col = n0 + cn;
      if (col < 128){
        float bd = bdt[col];
        #pragma unroll
        for (int r = 0; r < 4; r++){
          const int tr = m0 + q*4 + r;
          ushort_t dv = f2bf(softplus_f(acc[r] + bd));
          DTb[(segtok + tr)*128 + col] = dv;
          s_dt2[tr*136 + col] = dv;
        }
      } else if (col < 136){
        #pragma unroll
        for (int r = 0; r < 4; r++){
          const int tr = m0 + q*4 + r;
          ushort_t bb = f2bf(acc[r]);
          BTu[(segtok + tr)*8 + (col-128)] = bb;
          s_btc[tr*8 + (col-128)] = bb;
        }
      } else {
        #pragma unroll
        for (int r = 0; r < 4; r++)
          CTu[(segtok + m0 + q*4 + r)*8 + (col-136)] = f2bf(acc[r]);
      }
    }
  }
  __syncthreads();

  // phase A (next layer): thread=(d,half) over its 16 tokens
  {
    float A2n[8], hh[8], pp[8];
    #pragma unroll
    for (int s = 0; s < 8; s++){
      A2n[s] = -__expf(alogn[d*8 + s]) * LOG2E;
      hh[s] = 0.f; pp[s] = 1.f;
    }
    #pragma unroll 4
    for (int tt = 0; tt < 16; tt++){
      const int t = half*16 + tt;
      float dt = b2f(s_dt2[t*136 + d]);
      float wv = dt * b2f(s_xin[t*136 + d]);
      #pragma unroll
      for (int s = 0; s < 8; s++){
        float dA = exp2f(dt * A2n[s]);
        hh[s] = fmaf(dA, hh[s], wv * b2f(s_btc[t*8 + s]));
        pp[s] *= dA;
      }
    }
    const size_t o = ((size_t)b*SSEG + pair*2 + half)*1024 + d*8;
    #pragma unroll
    for (int s = 0; s < 8; s++){ HLo[o+s] = hh[s]; PPo[o+s] = pp[s]; }
  }
}

// ---- k_scan2h: 32-token block; phaseB+post, LNfn, pw1, LN, silu, pw2 ----
__global__ __launch_bounds__(256, 4) void k_scan2h(
    const ushort_t* DTb, const ushort_t* XINb, const ushort_t* Zb,
    const ushort_t* BTu, const ushort_t* CTu,
    const float* __restrict__ alog, const float* __restrict__ HLpre,
    const float* __restrict__ dpar, const ushort_t* __restrict__ woutb,
    float* __restrict__ X,
    const float* __restrict__ fng, const float* __restrict__ fnb,
    const ushort_t* __restrict__ pw1b, const float* __restrict__ pb1,
    const float* __restrict__ pg, const float* __restrict__ pbb,
    const ushort_t* __restrict__ pw2b, const float* __restrict__ pb2,
    float* __restrict__ out)
{
  __shared__ __align__(16) char sm[SMB];
  const int tid = threadIdx.x;
  float*    s_x  = (float*)sm;
  ushort_t* s_a  = (ushort_t*)(sm + 16384);
  float*    s_mr = (float*)(sm + 26112);

  const int b = blockIdx.x >> 4;
  const int pair = blockIdx.x & 15;
  const int lane = tid & 63, w = tid >> 6, q = lane >> 4, cn = lane & 15;
  const int m0 = (w & 1) * 16, nh = w >> 1;
  const int d = tid & 127, half = tid >> 7;
  const size_t segtok = (size_t)b*TT + pair*32;

  phaseB32((ushort_t*)DTb, (ushort_t*)XINb, (ushort_t*)Zb,
           (ushort_t*)BTu, (ushort_t*)CTu, alog, HLpre,
           dpar, woutb, X, sm, b, pair, tid);

  // LN_fn -> s_a (x31 trick)
  {
    float g = fng[d], c0v = fnb[d];
    float x31 = s_x[31*130 + d];
    __syncthreads();
    #pragma unroll
    for (int tt = 0; tt < 16; tt++){
      const int t = half*16 + tt;
      float xv = (t == 31) ? x31 : s_x[t*130 + d];
      float v = (xv - s_mr[t*2]) * s_mr[t*2+1] * g + c0v;
      s_a[t*136 + d] = f2bf(v);
    }
  }
  __syncthreads();

  // pw1 GEMM (M=32, N=128) -> s_x (+bias)
  {
    short8 af[4];
    #pragma unroll
    for (int ks = 0; ks < 4; ks++)
      af[ks] = *(const short8*)&s_a[(m0 + cn)*136 + ks*32 + q*8];
    __syncthreads();   // af in regs before s_x tail clobbers s_a row0
    #pragma unroll
    for (int i = 0; i < 4; i++){
      const int n0 = (nh*4 + i) * 16;
      short8 bf[4];
      #pragma unroll
      for (int ks = 0; ks < 4; ks++)
        bf[ks] = *(const short8*)&pw1b[(size_t)(n0+cn)*128 + ks*32 + q*8];
      float bias = pb1[n0 + cn];
      f32x4 acc = {0.f,0.f,0.f,0.f};
      #pragma unroll
      for (int ks = 0; ks < 4; ks++) acc = MFMA(af[ks], bf[ks], acc);
      #pragma unroll
      for (int r = 0; r < 4; r++)
        s_x[(m0 + q*4 + r)*130 + n0 + cn] = acc[r] + bias;
    }
  }
  __syncthreads();

  // LN stats (8 thr/token)
  {
    const int t = tid >> 3, part = tid & 7;
    float s = 0.f, s2 = 0.f;
    const float* row = s_x + t*130 + part*16;
    #pragma unroll
    for (int j = 0; j < 16; j++){ float v = row[j]; s += v; s2 = fmaf(v, v, s2); }
    s  += __shfl_xor(s, 1, 64);  s2 += __shfl_xor(s2, 1, 64);
    s  += __shfl_xor(s, 2, 64);  s2 += __shfl_xor(s2, 2, 64);
    s  += __shfl_xor(s, 4, 64);  s2 += __shfl_xor(s2, 4, 64);
    if (part == 0){
      float m = s * (1.f/128.f);
      s_mr[t*2] = m;
      s_mr[t*2+1] = rsqrtf(s2 * (1.f/128.f) - m*m + 1e-5f);
    }
  }
  __syncthreads();

  // silu(LN) -> s_a (x31 trick)
  {
    float g = pg[d], c0v = pbb[d];
    float x31 = s_x[31*130 + d];
    __syncthreads();
    #pragma unroll
    for (int tt = 0; tt < 16; tt++){
      const int t = half*16 + tt;
      float xv = (t == 31) ? x31 : s_x[t*130 + d];
      float v = (xv - s_mr[t*2]) * s_mr[t*2+1] * g + c0v;
      s_a[t*136 + d] = f2bf(silu_f(v));
    }
  }
  __syncthreads();

  // pw2 GEMM (M=32, N=32; cols<19 stored)
  {
    short8 af[4];
    #pragma unroll
    for (int ks = 0; ks < 4; ks++)
      af[ks] = *(const short8*)&s_a[(m0 + cn)*136 + ks*32 + q*8];
    const int n0 = (w >> 1) * 16;
    short8 bf[4];
    #pragma unroll
    for (int ks = 0; ks < 4; ks++)
      bf[ks] = *(const short8*)&pw2b[(size_t)(n0+cn)*128 + ks*32 + q*8];
    const int col = n0 + cn;
    f32x4 acc = {0.f,0.f,0.f,0.f};
    #pragma unroll
    for (int ks = 0; ks < 4; ks++) acc = MFMA(af[ks], bf[ks], acc);
    if (col < NAD){
      float bias = pb2[col];
      #pragma unroll
      for (int r = 0; r < 4; r++)
        out[(segtok + m0 + q*4 + r)*NAD + col] = acc[r] + bias;
    }
  }
}

extern "C" void kernel_launch(void* const* d_in, const int* in_sizes, int n_in,
                              void* d_out, int out_size, void* d_ws, size_t ws_size,
                              hipStream_t stream) {
  const float* obs    = (const float*)d_in[0];
  const float* h0     = (const float*)d_in[1];
  const float* enc_w1 = (const float*)d_in[2];
  const float* enc_b1 = (const float*)d_in[3];
  const float* enc_g1 = (const float*)d_in[4];
  const float* enc_bb1= (const float*)d_in[5];
  const float* enc_w2 = (const float*)d_in[6];
  const float* enc_b2 = (const float*)d_in[7];
  const float* enc_g2 = (const float*)d_in[8];
  const float* enc_bb2= (const float*)d_in[9];
  const float* emb    = (const float*)d_in[10];
  const float* proj_w = (const float*)d_in[11];
  const float* proj_b = (const float*)d_in[12];
  const float* proj_g = (const float*)d_in[13];
  const float* proj_bb= (const float*)d_in[14];
  const float* m_ln_g = (const float*)d_in[15];
  const float* m_ln_b = (const float*)d_in[16];
  const float* m_w_ig = (const float*)d_in[17];
  const float* m_w_dt = (const float*)d_in[18];
  const float* m_b_dt = (const float*)d_in[19];
  const float* m_a_log= (const float*)d_in[20];
  const float* m_w_b  = (const float*)d_in[21];
  const float* m_w_c  = (const float*)d_in[22];
  const float* m_d    = (const float*)d_in[23];
  const float* m_w_out= (const float*)d_in[24];
  const float* fn_g   = (const float*)d_in[25];
  const float* fn_b   = (const float*)d_in[26];
  const float* pol_w1 = (const float*)d_in[27];
  const float* pol_b1 = (const float*)d_in[28];
  const float* pol_g  = (const float*)d_in[29];
  const float* pol_bb = (const float*)d_in[30];
  const float* pol_w2 = (const float*)d_in[31];
  const float* pol_b2 = (const float*)d_in[32];
  const int*   pact   = (const int*)d_in[33];

  float* ws  = (float*)d_ws;
  float* X    = ws;
  float* HLA  = X + (size_t)NTOK*128;
  float* PPA  = HLA + (size_t)BB*SSEG*1024;
  ushort_t* E1 = (ushort_t*)(PPA + (size_t)BB*SSEG*1024);
  // HLB/PPB alias E1 (E1 dead after k_enc2p; HLB first written by scan layer 0,
  // stream-ordered after k_enc2p). 2*BB*SSEG*1024 f32 == NTOK*256 bf16 bytes.
  float* HLB  = (float*)E1;
  float* PPB  = HLB + (size_t)BB*SSEG*1024;
  ushort_t* XINb = E1   + (size_t)NTOK*256;
  ushort_t* Zb   = XINb + (size_t)NTOK*128;
  ushort_t* DTb  = Zb   + (size_t)NTOK*128;
  ushort_t* BTu  = DTb  + (size_t)NTOK*128;
  ushort_t* CTu  = BTu  + (size_t)NTOK*8;

  ushort_t* W1B   = CTu   + (size_t)NTOK*8;
  ushort_t* W2B   = W1B   + 256*128;
  ushort_t* PWB   = W2B   + 128*256;
  ushort_t* WIGB  = PWB   + 128*160;
  ushort_t* WDBCB = WIGB  + 3*256*128;
  ushort_t* WOUTB = WDBCB + 3*144*128;
  ushort_t* PW1B  = WOUTB + 3*128*128;
  ushort_t* PW2B  = PW1B  + 128*128;

  PJobs P;
  int nj = 0;
  auto add = [&](const float* src, ushort_t* dst, int N, int K, int Kpad, int rowofs, int Nw){
    P.j[nj].src = src; P.j[nj].dst = dst; P.j[nj].N = N; P.j[nj].K = K;
    P.j[nj].Kpad = Kpad; P.j[nj].rowofs = rowofs; P.j[nj].Nw = Nw; nj++;
  };
  add(enc_w1, W1B, 256, 115, 128, 0, 256);
  add(enc_w2, W2B, 128, 256, 256, 0, 128);
  add(proj_w, PWB, 128, 144, 160, 0, 128);
  for (int l = 0; l < NLD; l++)
    add(m_w_ig + (size_t)l*256*128, WIGB + (size_t)l*256*128, 256, 128, 128, 0, 256);
  for (int l = 0; l < NLD; l++){
    add(m_w_dt + (size_t)l*128*128, WDBCB + (size_t)l*144*128, 128, 128, 128, 0,   128);
    add(m_w_b  + (size_t)l*8*128,   WDBCB + (size_t)l*144*128,   8, 128, 128, 128,   8);
    add(m_w_c  + (size_t)l*8*128,   WDBCB + (size_t)l*144*128,   8, 128, 128, 136,   8);
  }
  for (int l = 0; l < NLD; l++)
    add(m_w_out + (size_t)l*128*128, WOUTB + (size_t)l*128*128, 128, 128, 128, 0, 128);
  add(pol_w1, PW1B, 128, 128, 128, 0, 128);
  add(pol_w2, PW2B,  19, 128, 128, 0,  32);

  k_prep<<<20*4, 256, 0, stream>>>(P);
  k_enc1<<<NTOK/32, 256, 0, stream>>>(obs, W1B, enc_b1, enc_g1, enc_bb1, E1);
  k_enc2p<<<NTOK/32, 256, 0, stream>>>(E1, W2B, enc_b2, enc_g2, enc_bb2,
      emb, pact, PWB, proj_b, proj_g, proj_bb, X,
      m_ln_g, m_ln_b, WIGB, WDBCB, m_b_dt,
      XINb, Zb, DTb, BTu, CTu,
      m_a_log, HLA, PPA);

  const int carrygrid = BB*1024/256;   // 256 blocks
  const int scangrid  = NTOK/32;       // 1024 blocks x 256 thr

  // layer 0
  k_carry<<<carrygrid, 256, 0, stream>>>(HLA, PPA, h0);
  k_scan2p<<<scangrid, 256, 0, stream>>>(DTb, XINb, Zb, BTu, CTu,
      m_a_log, HLA, m_d, WOUTB, X,
      m_ln_g + 128, m_ln_b + 128,
      WIGB + (size_t)256*128, WDBCB + (size_t)144*128, m_b_dt + 128,
      m_a_log + 1024, HLB, PPB);
  // layer 1
  k_carry<<<carrygrid, 256, 0, stream>>>(HLB, PPB, h0 + (size_t)BB*1024);
  k_scan2p<<<scangrid, 256, 0, stream>>>(DTb, XINb, Zb, BTu, CTu,
      m_a_log + 1024, HLB, m_d + 128, WOUTB + (size_t)128*128, X,
      m_ln_g + 256, m_ln_b + 256,
      WIGB + (size_t)2*256*128, WDBCB + (size_t)2*144*128, m_b_dt + 256,
      m_a_log + 2048, HLA, PPA);
  // layer 2
  k_carry<<<carrygrid, 256, 0, stream>>>(HLA, PPA, h0 + (size_t)2*BB*1024);
  k_scan2h<<<scangrid, 256, 0, stream>>>(DTb, XINb, Zb, BTu, CTu,
      m_a_log + 2048, HLA, m_d + 256, WOUTB + (size_t)2*128*128, X,
      fn_g, fn_b, PW1B, pol_b1, pol_g, pol_bb, PW2B, pol_b2,
      (float*)d_out);
}

// Round 3
// 409.026 us; speedup vs baseline: 1.1413x; 1.0313x over previous
//
#include <hip/hip_runtime.h>
#include <math.h>

#define BB 64
#define TT 512
#define OBSD 115
#define DMD 128
#define DSD 8
#define NLD 3
#define EMBD 16
#define NAD 19
#define H1D 256
#define NTOK (BB*TT)
#define SSEG 32
#define TSEG (TT/SSEG)   // 16

typedef unsigned short ushort_t;
typedef __attribute__((ext_vector_type(8))) short short8;
typedef __attribute__((ext_vector_type(4))) float f32x4;

__device__ __forceinline__ float silu_f(float x){ return x / (1.f + __expf(-x)); }
__device__ __forceinline__ float softplus_f(float x){
  return fmaxf(x, 0.f) + log1pf(__expf(-fabsf(x)));
}
__device__ __forceinline__ ushort_t f2bf(float x){
  unsigned u = __float_as_uint(x);
  unsigned r = (u + 0x7fffu + ((u >> 16) & 1u)) >> 16;
  return (ushort_t)r;
}
__device__ __forceinline__ float b2f(ushort_t x){
  return __uint_as_float(((unsigned)x) << 16);
}
#define MFMA(a,b,c) __builtin_amdgcn_mfma_f32_16x16x32_bf16((a),(b),(c),0,0,0)
#define LOG2E 1.44269504f

// LN stats over 32 tokens, D cols, stride SV floats (SV%32==8 -> conflict-free).
template<int D, int SV>
__device__ __forceinline__ void ln32(const float* s_val, float* s_mr, int tid){
  const int t = tid >> 3, part = tid & 7;
  float s = 0.f, s2 = 0.f;
  #pragma unroll
  for (int j = part; j < D; j += 8){ float v = s_val[t*SV + j]; s += v; s2 = fmaf(v, v, s2); }
  s += __shfl_xor(s, 1, 64); s2 += __shfl_xor(s2, 1, 64);
  s += __shfl_xor(s, 2, 64); s2 += __shfl_xor(s2, 2, 64);
  s += __shfl_xor(s, 4, 64); s2 += __shfl_xor(s2, 4, 64);
  if (part == 0){
    float m = s * (1.f/(float)D);
    s_mr[t*2] = m;
    s_mr[t*2+1] = rsqrtf(s2 * (1.f/(float)D) - m*m + 1e-5f);
  }
}

// ---------------- k_prep ----------------
struct PJob { const float* src; ushort_t* dst; int N; int K; int Kpad; int rowofs; int Nw; };
struct PJobs { PJob j[20]; };

__global__ __launch_bounds__(256) void k_prep(PJobs P){
  const int job = blockIdx.x >> 2;
  const int sub = blockIdx.x & 3;
  PJob pj = P.j[job];
  const int elems = pj.Nw * pj.Kpad;
  for (int idx = sub*256 + threadIdx.x; idx < elems; idx += 4*256){
    int n = idx / pj.Kpad;
    int k = idx - n*pj.Kpad;
    float v = (n < pj.N && k < pj.K) ? pj.src[(size_t)n*pj.K + k] : 0.f;
    pj.dst[(size_t)(pj.rowofs + n)*pj.Kpad + k] = f2bf(v);
  }
}

// ======== k_enc12p: enc1+enc2+proj+LN(l0)+wig/wdbc(l0)+phaseA(l0), 32 tok/block ========
// LDS layout (bytes):
//  [0,17408)     : s_val f32 32x136  (GEMM2/proj/silu-x; also s_obs bf16 32x136 [0,8704) early,
//                  s_xin bf16 [0,8704) late, s_dt bf16 [8704,17408) late)
//  [17408,34304) : s_e1 bf16 32x264 (16896) ; later s_a2 bf16 32x168 (10752) at [17408,28160)
//  [34304,34816) : s_stats float2[32][2]
//  [34816,35328) : s_btc 32x8 bf16
//  [35328,35584) : s_mr
__global__ __launch_bounds__(256) void k_enc12p(
    const float* __restrict__ obs, const ushort_t* __restrict__ w1b,
    const float* __restrict__ b1, const float* __restrict__ g1,
    const float* __restrict__ bb1,
    const ushort_t* __restrict__ w2b,
    const float* __restrict__ b2, const float* __restrict__ g2,
    const float* __restrict__ bb2,
    const float* __restrict__ emb, const int* __restrict__ pact,
    const ushort_t* __restrict__ pwb, const float* __restrict__ pb,
    const float* __restrict__ pg, const float* __restrict__ pbb,
    float* __restrict__ X,
    const float* __restrict__ lng, const float* __restrict__ lnb,
    const ushort_t* __restrict__ wigb, const ushort_t* __restrict__ wdbcb,
    const float* __restrict__ bdt,
    ushort_t* __restrict__ XINb, ushort_t* __restrict__ Zb,
    ushort_t* __restrict__ DTb, ushort_t* __restrict__ BTu, ushort_t* __restrict__ CTu,
    const float* __restrict__ alog0,
    float* __restrict__ HLOC, float* __restrict__ PPR)
{
  __shared__ __align__(16) char sm[35584];
  float*    s_val  = (float*)sm;
  ushort_t* s_obs  = (ushort_t*)sm;
  ushort_t* s_xin  = (ushort_t*)sm;
  ushort_t* s_dt   = (ushort_t*)(sm + 8704);
  ushort_t* s_e1   = (ushort_t*)(sm + 17408);
  ushort_t* s_a2   = (ushort_t*)(sm + 17408);
  float2*   s_st   = (float2*)(sm + 34304);
  ushort_t* s_btc  = (ushort_t*)(sm + 34816);
  float*    s_mr   = (float*)(sm + 35328);

  const int tok0 = blockIdx.x * 32;
  const int bidx = blockIdx.x >> 4;
  const int ch   = blockIdx.x & 15;
  const int tid = threadIdx.x;
  const int lane = tid & 63, w = tid >> 6;
  const int q = lane >> 4, cn = lane & 15;
  const int m0 = (w & 1) * 16, nh = w >> 1;

  // -- stage obs -> s_obs bf16 (pad 115 -> 128) --
  for (int e = tid; e < 32*16; e += 256){
    int t = e >> 4, kc = e & 15;
    const float* op = obs + (size_t)(tok0 + t)*OBSD;
    short8 v;
    #pragma unroll
    for (int j = 0; j < 8; j++){
      int k = kc*8 + j;
      v[j] = (short)f2bf(k < OBSD ? op[k] : 0.f);
    }
    *(short8*)&s_obs[t*136 + kc*8] = v;
  }
  __syncthreads();

  // -- GEMM1 (obs @ w1.T + b1), acc in registers --
  f32x4 acc[8];
  {
    short8 af[4];
    #pragma unroll
    for (int ks = 0; ks < 4; ks++)
      af[ks] = *(const short8*)&s_obs[(m0 + cn)*136 + ks*32 + q*8];
    #pragma unroll
    for (int nt = 0; nt < 8; nt++){
      const int n0 = (nh*8 + nt) * 16;
      f32x4 a = {0.f,0.f,0.f,0.f};
      #pragma unroll
      for (int ks = 0; ks < 4; ks++){
        short8 bf = *(const short8*)&w1b[(size_t)(n0 + cn)*128 + ks*32 + q*8];
        a = MFMA(af[ks], bf, a);
      }
      float bv = b1[n0 + cn];
      #pragma unroll
      for (int r = 0; r < 4; r++) a[r] += bv;
      acc[nt] = a;
    }
  }

  // -- register LN stats over 256 cols (this warp holds 128; combine 2 warps via s_st) --
  {
    #pragma unroll
    for (int r = 0; r < 4; r++){
      float s = 0.f, s2 = 0.f;
      #pragma unroll
      for (int nt = 0; nt < 8; nt++){ float v = acc[nt][r]; s += v; s2 = fmaf(v, v, s2); }
      s += __shfl_xor(s, 1, 64); s2 += __shfl_xor(s2, 1, 64);
      s += __shfl_xor(s, 2, 64); s2 += __shfl_xor(s2, 2, 64);
      s += __shfl_xor(s, 4, 64); s2 += __shfl_xor(s2, 4, 64);
      s += __shfl_xor(s, 8, 64); s2 += __shfl_xor(s2, 8, 64);
      if (cn == 0) s_st[(m0 + q*4 + r)*2 + nh] = make_float2(s, s2);
    }
  }
  __syncthreads();

  // -- normalize + silu -> s_e1 bf16 --
  {
    float mu[4], rs[4];
    #pragma unroll
    for (int r = 0; r < 4; r++){
      const int row = m0 + q*4 + r;
      float2 p0 = s_st[row*2 + 0], p1 = s_st[row*2 + 1];
      float s = p0.x + p1.x, s2 = p0.y + p1.y;
      float m = s * (1.f/256.f);
      mu[r] = m;
      rs[r] = rsqrtf(s2 * (1.f/256.f) - m*m + 1e-5f);
    }
    #pragma unroll
    for (int nt = 0; nt < 8; nt++){
      const int col = (nh*8 + nt)*16 + cn;
      float gg = g1[col], bbv = bb1[col];
      #pragma unroll
      for (int r = 0; r < 4; r++){
        float v = (acc[nt][r] - mu[r]) * rs[r] * gg + bbv;
        s_e1[(m0 + q*4 + r)*264 + col] = f2bf(silu_f(v));
      }
    }
  }
  __syncthreads();

  // -- GEMM2 (e1 @ w2.T + b2) -> s_val --
  {
    short8 af2[8];
    #pragma unroll
    for (int ks = 0; ks < 8; ks++)
      af2[ks] = *(const short8*)&s_e1[(m0 + cn)*264 + ks*32 + q*8];
    __syncthreads();   // s_e1 dead; s_a2 emb region may be written

    // stage emb -> s_a2 cols [128,160)
    for (int e = tid; e < 32*32; e += 256){
      int t = e >> 5, k = e & 31;
      float v = 0.f;
      if (k < EMBD){ int a = pact[tok0 + t]; v = emb[(size_t)a*EMBD + k]; }
      s_a2[t*168 + 128 + k] = f2bf(v);
    }

    #pragma unroll
    for (int nt = 0; nt < 4; nt++){
      const int n0 = (nh*4 + nt) * 16;
      f32x4 a = {0.f,0.f,0.f,0.f};
      #pragma unroll
      for (int ks = 0; ks < 8; ks++){
        short8 bf = *(const short8*)&w2b[(size_t)(n0 + cn)*256 + ks*32 + q*8];
        a = MFMA(af2[ks], bf, a);
      }
      float bias = b2[n0 + cn];
      #pragma unroll
      for (int r = 0; r < 4; r++)
        s_val[(m0 + q*4 + r)*136 + n0 + cn] = a[r] + bias;
    }
  }
  __syncthreads();

  ln32<128,136>(s_val, s_mr, tid);
  __syncthreads();
  for (int e = tid; e < 32*128; e += 256){
    int t = e >> 7, c = e & 127;
    float v = (s_val[t*136 + c] - s_mr[t*2]) * s_mr[t*2+1] * g2[c] + bb2[c];
    s_a2[t*168 + c] = f2bf(v);
  }
  __syncthreads();

  // -- proj GEMM (concat(e2,pa) @ proj_w.T + pb) -> s_val --
  {
    short8 af3[5];
    #pragma unroll
    for (int ks = 0; ks < 5; ks++)
      af3[ks] = *(const short8*)&s_a2[(m0 + cn)*168 + ks*32 + q*8];
    #pragma unroll
    for (int nt = 0; nt < 4; nt++){
      const int n0 = (nh*4 + nt) * 16;
      f32x4 a = {0.f,0.f,0.f,0.f};
      #pragma unroll
      for (int ks = 0; ks < 5; ks++){
        short8 bf = *(const short8*)&pwb[(size_t)(n0 + cn)*160 + ks*32 + q*8];
        a = MFMA(af3[ks], bf, a);
      }
      float bias = pb[n0 + cn];
      #pragma unroll
      for (int r = 0; r < 4; r++)
        s_val[(m0 + q*4 + r)*136 + n0 + cn] = a[r] + bias;
    }
  }
  __syncthreads();

  ln32<128,136>(s_val, s_mr, tid);
  __syncthreads();
  for (int e = tid; e < 32*128; e += 256){
    int t = e >> 7, c = e & 127;
    float v = (s_val[t*136 + c] - s_mr[t*2]) * s_mr[t*2+1] * pg[c] + pbb[c];
    v = silu_f(v);
    X[(size_t)tok0*128 + e] = v;
    s_val[t*136 + c] = v;
  }
  __syncthreads();

  ln32<128,136>(s_val, s_mr, tid);
  __syncthreads();
  for (int e = tid; e < 32*128; e += 256){
    int t = e >> 7, c = e & 127;
    float v = (s_val[t*136 + c] - s_mr[t*2]) * s_mr[t*2+1] * lng[c] + lnb[c];
    s_a2[t*168 + c] = f2bf(v);
  }
  __syncthreads();   // s_val DEAD; s_xin/s_dt may be written

  // -- wig GEMM --
  {
    short8 af[4];
    #pragma unroll
    for (int ks = 0; ks < 4; ks++)
      af[ks] = *(const short8*)&s_a2[(m0 + cn)*168 + ks*32 + q*8];
    #pragma unroll
    for (int nt = 0; nt < 8; nt++){
      const int n0 = (nh*8 + nt) * 16;
      f32x4 a = {0.f,0.f,0.f,0.f};
      #pragma unroll
      for (int ks = 0; ks < 4; ks++){
        short8 bf = *(const short8*)&wigb[(size_t)(n0 + cn)*128 + ks*32 + q*8];
        a = MFMA(af[ks], bf, a);
      }
      if (n0 < 128){
        #pragma unroll
        for (int r = 0; r < 4; r++){
          int tr = m0 + q*4 + r;
          ushort_t bb = f2bf(a[r]);
          XINb[(size_t)(tok0 + tr)*128 + n0 + cn] = bb;
          s_xin[tr*136 + n0 + cn] = bb;
        }
      } else {
        #pragma unroll
        for (int r = 0; r < 4; r++){
          int tr = m0 + q*4 + r;
          Zb[(size_t)(tok0 + tr)*128 + (n0 - 128) + cn] = f2bf(a[r]);
        }
      }
    }
  }
  __syncthreads();

  // -- wdbc GEMM (fills s_dt / s_btc) --
  {
    short8 af2[4];
    #pragma unroll
    for (int ks = 0; ks < 4; ks++)
      af2[ks] = *(const short8*)&s_xin[(m0 + cn)*136 + ks*32 + q*8];
    for (int nt = nh; nt < 9; nt += 2){
      const int n0 = nt * 16;
      f32x4 a = {0.f,0.f,0.f,0.f};
      #pragma unroll
      for (int ks = 0; ks < 4; ks++){
        short8 bf = *(const short8*)&wdbcb[(size_t)(n0 + cn)*128 + ks*32 + q*8];
        a = MFMA(af2[ks], bf, a);
      }
      const int col = n0 + cn;
      if (col < 128){
        float bd = bdt[col];
        #pragma unroll
        for (int r = 0; r < 4; r++){
          int tr = m0 + q*4 + r;
          ushort_t dv = f2bf(softplus_f(a[r] + bd));
          DTb[(size_t)(tok0 + tr)*128 + col] = dv;
          s_dt[tr*136 + col] = dv;
        }
      } else if (col < 136){
        #pragma unroll
        for (int r = 0; r < 4; r++){
          int tr = m0 + q*4 + r;
          ushort_t bb = f2bf(a[r]);
          BTu[(size_t)(tok0 + tr)*8 + (col - 128)] = bb;
          s_btc[tr*8 + (col - 128)] = bb;
        }
      } else {
        #pragma unroll
        for (int r = 0; r < 4; r++)
          CTu[(size_t)(tok0 + m0 + q*4 + r)*8 + (col - 136)] = f2bf(a[r]);
      }
    }
  }
  __syncthreads();

  // -- phase A (layer 0): two 16-token chunks, thread=(d, half) --
  {
    const int d = tid & 127, half = tid >> 7;
    float A2c[8], hh[8], pp[8];
    #pragma unroll
    for (int s = 0; s < 8; s++){
      A2c[s] = -__expf(alog0[d*8 + s]) * LOG2E;
      hh[s] = 0.f; pp[s] = 1.f;
    }
    const int t0 = half * 16;
    #pragma unroll 4
    for (int tt = 0; tt < 16; tt++){
      const int t = t0 + tt;
      float dt = b2f(s_dt[t*136 + d]);
      float wv = dt * b2f(s_xin[t*136 + d]);
      #pragma unroll
      for (int s = 0; s < 8; s++){
        float dA = exp2f(dt * A2c[s]);
        hh[s] = fmaf(dA, hh[s], wv * b2f(s_btc[t*8 + s]));
        pp[s] *= dA;
      }
    }
    const size_t o = ((size_t)bidx*SSEG + ch*2 + half)*1024 + d*8;
    #pragma unroll
    for (int s = 0; s < 8; s++){ HLOC[o+s] = hh[s]; PPR[o+s] = pp[s]; }
  }
}

// ---- k_carry: HL[b,ch] := exclusive prefix (in place); prefetch-all then chain ----
__global__ __launch_bounds__(256) void k_carry(
    float* __restrict__ HL, const float* __restrict__ PP,
    const float* __restrict__ h0g)
{
  const int idx = blockIdx.x*256 + threadIdx.x;
  const size_t base = (size_t)(idx >> 10) * (SSEG*1024) + (idx & 1023);
  float hl[SSEG], pp[SSEG];
  #pragma unroll
  for (int ch = 0; ch < SSEG; ch++){
    hl[ch] = HL[base + (size_t)ch*1024];
    pp[ch] = PP[base + (size_t)ch*1024];
  }
  float h = h0g[idx];
  #pragma unroll
  for (int ch = 0; ch < SSEG; ch++){
    HL[base + (size_t)ch*1024] = h;
    h = fmaf(pp[ch], h, hl[ch]);
  }
}

// ======== block-wide phase B over 32 tokens (2 chunks) + wout + residual + LN stats ====
// LDS layout (bytes) — s_a DISJOINT from s_x:
//  [0,16640)     : s_x f32 32x130 ; aliases s_dtS [0,8192) + s_xiS [8192,16384)
//                  s_xin bf16 32x136 aliases [0,8704) ; s_dt2 bf16 at [8704,17408)
//  [16640,25344) : s_a bf16 32x136
//  [25344,25856) : s_bt ; [25856,26368): s_ct ; [26368,26624): s_mr
#define SMB 26624

__device__ __forceinline__ void phaseB32(
    const ushort_t* DTb, const ushort_t* XINb, const ushort_t* Zb,
    const ushort_t* BTu, const ushort_t* CTu,
    const float* __restrict__ alog, const float* __restrict__ HLpre,
    const float* __restrict__ dpar, const ushort_t* __restrict__ woutb,
    float* __restrict__ X, char* sm, int b, int pair, int tid)
{
  ushort_t* s_dtS = (ushort_t*)sm;
  ushort_t* s_xiS = (ushort_t*)(sm + 8192);
  float*    s_x   = (float*)sm;
  ushort_t* s_a   = (ushort_t*)(sm + 16640);
  ushort_t* s_bt  = (ushort_t*)(sm + 25344);
  ushort_t* s_ct  = (ushort_t*)(sm + 25856);
  float*    s_mr  = (float*)(sm + 26368);

  const int lane = tid & 63, w = tid >> 6, q = lane >> 4, cn = lane & 15;
  const int m0 = (w & 1) * 16, nh = w >> 1;
  const int d = tid & 127, half = tid >> 7;
  const size_t segtok = (size_t)b*TT + pair*32;

  // stage 32 tokens of dt/xin/bt/ct
  {
    const uint4* gdt = (const uint4*)(DTb + segtok*128);
    const uint4* gxi = (const uint4*)(XINb + segtok*128);
    #pragma unroll
    for (int i = 0; i < 2; i++){
      ((uint4*)s_dtS)[tid + i*256] = gdt[tid + i*256];
      ((uint4*)s_xiS)[tid + i*256] = gxi[tid + i*256];
    }
    if (tid < 128){
      ((unsigned*)s_bt)[tid] = ((const unsigned*)(BTu + segtok*8))[tid];
      ((unsigned*)s_ct)[tid] = ((const unsigned*)(CTu + segtok*8))[tid];
    }
  }
  float A2[8], h[8];
  {
    const size_t o = ((size_t)b*SSEG + pair*2 + half)*1024 + d*8;
    float4 h0v = *(const float4*)(HLpre + o);
    float4 h1v = *(const float4*)(HLpre + o + 4);
    h[0]=h0v.x; h[1]=h0v.y; h[2]=h0v.z; h[3]=h0v.w;
    h[4]=h1v.x; h[5]=h1v.y; h[6]=h1v.z; h[7]=h1v.w;
    #pragma unroll
    for (int s = 0; s < 8; s++) A2[s] = -__expf(alog[d*8 + s]) * LOG2E;
  }
  __syncthreads();

  // scan: thread=(d,half) over its 16 tokens; y -> s_a
  #pragma unroll 4
  for (int tt = 0; tt < 16; tt++){
    const int t = half*16 + tt;
    float dt = b2f(s_dtS[t*128 + d]);
    float xi = b2f(s_xiS[t*128 + d]);
    float wv = dt * xi;
    float y = 0.f;
    #pragma unroll
    for (int s = 0; s < 8; s++){
      float dA = exp2f(dt * A2[s]);
      h[s] = fmaf(dA, h[s], wv * b2f(s_bt[t*8 + s]));
      y = fmaf(h[s], b2f(s_ct[t*8 + s]), y);
    }
    s_a[t*136 + d] = f2bf(y);
  }
  __syncthreads();

  // z-apply: ssm = y*silu(z) + xi*dp  (256 thr over 32 tokens)
  {
    const int c0 = (tid & 15)*8, trow = tid >> 4;
    float dpv[8];
    #pragma unroll
    for (int j = 0; j < 8; j++) dpv[j] = dpar[c0 + j];
    #pragma unroll
    for (int i = 0; i < 2; i++){
      const int t = trow + i*16;
      uint4 zb = ((const uint4*)(Zb + segtok*128))[tid + i*256];
      const ushort_t* zp = (const ushort_t*)&zb;
      #pragma unroll
      for (int j = 0; j < 8; j++){
        float y  = b2f(s_a[t*136 + c0 + j]);
        float xi = b2f(s_xiS[t*128 + c0 + j]);
        float ssm = y * silu_f(b2f(zp[j])) + xi * dpv[j];
        s_a[t*136 + c0 + j] = f2bf(ssm);
      }
    }
  }
  __syncthreads();   // staging dead; s_x writable (s_a disjoint)

  // wout GEMM (M=32, block-wide) + residual -> s_x + X
  {
    short8 af[4];
    #pragma unroll
    for (int ks = 0; ks < 4; ks++)
      af[ks] = *(const short8*)&s_a[(m0 + cn)*136 + ks*32 + q*8];
    #pragma unroll
    for (int i = 0; i < 4; i++){
      const int n0 = (nh*4 + i) * 16;
      short8 bf[4];
      #pragma unroll
      for (int ks = 0; ks < 4; ks++)
        bf[ks] = *(const short8*)&woutb[(size_t)(n0+cn)*128 + ks*32 + q*8];
      f32x4 acc = {0.f,0.f,0.f,0.f};
      #pragma unroll
      for (int ks = 0; ks < 4; ks++) acc = MFMA(af[ks], bf[ks], acc);
      #pragma unroll
      for (int r = 0; r < 4; r++){
        const int tr = m0 + q*4 + r;
        const size_t g = (segtok + tr)*128 + n0 + cn;
        float xn = X[g] + acc[r];
        X[g] = xn;
        s_x[tr*130 + n0 + cn] = xn;
      }
    }
  }
  __syncthreads();

  // LN stats (8 thr/token over 32 tokens)
  {
    const int t = tid >> 3, part = tid & 7;
    float s = 0.f, s2 = 0.f;
    const float* row = s_x + t*130 + part*16;
    #pragma unroll
    for (int j = 0; j < 16; j++){ float v = row[j]; s += v; s2 = fmaf(v, v, s2); }
    s  += __shfl_xor(s, 1, 64);  s2 += __shfl_xor(s2, 1, 64);
    s  += __shfl_xor(s, 2, 64);  s2 += __shfl_xor(s2, 2, 64);
    s  += __shfl_xor(s, 4, 64);  s2 += __shfl_xor(s2, 4, 64);
    if (part == 0){
      float m = s * (1.f/128.f);
      s_mr[t*2] = m;
      s_mr[t*2+1] = rsqrtf(s2 * (1.f/128.f) - m*m + 1e-5f);
    }
  }
  __syncthreads();
}

// ---- k_scan2p: 32-token block; phaseB+post, LN, wig, wdbc, phaseA(next) ----
__global__ __launch_bounds__(256, 4) void k_scan2p(
    ushort_t* DTb, ushort_t* XINb, ushort_t* Zb,
    ushort_t* BTu, ushort_t* CTu,
    const float* __restrict__ alog, const float* __restrict__ HLpre,
    const float* __restrict__ dpar, const ushort_t* __restrict__ woutb,
    float* __restrict__ X,
    const float* __restrict__ lng, const float* __restrict__ lnb,
    const ushort_t* __restrict__ wigb, const ushort_t* __restrict__ wdbcb,
    const float* __restrict__ bdt,
    const float* __restrict__ alogn,
    float* __restrict__ HLo, float* __restrict__ PPo)
{
  __shared__ __align__(16) char sm[SMB];
  const int tid = threadIdx.x;
  float*    s_x   = (float*)sm;
  ushort_t* s_xin = (ushort_t*)sm;
  ushort_t* s_dt2 = (ushort_t*)(sm + 8704);
  ushort_t* s_a   = (ushort_t*)(sm + 16640);
  ushort_t* s_btc = (ushort_t*)(sm + 25344);
  float*    s_mr  = (float*)(sm + 26368);

  const int b = blockIdx.x >> 4;
  const int pair = blockIdx.x & 15;
  const int lane = tid & 63, w = tid >> 6, q = lane >> 4, cn = lane & 15;
  const int m0 = (w & 1) * 16, nh = w >> 1;
  const int d = tid & 127, half = tid >> 7;
  const size_t segtok = (size_t)b*TT + pair*32;

  phaseB32(DTb, XINb, Zb, BTu, CTu, alog, HLpre, dpar, woutb, X, sm, b, pair, tid);

  // normalize -> s_a (disjoint from s_x)
  {
    float g = lng[d], c0v = lnb[d];
    #pragma unroll
    for (int tt = 0; tt < 16; tt++){
      const int t = half*16 + tt;
      float v = (s_x[t*130 + d] - s_mr[t*2]) * s_mr[t*2+1] * g + c0v;
      s_a[t*136 + d] = f2bf(v);
    }
  }
  __syncthreads();

  // wig GEMM (M=32, N=256); writes s_xin (aliases dead s_x) + XINb/Zb
  {
    short8 af[4];
    #pragma unroll
    for (int ks = 0; ks < 4; ks++)
      af[ks] = *(const short8*)&s_a[(m0 + cn)*136 + ks*32 + q*8];
    #pragma unroll
    for (int i = 0; i < 8; i++){
      const int n0 = (nh*8 + i) * 16;
      short8 bf[4];
      #pragma unroll
      for (int ks = 0; ks < 4; ks++)
        bf[ks] = *(const short8*)&wigb[(size_t)(n0+cn)*128 + ks*32 + q*8];
      f32x4 acc = {0.f,0.f,0.f,0.f};
      #pragma unroll
      for (int ks = 0; ks < 4; ks++) acc = MFMA(af[ks], bf[ks], acc);
      if (n0 < 128){
        #pragma unroll
        for (int r = 0; r < 4; r++){
          const int tr = m0 + q*4 + r;
          ushort_t bb = f2bf(acc[r]);
          XINb[(segtok + tr)*128 + n0 + cn] = bb;
          s_xin[tr*136 + n0 + cn] = bb;
        }
      } else {
        #pragma unroll
        for (int r = 0; r < 4; r++){
          const int tr = m0 + q*4 + r;
          Zb[(segtok + tr)*128 + (n0-128) + cn] = f2bf(acc[r]);
        }
      }
    }
  }
  __syncthreads();

  // wdbc GEMM (M=32, N=144); fills s_dt2 / s_btc  (s_dt2 tail clobbers dead s_a head)
  {
    short8 af2[4];
    #pragma unroll
    for (int ks = 0; ks < 4; ks++)
      af2[ks] = *(const short8*)&s_xin[(m0 + cn)*136 + ks*32 + q*8];
    for (int nt = nh; nt < 9; nt += 2){
      const int n0 = nt * 16;
      short8 bf[4];
      #pragma unroll
      for (int ks = 0; ks < 4; ks++)
        bf[ks] = *(const short8*)&wdbcb[(size_t)(n0+cn)*128 + ks*32 + q*8];
      f32x4 acc = {0.f,0.f,0.f,0.f};
      #pragma unroll
      for (int ks = 0; ks < 4; ks++) acc = MFMA(af2[ks], bf[ks], acc);
      const int col = n0 + cn;
      if (col < 128){
        float bd = bdt[col];
        #pragma unroll
        for (int r = 0; r < 4; r++){
          const int tr = m0 + q*4 + r;
          ushort_t dv = f2bf(softplus_f(acc[r] + bd));
          DTb[(segtok + tr)*128 + col] = dv;
          s_dt2[tr*136 + col] = dv;
        }
      } else if (col < 136){
        #pragma unroll
        for (int r = 0; r < 4; r++){
          const int tr = m0 + q*4 + r;
          ushort_t bb = f2bf(acc[r]);
          BTu[(segtok + tr)*8 + (col-128)] = bb;
          s_btc[tr*8 + (col-128)] = bb;
        }
      } else {
        #pragma unroll
        for (int r = 0; r < 4; r++)
          CTu[(segtok + m0 + q*4 + r)*8 + (col-136)] = f2bf(acc[r]);
      }
    }
  }
  __syncthreads();

  // phase A (next layer): thread=(d,half) over its 16 tokens
  {
    float A2n[8], hh[8], pp[8];
    #pragma unroll
    for (int s = 0; s < 8; s++){
      A2n[s] = -__expf(alogn[d*8 + s]) * LOG2E;
      hh[s] = 0.f; pp[s] = 1.f;
    }
    #pragma unroll 4
    for (int tt = 0; tt < 16; tt++){
      const int t = half*16 + tt;
      float dt = b2f(s_dt2[t*136 + d]);
      float wv = dt * b2f(s_xin[t*136 + d]);
      #pragma unroll
      for (int s = 0; s < 8; s++){
        float dA = exp2f(dt * A2n[s]);
        hh[s] = fmaf(dA, hh[s], wv * b2f(s_btc[t*8 + s]));
        pp[s] *= dA;
      }
    }
    const size_t o = ((size_t)b*SSEG + pair*2 + half)*1024 + d*8;
    #pragma unroll
    for (int s = 0; s < 8; s++){ HLo[o+s] = hh[s]; PPo[o+s] = pp[s]; }
  }
}

// ---- k_scan2h: 32-token block; phaseB+post, LNfn, pw1, LN, silu, pw2 ----
__global__ __launch_bounds__(256, 4) void k_scan2h(
    const ushort_t* DTb, const ushort_t* XINb, const ushort_t* Zb,
    const ushort_t* BTu, const ushort_t* CTu,
    const float* __restrict__ alog, const float* __restrict__ HLpre,
    const float* __restrict__ dpar, const ushort_t* __restrict__ woutb,
    float* __restrict__ X,
    const float* __restrict__ fng, const float* __restrict__ fnb,
    const ushort_t* __restrict__ pw1b, const float* __restrict__ pb1,
    const float* __restrict__ pg, const float* __restrict__ pbb,
    const ushort_t* __restrict__ pw2b, const float* __restrict__ pb2,
    float* __restrict__ out)
{
  __shared__ __align__(16) char sm[SMB];
  const int tid = threadIdx.x;
  float*    s_x  = (float*)sm;
  ushort_t* s_a  = (ushort_t*)(sm + 16640);
  float*    s_mr = (float*)(sm + 26368);

  const int b = blockIdx.x >> 4;
  const int pair = blockIdx.x & 15;
  const int lane = tid & 63, w = tid >> 6, q = lane >> 4, cn = lane & 15;
  const int m0 = (w & 1) * 16, nh = w >> 1;
  const int d = tid & 127, half = tid >> 7;
  const size_t segtok = (size_t)b*TT + pair*32;

  phaseB32((ushort_t*)DTb, (ushort_t*)XINb, (ushort_t*)Zb,
           (ushort_t*)BTu, (ushort_t*)CTu, alog, HLpre,
           dpar, woutb, X, sm, b, pair, tid);

  // LN_fn -> s_a
  {
    float g = fng[d], c0v = fnb[d];
    #pragma unroll
    for (int tt = 0; tt < 16; tt++){
      const int t = half*16 + tt;
      float v = (s_x[t*130 + d] - s_mr[t*2]) * s_mr[t*2+1] * g + c0v;
      s_a[t*136 + d] = f2bf(v);
    }
  }
  __syncthreads();

  // pw1 GEMM (M=32, N=128) -> s_x (+bias); s_a disjoint
  {
    short8 af[4];
    #pragma unroll
    for (int ks = 0; ks < 4; ks++)
      af[ks] = *(const short8*)&s_a[(m0 + cn)*136 + ks*32 + q*8];
    #pragma unroll
    for (int i = 0; i < 4; i++){
      const int n0 = (nh*4 + i) * 16;
      short8 bf[4];
      #pragma unroll
      for (int ks = 0; ks < 4; ks++)
        bf[ks] = *(const short8*)&pw1b[(size_t)(n0+cn)*128 + ks*32 + q*8];
      float bias = pb1[n0 + cn];
      f32x4 acc = {0.f,0.f,0.f,0.f};
      #pragma unroll
      for (int ks = 0; ks < 4; ks++) acc = MFMA(af[ks], bf[ks], acc);
      #pragma unroll
      for (int r = 0; r < 4; r++)
        s_x[(m0 + q*4 + r)*130 + n0 + cn] = acc[r] + bias;
    }
  }
  __syncthreads();

  // LN stats (8 thr/token)
  {
    const int t = tid >> 3, part = tid & 7;
    float s = 0.f, s2 = 0.f;
    const float* row = s_x + t*130 + part*16;
    #pragma unroll
    for (int j = 0; j < 16; j++){ float v = row[j]; s += v; s2 = fmaf(v, v, s2); }
    s  += __shfl_xor(s, 1, 64);  s2 += __shfl_xor(s2, 1, 64);
    s  += __shfl_xor(s, 2, 64);  s2 += __shfl_xor(s2, 2, 64);
    s  += __shfl_xor(s, 4, 64);  s2 += __shfl_xor(s2, 4, 64);
    if (part == 0){
      float m = s * (1.f/128.f);
      s_mr[t*2] = m;
      s_mr[t*2+1] = rsqrtf(s2 * (1.f/128.f) - m*m + 1e-5f);
    }
  }
  __syncthreads();

  // silu(LN) -> s_a
  {
    float g = pg[d], c0v = pbb[d];
    #pragma unroll
    for (int tt = 0; tt < 16; tt++){
      const int t = half*16 + tt;
      float v = (s_x[t*130 + d] - s_mr[t*2]) * s_mr[t*2+1] * g + c0v;
      s_a[t*136 + d] = f2bf(silu_f(v));
    }
  }
  __syncthreads();

  // pw2 GEMM (M=32, N=32; cols<19 stored)
  {
    short8 af[4];
    #pragma unroll
    for (int ks = 0; ks < 4; ks++)
      af[ks] = *(const short8*)&s_a[(m0 + cn)*136 + ks*32 + q*8];
    const int n0 = (w >> 1) * 16;
    short8 bf[4];
    #pragma unroll
    for (int ks = 0; ks < 4; ks++)
      bf[ks] = *(const short8*)&pw2b[(size_t)(n0+cn)*128 + ks*32 + q*8];
    const int col = n0 + cn;
    f32x4 acc = {0.f,0.f,0.f,0.f};
    #pragma unroll
    for (int ks = 0; ks < 4; ks++) acc = MFMA(af[ks], bf[ks], acc);
    if (col < NAD){
      float bias = pb2[col];
      #pragma unroll
      for (int r = 0; r < 4; r++)
        out[(segtok + m0 + q*4 + r)*NAD + col] = acc[r] + bias;
    }
  }
}

extern "C" void kernel_launch(void* const* d_in, const int* in_sizes, int n_in,
                              void* d_out, int out_size, void* d_ws, size_t ws_size,
                              hipStream_t stream) {
  const float* obs    = (const float*)d_in[0];
  const float* h0     = (const float*)d_in[1];
  const float* enc_w1 = (const float*)d_in[2];
  const float* enc_b1 = (const float*)d_in[3];
  const float* enc_g1 = (const float*)d_in[4];
  const float* enc_bb1= (const float*)d_in[5];
  const float* enc_w2 = (const float*)d_in[6];
  const float* enc_b2 = (const float*)d_in[7];
  const float* enc_g2 = (const float*)d_in[8];
  const float* enc_bb2= (const float*)d_in[9];
  const float* emb    = (const float*)d_in[10];
  const float* proj_w = (const float*)d_in[11];
  const float* proj_b = (const float*)d_in[12];
  const float* proj_g = (const float*)d_in[13];
  const float* proj_bb= (const float*)d_in[14];
  const float* m_ln_g = (const float*)d_in[15];
  const float* m_ln_b = (const float*)d_in[16];
  const float* m_w_ig = (const float*)d_in[17];
  const float* m_w_dt = (const float*)d_in[18];
  const float* m_b_dt = (const float*)d_in[19];
  const float* m_a_log= (const float*)d_in[20];
  const float* m_w_b  = (const float*)d_in[21];
  const float* m_w_c  = (const float*)d_in[22];
  const float* m_d    = (const float*)d_in[23];
  const float* m_w_out= (const float*)d_in[24];
  const float* fn_g   = (const float*)d_in[25];
  const float* fn_b   = (const float*)d_in[26];
  const float* pol_w1 = (const float*)d_in[27];
  const float* pol_b1 = (const float*)d_in[28];
  const float* pol_g  = (const float*)d_in[29];
  const float* pol_bb = (const float*)d_in[30];
  const float* pol_w2 = (const float*)d_in[31];
  const float* pol_b2 = (const float*)d_in[32];
  const int*   pact   = (const int*)d_in[33];

  float* ws  = (float*)d_ws;
  float* X    = ws;
  float* HLA  = X + (size_t)NTOK*128;
  float* PPA  = HLA + (size_t)BB*SSEG*1024;
  float* HLB  = PPA + (size_t)BB*SSEG*1024;
  float* PPB  = HLB + (size_t)BB*SSEG*1024;
  ushort_t* XINb = (ushort_t*)(PPB + (size_t)BB*SSEG*1024);
  ushort_t* Zb   = XINb + (size_t)NTOK*128;
  ushort_t* DTb  = Zb   + (size_t)NTOK*128;
  ushort_t* BTu  = DTb  + (size_t)NTOK*128;
  ushort_t* CTu  = BTu  + (size_t)NTOK*8;

  ushort_t* W1B   = CTu   + (size_t)NTOK*8;
  ushort_t* W2B   = W1B   + 256*128;
  ushort_t* PWB   = W2B   + 128*256;
  ushort_t* WIGB  = PWB   + 128*160;
  ushort_t* WDBCB = WIGB  + 3*256*128;
  ushort_t* WOUTB = WDBCB + 3*144*128;
  ushort_t* PW1B  = WOUTB + 3*128*128;
  ushort_t* PW2B  = PW1B  + 128*128;

  PJobs P;
  int nj = 0;
  auto add = [&](const float* src, ushort_t* dst, int N, int K, int Kpad, int rowofs, int Nw){
    P.j[nj].src = src; P.j[nj].dst = dst; P.j[nj].N = N; P.j[nj].K = K;
    P.j[nj].Kpad = Kpad; P.j[nj].rowofs = rowofs; P.j[nj].Nw = Nw; nj++;
  };
  add(enc_w1, W1B, 256, 115, 128, 0, 256);
  add(enc_w2, W2B, 128, 256, 256, 0, 128);
  add(proj_w, PWB, 128, 144, 160, 0, 128);
  for (int l = 0; l < NLD; l++)
    add(m_w_ig + (size_t)l*256*128, WIGB + (size_t)l*256*128, 256, 128, 128, 0, 256);
  for (int l = 0; l < NLD; l++){
    add(m_w_dt + (size_t)l*128*128, WDBCB + (size_t)l*144*128, 128, 128, 128, 0,   128);
    add(m_w_b  + (size_t)l*8*128,   WDBCB + (size_t)l*144*128,   8, 128, 128, 128,   8);
    add(m_w_c  + (size_t)l*8*128,   WDBCB + (size_t)l*144*128,   8, 128, 128, 136,   8);
  }
  for (int l = 0; l < NLD; l++)
    add(m_w_out + (size_t)l*128*128, WOUTB + (size_t)l*128*128, 128, 128, 128, 0, 128);
  add(pol_w1, PW1B, 128, 128, 128, 0, 128);
  add(pol_w2, PW2B,  19, 128, 128, 0,  32);

  k_prep<<<20*4, 256, 0, stream>>>(P);
  k_enc12p<<<NTOK/32, 256, 0, stream>>>(obs, W1B, enc_b1, enc_g1, enc_bb1,
      W2B, enc_b2, enc_g2, enc_bb2,
      emb, pact, PWB, proj_b, proj_g, proj_bb, X,
      m_ln_g, m_ln_b, WIGB, WDBCB, m_b_dt,
      XINb, Zb, DTb, BTu, CTu,
      m_a_log, HLA, PPA);

  const int carrygrid = BB*1024/256;   // 256 blocks
  const int scangrid  = NTOK/32;       // 1024 blocks x 256 thr

  // layer 0
  k_carry<<<carrygrid, 256, 0, stream>>>(HLA, PPA, h0);
  k_scan2p<<<scangrid, 256, 0, stream>>>(DTb, XINb, Zb, BTu, CTu,
      m_a_log, HLA, m_d, WOUTB, X,
      m_ln_g + 128, m_ln_b + 128,
      WIGB + (size_t)256*128, WDBCB + (size_t)144*128, m_b_dt + 128,
      m_a_log + 1024, HLB, PPB);
  // layer 1
  k_carry<<<carrygrid, 256, 0, stream>>>(HLB, PPB, h0 + (size_t)BB*1024);
  k_scan2p<<<scangrid, 256, 0, stream>>>(DTb, XINb, Zb, BTu, CTu,
      m_a_log + 1024, HLB, m_d + 128, WOUTB + (size_t)128*128, X,
      m_ln_g + 256, m_ln_b + 256,
      WIGB + (size_t)2*256*128, WDBCB + (size_t)2*144*128, m_b_dt + 256,
      m_a_log + 2048, HLA, PPA);
  // layer 2
  k_carry<<<carrygrid, 256, 0, stream>>>(HLA, PPA, h0 + (size_t)2*BB*1024);
  k_scan2h<<<scangrid, 256, 0, stream>>>(DTb, XINb, Zb, BTu, CTu,
      m_a_log + 2048, HLA, m_d + 256, WOUTB + (size_t)2*128*128, X,
      fn_g, fn_b, PW1B, pol_b1, pol_g, pol_bb, PW2B, pol_b2,
      (float*)d_out);
}

// Round 4
// 407.010 us; speedup vs baseline: 1.1469x; 1.0050x over previous
//
#include <hip/hip_runtime.h>
#include <math.h>

#define BB 64
#define TT 512
#define OBSD 115
#define DMD 128
#define DSD 8
#define NLD 3
#define EMBD 16
#define NAD 19
#define H1D 256
#define NTOK (BB*TT)
#define SSEG 32
#define TSEG (TT/SSEG)   // 16

typedef unsigned short ushort_t;
typedef __attribute__((ext_vector_type(8))) short short8;
typedef __attribute__((ext_vector_type(4))) float f32x4;

__device__ __forceinline__ float silu_f(float x){ return x / (1.f + __expf(-x)); }
__device__ __forceinline__ float softplus_f(float x){
  return fmaxf(x, 0.f) + log1pf(__expf(-fabsf(x)));
}
__device__ __forceinline__ ushort_t f2bf(float x){
  unsigned u = __float_as_uint(x);
  unsigned r = (u + 0x7fffu + ((u >> 16) & 1u)) >> 16;
  return (ushort_t)r;
}
__device__ __forceinline__ float b2f(ushort_t x){
  return __uint_as_float(((unsigned)x) << 16);
}
#define MFMA(a,b,c) __builtin_amdgcn_mfma_f32_16x16x32_bf16((a),(b),(c),0,0,0)
#define LOG2E 1.44269504f

// ---------------- k_prep ----------------
struct PJob { const float* src; ushort_t* dst; int N; int K; int Kpad; int rowofs; int Nw; };
struct PJobs { PJob j[20]; };

__global__ __launch_bounds__(256) void k_prep(PJobs P){
  const int job = blockIdx.x >> 2;
  const int sub = blockIdx.x & 3;
  PJob pj = P.j[job];
  const int elems = pj.Nw * pj.Kpad;
  for (int idx = sub*256 + threadIdx.x; idx < elems; idx += 4*256){
    int n = idx / pj.Kpad;
    int k = idx - n*pj.Kpad;
    float v = (n < pj.N && k < pj.K) ? pj.src[(size_t)n*pj.K + k] : 0.f;
    pj.dst[(size_t)(pj.rowofs + n)*pj.Kpad + k] = f2bf(v);
  }
}

// ======== k_enc12p: enc1+enc2+proj+LN(l0)+wig/wdbc(l0)+phaseA(l0), 32 tok/block ========
// All LayerNorms computed from MFMA accumulator registers (partial sums + shfl_xor over
// the 16-lane cn group, combined across the 2 N-half waves through s_st) — no f32
// scratch passes, ~10 barriers total.
// LDS (bytes):
//  [0,8704)      s_obs bf16 32x136   (dead after GEMM1 af load)
//  [0,16896)     s_e1 bf16 32x264    (dead after GEMM2 af2 load)
//  [0,8704)      s_xin bf16 32x136   (wig output, late)
//  [8704,17408)  s_dt  bf16 32x136   (wdbc output, late)
//  [16896,27648) s_a2 bf16 32x168    (enc2-LN out + emb; proj/wig A operand)
//  [27648,28160) s_btc 32x8 bf16
//  [28160,28672) s_st  float2[32][2]
//  [28672,29184) s_st2 float2[32][2]
__global__ __launch_bounds__(256, 4) void k_enc12p(
    const float* __restrict__ obs, const ushort_t* __restrict__ w1b,
    const float* __restrict__ b1, const float* __restrict__ g1,
    const float* __restrict__ bb1,
    const ushort_t* __restrict__ w2b,
    const float* __restrict__ b2, const float* __restrict__ g2,
    const float* __restrict__ bb2,
    const float* __restrict__ emb, const int* __restrict__ pact,
    const ushort_t* __restrict__ pwb, const float* __restrict__ pb,
    const float* __restrict__ pg, const float* __restrict__ pbb,
    float* __restrict__ X,
    const float* __restrict__ lng, const float* __restrict__ lnb,
    const ushort_t* __restrict__ wigb, const ushort_t* __restrict__ wdbcb,
    const float* __restrict__ bdt,
    ushort_t* __restrict__ XINb, ushort_t* __restrict__ Zb,
    ushort_t* __restrict__ DTb, ushort_t* __restrict__ BTu, ushort_t* __restrict__ CTu,
    const float* __restrict__ alog0,
    float* __restrict__ HLOC, float* __restrict__ PPR)
{
  __shared__ __align__(16) char sm[29184];
  ushort_t* s_obs  = (ushort_t*)sm;
  ushort_t* s_e1   = (ushort_t*)sm;
  ushort_t* s_xin  = (ushort_t*)sm;
  ushort_t* s_dt   = (ushort_t*)(sm + 8704);
  ushort_t* s_a2   = (ushort_t*)(sm + 16896);
  ushort_t* s_btc  = (ushort_t*)(sm + 27648);
  float2*   s_st   = (float2*)(sm + 28160);
  float2*   s_st2  = (float2*)(sm + 28672);

  const int tok0 = blockIdx.x * 32;
  const int bidx = blockIdx.x >> 4;
  const int ch   = blockIdx.x & 15;
  const int tid = threadIdx.x;
  const int lane = tid & 63, w = tid >> 6;
  const int q = lane >> 4, cn = lane & 15;
  const int m0 = (w & 1) * 16, nh = w >> 1;

  // -- P1: stage obs -> s_obs bf16 (pad 115->128); stage emb -> s_a2 cols [128,160) --
  for (int e = tid; e < 32*16; e += 256){
    int t = e >> 4, kc = e & 15;
    const float* op = obs + (size_t)(tok0 + t)*OBSD;
    short8 v;
    #pragma unroll
    for (int j = 0; j < 8; j++){
      int k = kc*8 + j;
      v[j] = (short)f2bf(k < OBSD ? op[k] : 0.f);
    }
    *(short8*)&s_obs[t*136 + kc*8] = v;
  }
  for (int e = tid; e < 32*32; e += 256){
    int t = e >> 5, k = e & 31;
    float v = 0.f;
    if (k < EMBD){ int a = pact[tok0 + t]; v = emb[(size_t)a*EMBD + k]; }
    s_a2[t*168 + 128 + k] = f2bf(v);
  }
  __syncthreads();

  // -- P2: GEMM1 (obs @ w1.T + b1) -> acc regs; in-reg LN stats -> s_st --
  f32x4 acc[8];
  {
    short8 af[4];
    #pragma unroll
    for (int ks = 0; ks < 4; ks++)
      af[ks] = *(const short8*)&s_obs[(m0 + cn)*136 + ks*32 + q*8];
    #pragma unroll
    for (int nt = 0; nt < 8; nt++){
      const int n0 = (nh*8 + nt) * 16;
      f32x4 a = {0.f,0.f,0.f,0.f};
      #pragma unroll
      for (int ks = 0; ks < 4; ks++){
        short8 bf = *(const short8*)&w1b[(size_t)(n0 + cn)*128 + ks*32 + q*8];
        a = MFMA(af[ks], bf, a);
      }
      float bv = b1[n0 + cn];
      #pragma unroll
      for (int r = 0; r < 4; r++) a[r] += bv;
      acc[nt] = a;
    }
    #pragma unroll
    for (int r = 0; r < 4; r++){
      float s = 0.f, s2 = 0.f;
      #pragma unroll
      for (int nt = 0; nt < 8; nt++){ float v = acc[nt][r]; s += v; s2 = fmaf(v, v, s2); }
      s += __shfl_xor(s, 1, 64); s2 += __shfl_xor(s2, 1, 64);
      s += __shfl_xor(s, 2, 64); s2 += __shfl_xor(s2, 2, 64);
      s += __shfl_xor(s, 4, 64); s2 += __shfl_xor(s2, 4, 64);
      s += __shfl_xor(s, 8, 64); s2 += __shfl_xor(s2, 8, 64);
      if (cn == 0) s_st[(m0 + q*4 + r)*2 + nh] = make_float2(s, s2);
    }
  }
  __syncthreads();   // s_obs dead (af consumed); s_e1 writable

  // -- P3: normalize(256) + silu -> s_e1 --
  {
    float mu[4], rs[4];
    #pragma unroll
    for (int r = 0; r < 4; r++){
      const int row = m0 + q*4 + r;
      float2 p0 = s_st[row*2 + 0], p1 = s_st[row*2 + 1];
      float s = p0.x + p1.x, s2 = p0.y + p1.y;
      float m = s * (1.f/256.f);
      mu[r] = m;
      rs[r] = rsqrtf(s2 * (1.f/256.f) - m*m + 1e-5f);
    }
    #pragma unroll
    for (int nt = 0; nt < 8; nt++){
      const int col = (nh*8 + nt)*16 + cn;
      float gg = g1[col], bbv = bb1[col];
      #pragma unroll
      for (int r = 0; r < 4; r++){
        float v = (acc[nt][r] - mu[r]) * rs[r] * gg + bbv;
        s_e1[(m0 + q*4 + r)*264 + col] = f2bf(silu_f(v));
      }
    }
  }
  __syncthreads();

  // -- P4: GEMM2 (e1 @ w2.T + b2) -> acc2 regs; in-reg LN stats -> s_st --
  f32x4 acc2[4];
  {
    short8 af2[8];
    #pragma unroll
    for (int ks = 0; ks < 8; ks++)
      af2[ks] = *(const short8*)&s_e1[(m0 + cn)*264 + ks*32 + q*8];
    #pragma unroll
    for (int nt = 0; nt < 4; nt++){
      const int n0 = (nh*4 + nt) * 16;
      f32x4 a = {0.f,0.f,0.f,0.f};
      #pragma unroll
      for (int ks = 0; ks < 8; ks++){
        short8 bf = *(const short8*)&w2b[(size_t)(n0 + cn)*256 + ks*32 + q*8];
        a = MFMA(af2[ks], bf, a);
      }
      float bv = b2[n0 + cn];
      #pragma unroll
      for (int r = 0; r < 4; r++) a[r] += bv;
      acc2[nt] = a;
    }
    #pragma unroll
    for (int r = 0; r < 4; r++){
      float s = 0.f, s2 = 0.f;
      #pragma unroll
      for (int nt = 0; nt < 4; nt++){ float v = acc2[nt][r]; s += v; s2 = fmaf(v, v, s2); }
      s += __shfl_xor(s, 1, 64); s2 += __shfl_xor(s2, 1, 64);
      s += __shfl_xor(s, 2, 64); s2 += __shfl_xor(s2, 2, 64);
      s += __shfl_xor(s, 4, 64); s2 += __shfl_xor(s2, 4, 64);
      s += __shfl_xor(s, 8, 64); s2 += __shfl_xor(s2, 8, 64);
      if (cn == 0) s_st[(m0 + q*4 + r)*2 + nh] = make_float2(s, s2);
    }
  }
  __syncthreads();

  // -- P5: normalize(128, g2/bb2) -> s_a2 cols [0,128) --
  {
    float mu[4], rs[4];
    #pragma unroll
    for (int r = 0; r < 4; r++){
      const int row = m0 + q*4 + r;
      float2 p0 = s_st[row*2 + 0], p1 = s_st[row*2 + 1];
      float s = p0.x + p1.x, s2 = p0.y + p1.y;
      float m = s * (1.f/128.f);
      mu[r] = m;
      rs[r] = rsqrtf(s2 * (1.f/128.f) - m*m + 1e-5f);
    }
    #pragma unroll
    for (int nt = 0; nt < 4; nt++){
      const int col = (nh*4 + nt)*16 + cn;
      float gg = g2[col], bbv = bb2[col];
      #pragma unroll
      for (int r = 0; r < 4; r++){
        float v = (acc2[nt][r] - mu[r]) * rs[r] * gg + bbv;
        s_a2[(m0 + q*4 + r)*168 + col] = f2bf(v);
      }
    }
  }
  __syncthreads();

  // -- P6: proj GEMM -> acc3 regs; in-reg stats -> s_st --
  f32x4 acc3[4];
  {
    short8 af3[5];
    #pragma unroll
    for (int ks = 0; ks < 5; ks++)
      af3[ks] = *(const short8*)&s_a2[(m0 + cn)*168 + ks*32 + q*8];
    #pragma unroll
    for (int nt = 0; nt < 4; nt++){
      const int n0 = (nh*4 + nt) * 16;
      f32x4 a = {0.f,0.f,0.f,0.f};
      #pragma unroll
      for (int ks = 0; ks < 5; ks++){
        short8 bf = *(const short8*)&pwb[(size_t)(n0 + cn)*160 + ks*32 + q*8];
        a = MFMA(af3[ks], bf, a);
      }
      float bv = pb[n0 + cn];
      #pragma unroll
      for (int r = 0; r < 4; r++) a[r] += bv;
      acc3[nt] = a;
    }
    #pragma unroll
    for (int r = 0; r < 4; r++){
      float s = 0.f, s2 = 0.f;
      #pragma unroll
      for (int nt = 0; nt < 4; nt++){ float v = acc3[nt][r]; s += v; s2 = fmaf(v, v, s2); }
      s += __shfl_xor(s, 1, 64); s2 += __shfl_xor(s2, 1, 64);
      s += __shfl_xor(s, 2, 64); s2 += __shfl_xor(s2, 2, 64);
      s += __shfl_xor(s, 4, 64); s2 += __shfl_xor(s2, 4, 64);
      s += __shfl_xor(s, 8, 64); s2 += __shfl_xor(s2, 8, 64);
      if (cn == 0) s_st[(m0 + q*4 + r)*2 + nh] = make_float2(s, s2);
    }
  }
  __syncthreads();

  // -- P7: normalize(pg/pbb)+silu -> acc3 (in place) + X write; stats2 -> s_st2 --
  {
    float mu[4], rs[4];
    #pragma unroll
    for (int r = 0; r < 4; r++){
      const int row = m0 + q*4 + r;
      float2 p0 = s_st[row*2 + 0], p1 = s_st[row*2 + 1];
      float s = p0.x + p1.x, s2 = p0.y + p1.y;
      float m = s * (1.f/128.f);
      mu[r] = m;
      rs[r] = rsqrtf(s2 * (1.f/128.f) - m*m + 1e-5f);
    }
    float ps[4] = {0.f,0.f,0.f,0.f}, ps2[4] = {0.f,0.f,0.f,0.f};
    #pragma unroll
    for (int nt = 0; nt < 4; nt++){
      const int col = (nh*4 + nt)*16 + cn;
      float gg = pg[col], bbv = pbb[col];
      #pragma unroll
      for (int r = 0; r < 4; r++){
        float v = (acc3[nt][r] - mu[r]) * rs[r] * gg + bbv;
        v = silu_f(v);
        acc3[nt][r] = v;
        X[(size_t)(tok0 + m0 + q*4 + r)*128 + col] = v;
        ps[r] += v; ps2[r] = fmaf(v, v, ps2[r]);
      }
    }
    #pragma unroll
    for (int r = 0; r < 4; r++){
      float s = ps[r], s2 = ps2[r];
      s += __shfl_xor(s, 1, 64); s2 += __shfl_xor(s2, 1, 64);
      s += __shfl_xor(s, 2, 64); s2 += __shfl_xor(s2, 2, 64);
      s += __shfl_xor(s, 4, 64); s2 += __shfl_xor(s2, 4, 64);
      s += __shfl_xor(s, 8, 64); s2 += __shfl_xor(s2, 8, 64);
      if (cn == 0) s_st2[(m0 + q*4 + r)*2 + nh] = make_float2(s, s2);
    }
  }
  __syncthreads();

  // -- P8: mamba LN (lng/lnb) -> s_a2 cols [0,128) --
  {
    float mu[4], rs[4];
    #pragma unroll
    for (int r = 0; r < 4; r++){
      const int row = m0 + q*4 + r;
      float2 p0 = s_st2[row*2 + 0], p1 = s_st2[row*2 + 1];
      float s = p0.x + p1.x, s2 = p0.y + p1.y;
      float m = s * (1.f/128.f);
      mu[r] = m;
      rs[r] = rsqrtf(s2 * (1.f/128.f) - m*m + 1e-5f);
    }
    #pragma unroll
    for (int nt = 0; nt < 4; nt++){
      const int col = (nh*4 + nt)*16 + cn;
      float gg = lng[col], bbv = lnb[col];
      #pragma unroll
      for (int r = 0; r < 4; r++){
        float v = (acc3[nt][r] - mu[r]) * rs[r] * gg + bbv;
        s_a2[(m0 + q*4 + r)*168 + col] = f2bf(v);
      }
    }
  }
  __syncthreads();

  // -- P9: wig GEMM --
  {
    short8 af[4];
    #pragma unroll
    for (int ks = 0; ks < 4; ks++)
      af[ks] = *(const short8*)&s_a2[(m0 + cn)*168 + ks*32 + q*8];
    #pragma unroll
    for (int nt = 0; nt < 8; nt++){
      const int n0 = (nh*8 + nt) * 16;
      f32x4 a = {0.f,0.f,0.f,0.f};
      #pragma unroll
      for (int ks = 0; ks < 4; ks++){
        short8 bf = *(const short8*)&wigb[(size_t)(n0 + cn)*128 + ks*32 + q*8];
        a = MFMA(af[ks], bf, a);
      }
      if (n0 < 128){
        #pragma unroll
        for (int r = 0; r < 4; r++){
          int tr = m0 + q*4 + r;
          ushort_t bb = f2bf(a[r]);
          XINb[(size_t)(tok0 + tr)*128 + n0 + cn] = bb;
          s_xin[tr*136 + n0 + cn] = bb;
        }
      } else {
        #pragma unroll
        for (int r = 0; r < 4; r++){
          int tr = m0 + q*4 + r;
          Zb[(size_t)(tok0 + tr)*128 + (n0 - 128) + cn] = f2bf(a[r]);
        }
      }
    }
  }
  __syncthreads();

  // -- P10: wdbc GEMM (fills s_dt / s_btc; s_dt tail overlaps dead s_a2 head) --
  {
    short8 af2[4];
    #pragma unroll
    for (int ks = 0; ks < 4; ks++)
      af2[ks] = *(const short8*)&s_xin[(m0 + cn)*136 + ks*32 + q*8];
    for (int nt = nh; nt < 9; nt += 2){
      const int n0 = nt * 16;
      f32x4 a = {0.f,0.f,0.f,0.f};
      #pragma unroll
      for (int ks = 0; ks < 4; ks++){
        short8 bf = *(const short8*)&wdbcb[(size_t)(n0 + cn)*128 + ks*32 + q*8];
        a = MFMA(af2[ks], bf, a);
      }
      const int col = n0 + cn;
      if (col < 128){
        float bd = bdt[col];
        #pragma unroll
        for (int r = 0; r < 4; r++){
          int tr = m0 + q*4 + r;
          ushort_t dv = f2bf(softplus_f(a[r] + bd));
          DTb[(size_t)(tok0 + tr)*128 + col] = dv;
          s_dt[tr*136 + col] = dv;
        }
      } else if (col < 136){
        #pragma unroll
        for (int r = 0; r < 4; r++){
          int tr = m0 + q*4 + r;
          ushort_t bb = f2bf(a[r]);
          BTu[(size_t)(tok0 + tr)*8 + (col - 128)] = bb;
          s_btc[tr*8 + (col - 128)] = bb;
        }
      } else {
        #pragma unroll
        for (int r = 0; r < 4; r++)
          CTu[(size_t)(tok0 + m0 + q*4 + r)*8 + (col - 136)] = f2bf(a[r]);
      }
    }
  }
  __syncthreads();

  // -- P11: phase A (layer 0): thread=(d, half) over its 16 tokens --
  {
    const int d = tid & 127, half = tid >> 7;
    float A2c[8], hh[8], pp[8];
    #pragma unroll
    for (int s = 0; s < 8; s++){
      A2c[s] = -__expf(alog0[d*8 + s]) * LOG2E;
      hh[s] = 0.f; pp[s] = 1.f;
    }
    const int t0 = half * 16;
    #pragma unroll 4
    for (int tt = 0; tt < 16; tt++){
      const int t = t0 + tt;
      float dt = b2f(s_dt[t*136 + d]);
      float wv = dt * b2f(s_xin[t*136 + d]);
      #pragma unroll
      for (int s = 0; s < 8; s++){
        float dA = exp2f(dt * A2c[s]);
        hh[s] = fmaf(dA, hh[s], wv * b2f(s_btc[t*8 + s]));
        pp[s] *= dA;
      }
    }
    const size_t o = ((size_t)bidx*SSEG + ch*2 + half)*1024 + d*8;
    #pragma unroll
    for (int s = 0; s < 8; s++){ HLOC[o+s] = hh[s]; PPR[o+s] = pp[s]; }
  }
}

// ---- k_carry: HL[b,ch] := exclusive prefix (in place); prefetch-all then chain ----
__global__ __launch_bounds__(256) void k_carry(
    float* __restrict__ HL, const float* __restrict__ PP,
    const float* __restrict__ h0g)
{
  const int idx = blockIdx.x*256 + threadIdx.x;
  const size_t base = (size_t)(idx >> 10) * (SSEG*1024) + (idx & 1023);
  float hl[SSEG], pp[SSEG];
  #pragma unroll
  for (int ch = 0; ch < SSEG; ch++){
    hl[ch] = HL[base + (size_t)ch*1024];
    pp[ch] = PP[base + (size_t)ch*1024];
  }
  float h = h0g[idx];
  #pragma unroll
  for (int ch = 0; ch < SSEG; ch++){
    HL[base + (size_t)ch*1024] = h;
    h = fmaf(pp[ch], h, hl[ch]);
  }
}

// ======== phase B over 32 tokens: scan(+z/silu/D inline) + wout + residual + in-reg LN stats
// LDS (bytes):
//  [0,8192)      s_dtS ; [8192,16384) s_xiS ; [16384,24576) s_zS   [staging, dead after scan]
//  [0,16640)     s_x f32 32x130 (wout out) ; s_xin bf16 [0,8704) ; s_dt2 [8704,17408)
//  [24576,33280) s_a bf16 32x136
//  [33280,33792) s_bt ; [33792,34304) s_ct  (s_btc reuses s_bt late)
//  [34304,34816) s_st float2[32][2]
#define SMB 34816

__device__ __forceinline__ void phaseB32(
    const ushort_t* DTb, const ushort_t* XINb, const ushort_t* Zb,
    const ushort_t* BTu, const ushort_t* CTu,
    const float* __restrict__ alog, const float* __restrict__ HLpre,
    const float* __restrict__ dpar, const ushort_t* __restrict__ woutb,
    float* __restrict__ X, char* sm, int b, int pair, int tid)
{
  ushort_t* s_dtS = (ushort_t*)sm;
  ushort_t* s_xiS = (ushort_t*)(sm + 8192);
  ushort_t* s_zS  = (ushort_t*)(sm + 16384);
  float*    s_x   = (float*)sm;
  ushort_t* s_a   = (ushort_t*)(sm + 24576);
  ushort_t* s_bt  = (ushort_t*)(sm + 33280);
  ushort_t* s_ct  = (ushort_t*)(sm + 33792);
  float2*   s_st  = (float2*)(sm + 34304);

  const int lane = tid & 63, w = tid >> 6, q = lane >> 4, cn = lane & 15;
  const int m0 = (w & 1) * 16, nh = w >> 1;
  const int d = tid & 127, half = tid >> 7;
  const size_t segtok = (size_t)b*TT + pair*32;

  // P1: stage dt/xin/z + bt/ct
  {
    const uint4* gdt = (const uint4*)(DTb + segtok*128);
    const uint4* gxi = (const uint4*)(XINb + segtok*128);
    const uint4* gz  = (const uint4*)(Zb + segtok*128);
    #pragma unroll
    for (int i = 0; i < 2; i++){
      ((uint4*)s_dtS)[tid + i*256] = gdt[tid + i*256];
      ((uint4*)s_xiS)[tid + i*256] = gxi[tid + i*256];
      ((uint4*)s_zS )[tid + i*256] = gz [tid + i*256];
    }
    if (tid < 128){
      ((unsigned*)s_bt)[tid] = ((const unsigned*)(BTu + segtok*8))[tid];
      ((unsigned*)s_ct)[tid] = ((const unsigned*)(CTu + segtok*8))[tid];
    }
  }
  float A2[8], h[8];
  float dp = dpar[d];
  {
    const size_t o = ((size_t)b*SSEG + pair*2 + half)*1024 + d*8;
    float4 h0v = *(const float4*)(HLpre + o);
    float4 h1v = *(const float4*)(HLpre + o + 4);
    h[0]=h0v.x; h[1]=h0v.y; h[2]=h0v.z; h[3]=h0v.w;
    h[4]=h1v.x; h[5]=h1v.y; h[6]=h1v.z; h[7]=h1v.w;
    #pragma unroll
    for (int s = 0; s < 8; s++) A2[s] = -__expf(alog[d*8 + s]) * LOG2E;
  }
  __syncthreads();

  // P2: scan with inline z-gate + D-skip; thread=(d,half) over its 16 tokens
  #pragma unroll 4
  for (int tt = 0; tt < 16; tt++){
    const int t = half*16 + tt;
    float dt = b2f(s_dtS[t*128 + d]);
    float xi = b2f(s_xiS[t*128 + d]);
    float zv = b2f(s_zS [t*128 + d]);
    float wv = dt * xi;
    float y = 0.f;
    #pragma unroll
    for (int s = 0; s < 8; s++){
      float dA = exp2f(dt * A2[s]);
      h[s] = fmaf(dA, h[s], wv * b2f(s_bt[t*8 + s]));
      y = fmaf(h[s], b2f(s_ct[t*8 + s]), y);
    }
    float ssm = y * silu_f(zv) + xi * dp;
    s_a[t*136 + d] = f2bf(ssm);
  }
  __syncthreads();   // staging dead; s_x writable

  // P3: wout GEMM + residual -> s_x + X; in-reg LN stats -> s_st
  {
    short8 af[4];
    #pragma unroll
    for (int ks = 0; ks < 4; ks++)
      af[ks] = *(const short8*)&s_a[(m0 + cn)*136 + ks*32 + q*8];
    float ps[4] = {0.f,0.f,0.f,0.f}, ps2[4] = {0.f,0.f,0.f,0.f};
    #pragma unroll
    for (int i = 0; i < 4; i++){
      const int n0 = (nh*4 + i) * 16;
      short8 bf[4];
      #pragma unroll
      for (int ks = 0; ks < 4; ks++)
        bf[ks] = *(const short8*)&woutb[(size_t)(n0+cn)*128 + ks*32 + q*8];
      f32x4 acc = {0.f,0.f,0.f,0.f};
      #pragma unroll
      for (int ks = 0; ks < 4; ks++) acc = MFMA(af[ks], bf[ks], acc);
      #pragma unroll
      for (int r = 0; r < 4; r++){
        const int tr = m0 + q*4 + r;
        const size_t g = (segtok + tr)*128 + n0 + cn;
        float xn = X[g] + acc[r];
        X[g] = xn;
        s_x[tr*130 + n0 + cn] = xn;
        ps[r] += xn; ps2[r] = fmaf(xn, xn, ps2[r]);
      }
    }
    #pragma unroll
    for (int r = 0; r < 4; r++){
      float s = ps[r], s2 = ps2[r];
      s += __shfl_xor(s, 1, 64); s2 += __shfl_xor(s2, 1, 64);
      s += __shfl_xor(s, 2, 64); s2 += __shfl_xor(s2, 2, 64);
      s += __shfl_xor(s, 4, 64); s2 += __shfl_xor(s2, 4, 64);
      s += __shfl_xor(s, 8, 64); s2 += __shfl_xor(s2, 8, 64);
      if (cn == 0) s_st[(m0 + q*4 + r)*2 + nh] = make_float2(s, s2);
    }
  }
  __syncthreads();
}

// ---- k_scan2p: 32-token block; phaseB, LN, wig, wdbc, phaseA(next) ----
__global__ __launch_bounds__(256, 4) void k_scan2p(
    ushort_t* DTb, ushort_t* XINb, ushort_t* Zb,
    ushort_t* BTu, ushort_t* CTu,
    const float* __restrict__ alog, const float* __restrict__ HLpre,
    const float* __restrict__ dpar, const ushort_t* __restrict__ woutb,
    float* __restrict__ X,
    const float* __restrict__ lng, const float* __restrict__ lnb,
    const ushort_t* __restrict__ wigb, const ushort_t* __restrict__ wdbcb,
    const float* __restrict__ bdt,
    const float* __restrict__ alogn,
    float* __restrict__ HLo, float* __restrict__ PPo)
{
  __shared__ __align__(16) char sm[SMB];
  const int tid = threadIdx.x;
  float*    s_x   = (float*)sm;
  ushort_t* s_xin = (ushort_t*)sm;
  ushort_t* s_dt2 = (ushort_t*)(sm + 8704);
  ushort_t* s_a   = (ushort_t*)(sm + 24576);
  ushort_t* s_btc = (ushort_t*)(sm + 33280);
  float2*   s_st  = (float2*)(sm + 34304);

  const int b = blockIdx.x >> 4;
  const int pair = blockIdx.x & 15;
  const int lane = tid & 63, w = tid >> 6, q = lane >> 4, cn = lane & 15;
  const int m0 = (w & 1) * 16, nh = w >> 1;
  const int d = tid & 127, half = tid >> 7;
  const size_t segtok = (size_t)b*TT + pair*32;

  phaseB32(DTb, XINb, Zb, BTu, CTu, alog, HLpre, dpar, woutb, X, sm, b, pair, tid);

  // P4: normalize (lng/lnb) -> s_a ; mu/rs combined redundantly per thread
  {
    float g = lng[d], c0v = lnb[d];
    #pragma unroll
    for (int tt = 0; tt < 16; tt++){
      const int t = half*16 + tt;
      float2 p0 = s_st[t*2 + 0], p1 = s_st[t*2 + 1];
      float ssum = p0.x + p1.x, ss2 = p0.y + p1.y;
      float mu = ssum * (1.f/128.f);
      float rs = rsqrtf(ss2 * (1.f/128.f) - mu*mu + 1e-5f);
      float v = (s_x[t*130 + d] - mu) * rs * g + c0v;
      s_a[t*136 + d] = f2bf(v);
    }
  }
  __syncthreads();

  // P5: wig GEMM (M=32, N=256); writes s_xin (aliases dead s_x) + XINb/Zb
  {
    short8 af[4];
    #pragma unroll
    for (int ks = 0; ks < 4; ks++)
      af[ks] = *(const short8*)&s_a[(m0 + cn)*136 + ks*32 + q*8];
    #pragma unroll
    for (int i = 0; i < 8; i++){
      const int n0 = (nh*8 + i) * 16;
      short8 bf[4];
      #pragma unroll
      for (int ks = 0; ks < 4; ks++)
        bf[ks] = *(const short8*)&wigb[(size_t)(n0+cn)*128 + ks*32 + q*8];
      f32x4 acc = {0.f,0.f,0.f,0.f};
      #pragma unroll
      for (int ks = 0; ks < 4; ks++) acc = MFMA(af[ks], bf[ks], acc);
      if (n0 < 128){
        #pragma unroll
        for (int r = 0; r < 4; r++){
          const int tr = m0 + q*4 + r;
          ushort_t bb = f2bf(acc[r]);
          XINb[(segtok + tr)*128 + n0 + cn] = bb;
          s_xin[tr*136 + n0 + cn] = bb;
        }
      } else {
        #pragma unroll
        for (int r = 0; r < 4; r++){
          const int tr = m0 + q*4 + r;
          Zb[(segtok + tr)*128 + (n0-128) + cn] = f2bf(acc[r]);
        }
      }
    }
  }
  __syncthreads();

  // P6: wdbc GEMM; fills s_dt2 / s_btc
  {
    short8 af2[4];
    #pragma unroll
    for (int ks = 0; ks < 4; ks++)
      af2[ks] = *(const short8*)&s_xin[(m0 + cn)*136 + ks*32 + q*8];
    for (int nt = nh; nt < 9; nt += 2){
      const int n0 = nt * 16;
      short8 bf[4];
      #pragma unroll
      for (int ks = 0; ks < 4; ks++)
        bf[ks] = *(const short8*)&wdbcb[(size_t)(n0+cn)*128 + ks*32 + q*8];
      f32x4 acc = {0.f,0.f,0.f,0.f};
      #pragma unroll
      for (int ks = 0; ks < 4; ks++) acc = MFMA(af2[ks], bf[ks], acc);
      const int col = n0 + cn;
      if (col < 128){
        float bd = bdt[col];
        #pragma unroll
        for (int r = 0; r < 4; r++){
          const int tr = m0 + q*4 + r;
          ushort_t dv = f2bf(softplus_f(acc[r] + bd));
          DTb[(segtok + tr)*128 + col] = dv;
          s_dt2[tr*136 + col] = dv;
        }
      } else if (col < 136){
        #pragma unroll
        for (int r = 0; r < 4; r++){
          const int tr = m0 + q*4 + r;
          ushort_t bb = f2bf(acc[r]);
          BTu[(segtok + tr)*8 + (col-128)] = bb;
          s_btc[tr*8 + (col-128)] = bb;
        }
      } else {
        #pragma unroll
        for (int r = 0; r < 4; r++)
          CTu[(segtok + m0 + q*4 + r)*8 + (col-136)] = f2bf(acc[r]);
      }
    }
  }
  __syncthreads();

  // P7: phase A (next layer): thread=(d,half) over its 16 tokens
  {
    float A2n[8], hh[8], pp[8];
    #pragma unroll
    for (int s = 0; s < 8; s++){
      A2n[s] = -__expf(alogn[d*8 + s]) * LOG2E;
      hh[s] = 0.f; pp[s] = 1.f;
    }
    #pragma unroll 4
    for (int tt = 0; tt < 16; tt++){
      const int t = half*16 + tt;
      float dt = b2f(s_dt2[t*136 + d]);
      float wv = dt * b2f(s_xin[t*136 + d]);
      #pragma unroll
      for (int s = 0; s < 8; s++){
        float dA = exp2f(dt * A2n[s]);
        hh[s] = fmaf(dA, hh[s], wv * b2f(s_btc[t*8 + s]));
        pp[s] *= dA;
      }
    }
    const size_t o = ((size_t)b*SSEG + pair*2 + half)*1024 + d*8;
    #pragma unroll
    for (int s = 0; s < 8; s++){ HLo[o+s] = hh[s]; PPo[o+s] = pp[s]; }
  }
}

// ---- k_scan2h: 32-token block; phaseB, LNfn, pw1(+stats), LN+silu, pw2 ----
__global__ __launch_bounds__(256, 4) void k_scan2h(
    const ushort_t* DTb, const ushort_t* XINb, const ushort_t* Zb,
    const ushort_t* BTu, const ushort_t* CTu,
    const float* __restrict__ alog, const float* __restrict__ HLpre,
    const float* __restrict__ dpar, const ushort_t* __restrict__ woutb,
    float* __restrict__ X,
    const float* __restrict__ fng, const float* __restrict__ fnb,
    const ushort_t* __restrict__ pw1b, const float* __restrict__ pb1,
    const float* __restrict__ pg, const float* __restrict__ pbb,
    const ushort_t* __restrict__ pw2b, const float* __restrict__ pb2,
    float* __restrict__ out)
{
  __shared__ __align__(16) char sm[SMB];
  const int tid = threadIdx.x;
  float*    s_x  = (float*)sm;
  ushort_t* s_a  = (ushort_t*)(sm + 24576);
  float2*   s_st = (float2*)(sm + 34304);

  const int b = blockIdx.x >> 4;
  const int pair = blockIdx.x & 15;
  const int lane = tid & 63, w = tid >> 6, q = lane >> 4, cn = lane & 15;
  const int m0 = (w & 1) * 16, nh = w >> 1;
  const int d = tid & 127, half = tid >> 7;
  const size_t segtok = (size_t)b*TT + pair*32;

  phaseB32((ushort_t*)DTb, (ushort_t*)XINb, (ushort_t*)Zb,
           (ushort_t*)BTu, (ushort_t*)CTu, alog, HLpre,
           dpar, woutb, X, sm, b, pair, tid);

  // P4: LN_fn -> s_a
  {
    float g = fng[d], c0v = fnb[d];
    #pragma unroll
    for (int tt = 0; tt < 16; tt++){
      const int t = half*16 + tt;
      float2 p0 = s_st[t*2 + 0], p1 = s_st[t*2 + 1];
      float ssum = p0.x + p1.x, ss2 = p0.y + p1.y;
      float mu = ssum * (1.f/128.f);
      float rs = rsqrtf(ss2 * (1.f/128.f) - mu*mu + 1e-5f);
      float v = (s_x[t*130 + d] - mu) * rs * g + c0v;
      s_a[t*136 + d] = f2bf(v);
    }
  }
  __syncthreads();

  // P5: pw1 GEMM -> s_x (+bias); in-reg stats -> s_st
  {
    short8 af[4];
    #pragma unroll
    for (int ks = 0; ks < 4; ks++)
      af[ks] = *(const short8*)&s_a[(m0 + cn)*136 + ks*32 + q*8];
    float ps[4] = {0.f,0.f,0.f,0.f}, ps2[4] = {0.f,0.f,0.f,0.f};
    #pragma unroll
    for (int i = 0; i < 4; i++){
      const int n0 = (nh*4 + i) * 16;
      short8 bf[4];
      #pragma unroll
      for (int ks = 0; ks < 4; ks++)
        bf[ks] = *(const short8*)&pw1b[(size_t)(n0+cn)*128 + ks*32 + q*8];
      float bias = pb1[n0 + cn];
      f32x4 acc = {0.f,0.f,0.f,0.f};
      #pragma unroll
      for (int ks = 0; ks < 4; ks++) acc = MFMA(af[ks], bf[ks], acc);
      #pragma unroll
      for (int r = 0; r < 4; r++){
        float xv = acc[r] + bias;
        s_x[(m0 + q*4 + r)*130 + n0 + cn] = xv;
        ps[r] += xv; ps2[r] = fmaf(xv, xv, ps2[r]);
      }
    }
    #pragma unroll
    for (int r = 0; r < 4; r++){
      float s = ps[r], s2 = ps2[r];
      s += __shfl_xor(s, 1, 64); s2 += __shfl_xor(s2, 1, 64);
      s += __shfl_xor(s, 2, 64); s2 += __shfl_xor(s2, 2, 64);
      s += __shfl_xor(s, 4, 64); s2 += __shfl_xor(s2, 4, 64);
      s += __shfl_xor(s, 8, 64); s2 += __shfl_xor(s2, 8, 64);
      if (cn == 0) s_st[(m0 + q*4 + r)*2 + nh] = make_float2(s, s2);
    }
  }
  __syncthreads();

  // P6: LN(pg/pbb)+silu -> s_a
  {
    float g = pg[d], c0v = pbb[d];
    #pragma unroll
    for (int tt = 0; tt < 16; tt++){
      const int t = half*16 + tt;
      float2 p0 = s_st[t*2 + 0], p1 = s_st[t*2 + 1];
      float ssum = p0.x + p1.x, ss2 = p0.y + p1.y;
      float mu = ssum * (1.f/128.f);
      float rs = rsqrtf(ss2 * (1.f/128.f) - mu*mu + 1e-5f);
      float v = (s_x[t*130 + d] - mu) * rs * g + c0v;
      s_a[t*136 + d] = f2bf(silu_f(v));
    }
  }
  __syncthreads();

  // P7: pw2 GEMM (M=32, N=32; cols<19 stored)
  {
    short8 af[4];
    #pragma unroll
    for (int ks = 0; ks < 4; ks++)
      af[ks] = *(const short8*)&s_a[(m0 + cn)*136 + ks*32 + q*8];
    const int n0 = (w >> 1) * 16;
    short8 bf[4];
    #pragma unroll
    for (int ks = 0; ks < 4; ks++)
      bf[ks] = *(const short8*)&pw2b[(size_t)(n0+cn)*128 + ks*32 + q*8];
    const int col = n0 + cn;
    f32x4 acc = {0.f,0.f,0.f,0.f};
    #pragma unroll
    for (int ks = 0; ks < 4; ks++) acc = MFMA(af[ks], bf[ks], acc);
    if (col < NAD){
      float bias = pb2[col];
      #pragma unroll
      for (int r = 0; r < 4; r++)
        out[(segtok + m0 + q*4 + r)*NAD + col] = acc[r] + bias;
    }
  }
}

extern "C" void kernel_launch(void* const* d_in, const int* in_sizes, int n_in,
                              void* d_out, int out_size, void* d_ws, size_t ws_size,
                              hipStream_t stream) {
  const float* obs    = (const float*)d_in[0];
  const float* h0     = (const float*)d_in[1];
  const float* enc_w1 = (const float*)d_in[2];
  const float* enc_b1 = (const float*)d_in[3];
  const float* enc_g1 = (const float*)d_in[4];
  const float* enc_bb1= (const float*)d_in[5];
  const float* enc_w2 = (const float*)d_in[6];
  const float* enc_b2 = (const float*)d_in[7];
  const float* enc_g2 = (const float*)d_in[8];
  const float* enc_bb2= (const float*)d_in[9];
  const float* emb    = (const float*)d_in[10];
  const float* proj_w = (const float*)d_in[11];
  const float* proj_b = (const float*)d_in[12];
  const float* proj_g = (const float*)d_in[13];
  const float* proj_bb= (const float*)d_in[14];
  const float* m_ln_g = (const float*)d_in[15];
  const float* m_ln_b = (const float*)d_in[16];
  const float* m_w_ig = (const float*)d_in[17];
  const float* m_w_dt = (const float*)d_in[18];
  const float* m_b_dt = (const float*)d_in[19];
  const float* m_a_log= (const float*)d_in[20];
  const float* m_w_b  = (const float*)d_in[21];
  const float* m_w_c  = (const float*)d_in[22];
  const float* m_d    = (const float*)d_in[23];
  const float* m_w_out= (const float*)d_in[24];
  const float* fn_g   = (const float*)d_in[25];
  const float* fn_b   = (const float*)d_in[26];
  const float* pol_w1 = (const float*)d_in[27];
  const float* pol_b1 = (const float*)d_in[28];
  const float* pol_g  = (const float*)d_in[29];
  const float* pol_bb = (const float*)d_in[30];
  const float* pol_w2 = (const float*)d_in[31];
  const float* pol_b2 = (const float*)d_in[32];
  const int*   pact   = (const int*)d_in[33];

  float* ws  = (float*)d_ws;
  float* X    = ws;
  float* HLA  = X + (size_t)NTOK*128;
  float* PPA  = HLA + (size_t)BB*SSEG*1024;
  float* HLB  = PPA + (size_t)BB*SSEG*1024;
  float* PPB  = HLB + (size_t)BB*SSEG*1024;
  ushort_t* XINb = (ushort_t*)(PPB + (size_t)BB*SSEG*1024);
  ushort_t* Zb   = XINb + (size_t)NTOK*128;
  ushort_t* DTb  = Zb   + (size_t)NTOK*128;
  ushort_t* BTu  = DTb  + (size_t)NTOK*128;
  ushort_t* CTu  = BTu  + (size_t)NTOK*8;

  ushort_t* W1B   = CTu   + (size_t)NTOK*8;
  ushort_t* W2B   = W1B   + 256*128;
  ushort_t* PWB   = W2B   + 128*256;
  ushort_t* WIGB  = PWB   + 128*160;
  ushort_t* WDBCB = WIGB  + 3*256*128;
  ushort_t* WOUTB = WDBCB + 3*144*128;
  ushort_t* PW1B  = WOUTB + 3*128*128;
  ushort_t* PW2B  = PW1B  + 128*128;

  PJobs P;
  int nj = 0;
  auto add = [&](const float* src, ushort_t* dst, int N, int K, int Kpad, int rowofs, int Nw){
    P.j[nj].src = src; P.j[nj].dst = dst; P.j[nj].N = N; P.j[nj].K = K;
    P.j[nj].Kpad = Kpad; P.j[nj].rowofs = rowofs; P.j[nj].Nw = Nw; nj++;
  };
  add(enc_w1, W1B, 256, 115, 128, 0, 256);
  add(enc_w2, W2B, 128, 256, 256, 0, 128);
  add(proj_w, PWB, 128, 144, 160, 0, 128);
  for (int l = 0; l < NLD; l++)
    add(m_w_ig + (size_t)l*256*128, WIGB + (size_t)l*256*128, 256, 128, 128, 0, 256);
  for (int l = 0; l < NLD; l++){
    add(m_w_dt + (size_t)l*128*128, WDBCB + (size_t)l*144*128, 128, 128, 128, 0,   128);
    add(m_w_b  + (size_t)l*8*128,   WDBCB + (size_t)l*144*128,   8, 128, 128, 128,   8);
    add(m_w_c  + (size_t)l*8*128,   WDBCB + (size_t)l*144*128,   8, 128, 128, 136,   8);
  }
  for (int l = 0; l < NLD; l++)
    add(m_w_out + (size_t)l*128*128, WOUTB + (size_t)l*128*128, 128, 128, 128, 0, 128);
  add(pol_w1, PW1B, 128, 128, 128, 0, 128);
  add(pol_w2, PW2B,  19, 128, 128, 0,  32);

  k_prep<<<20*4, 256, 0, stream>>>(P);
  k_enc12p<<<NTOK/32, 256, 0, stream>>>(obs, W1B, enc_b1, enc_g1, enc_bb1,
      W2B, enc_b2, enc_g2, enc_bb2,
      emb, pact, PWB, proj_b, proj_g, proj_bb, X,
      m_ln_g, m_ln_b, WIGB, WDBCB, m_b_dt,
      XINb, Zb, DTb, BTu, CTu,
      m_a_log, HLA, PPA);

  const int carrygrid = BB*1024/256;   // 256 blocks
  const int scangrid  = NTOK/32;       // 1024 blocks x 256 thr

  // layer 0
  k_carry<<<carrygrid, 256, 0, stream>>>(HLA, PPA, h0);
  k_scan2p<<<scangrid, 256, 0, stream>>>(DTb, XINb, Zb, BTu, CTu,
      m_a_log, HLA, m_d, WOUTB, X,
      m_ln_g + 128, m_ln_b + 128,
      WIGB + (size_t)256*128, WDBCB + (size_t)144*128, m_b_dt + 128,
      m_a_log + 1024, HLB, PPB);
  // layer 1
  k_carry<<<carrygrid, 256, 0, stream>>>(HLB, PPB, h0 + (size_t)BB*1024);
  k_scan2p<<<scangrid, 256, 0, stream>>>(DTb, XINb, Zb, BTu, CTu,
      m_a_log + 1024, HLB, m_d + 128, WOUTB + (size_t)128*128, X,
      m_ln_g + 256, m_ln_b + 256,
      WIGB + (size_t)2*256*128, WDBCB + (size_t)2*144*128, m_b_dt + 256,
      m_a_log + 2048, HLA, PPA);
  // layer 2
  k_carry<<<carrygrid, 256, 0, stream>>>(HLA, PPA, h0 + (size_t)2*BB*1024);
  k_scan2h<<<scangrid, 256, 0, stream>>>(DTb, XINb, Zb, BTu, CTu,
      m_a_log + 2048, HLA, m_d + 256, WOUTB + (size_t)2*128*128, X,
      fn_g, fn_b, PW1B, pol_b1, pol_g, pol_bb, PW2B, pol_b2,
      (float*)d_out);
}

// Round 5
// 401.252 us; speedup vs baseline: 1.1634x; 1.0143x over previous
//
#include <hip/hip_runtime.h>
#include <math.h>

#define BB 64
#define TT 512
#define OBSD 115
#define DMD 128
#define DSD 8
#define NLD 3
#define EMBD 16
#define NAD 19
#define H1D 256
#define NTOK (BB*TT)
#define SSEG 32
#define TSEG (TT/SSEG)   // 16

typedef unsigned short ushort_t;
typedef __attribute__((ext_vector_type(8))) short short8;
typedef __attribute__((ext_vector_type(4))) float f32x4;

__device__ __forceinline__ float silu_f(float x){ return x / (1.f + __expf(-x)); }
__device__ __forceinline__ float softplus_f(float x){
  return fmaxf(x, 0.f) + log1pf(__expf(-fabsf(x)));
}
__device__ __forceinline__ ushort_t f2bf(float x){
  unsigned u = __float_as_uint(x);
  unsigned r = (u + 0x7fffu + ((u >> 16) & 1u)) >> 16;
  return (ushort_t)r;
}
__device__ __forceinline__ float b2f(ushort_t x){
  return __uint_as_float(((unsigned)x) << 16);
}
#define MFMA(a,b,c) __builtin_amdgcn_mfma_f32_16x16x32_bf16((a),(b),(c),0,0,0)
#define LOG2E 1.44269504f

// ---------------- k_prep ----------------
struct PJob { const float* src; ushort_t* dst; int N; int K; int Kpad; int rowofs; int Nw; };
struct PJobs { PJob j[20]; };

__global__ __launch_bounds__(256) void k_prep(PJobs P){
  const int job = blockIdx.x >> 2;
  const int sub = blockIdx.x & 3;
  PJob pj = P.j[job];
  const int elems = pj.Nw * pj.Kpad;
  for (int idx = sub*256 + threadIdx.x; idx < elems; idx += 4*256){
    int n = idx / pj.Kpad;
    int k = idx - n*pj.Kpad;
    float v = (n < pj.N && k < pj.K) ? pj.src[(size_t)n*pj.K + k] : 0.f;
    pj.dst[(size_t)(pj.rowofs + n)*pj.Kpad + k] = f2bf(v);
  }
}

// ======== k_enc12p: enc1+enc2+proj+LN(l0)+wig/wdbc(l0)+phaseA(l0), 16 tok/block ========
// M=16 tiles (row = q*4+r, A-frag row = cn). 4 waves split the N dimension.
// All LN stats from MFMA accumulators (shfl over 16-lane group + s_st cross-wave).
// LDS (bytes):
//  [0,4352)      s_obs bf16 16x136  (dead after GEMM1 af)
//  [0,8448)      s_e1  bf16 16x264  (dead after GEMM2 af2)
//  [0,4352)      s_xin bf16 16x136  (wig out, late)
//  [4352,8704)   s_dt  bf16 16x136  (wdbc out, late)
//  [8448,13824)  s_a2  bf16 16x168  (LN outs + emb)
//  [13824,14080) s_btc 16x8 bf16
//  [14080,14592) s_st  float2[16][4]
//  [14592,15104) s_st2 float2[16][4]
__global__ __launch_bounds__(256, 8) void k_enc12p(
    const float* __restrict__ obs, const ushort_t* __restrict__ w1b,
    const float* __restrict__ b1, const float* __restrict__ g1,
    const float* __restrict__ bb1,
    const ushort_t* __restrict__ w2b,
    const float* __restrict__ b2, const float* __restrict__ g2,
    const float* __restrict__ bb2,
    const float* __restrict__ emb, const int* __restrict__ pact,
    const ushort_t* __restrict__ pwb, const float* __restrict__ pb,
    const float* __restrict__ pg, const float* __restrict__ pbb,
    float* __restrict__ X,
    const float* __restrict__ lng, const float* __restrict__ lnb,
    const ushort_t* __restrict__ wigb, const ushort_t* __restrict__ wdbcb,
    const float* __restrict__ bdt,
    ushort_t* __restrict__ XINb, ushort_t* __restrict__ Zb,
    ushort_t* __restrict__ DTb, ushort_t* __restrict__ BTu, ushort_t* __restrict__ CTu,
    const float* __restrict__ alog0,
    float* __restrict__ HLOC, float* __restrict__ PPR)
{
  __shared__ __align__(16) char sm[15104];
  ushort_t* s_obs = (ushort_t*)sm;
  ushort_t* s_e1  = (ushort_t*)sm;
  ushort_t* s_xin = (ushort_t*)sm;
  ushort_t* s_dt  = (ushort_t*)(sm + 4352);
  ushort_t* s_a2  = (ushort_t*)(sm + 8448);
  ushort_t* s_btc = (ushort_t*)(sm + 13824);
  float2*   s_st  = (float2*)(sm + 14080);
  float2*   s_st2 = (float2*)(sm + 14592);

  const int tok0 = blockIdx.x * 16;
  const int bidx = blockIdx.x >> 5;
  const int ch   = blockIdx.x & 31;
  const int tid = threadIdx.x;
  const int lane = tid & 63, w = tid >> 6;
  const int q = lane >> 4, cn = lane & 15;

  // -- P1: stage obs (pad 115->128) + emb --
  {
    const int t = tid >> 4, kc = tid & 15;
    const float* op = obs + (size_t)(tok0 + t)*OBSD;
    short8 v;
    #pragma unroll
    for (int j = 0; j < 8; j++){
      int k = kc*8 + j;
      v[j] = (short)f2bf(k < OBSD ? op[k] : 0.f);
    }
    *(short8*)&s_obs[t*136 + kc*8] = v;
  }
  for (int e = tid; e < 16*32; e += 256){
    int t = e >> 5, k = e & 31;
    float v = 0.f;
    if (k < EMBD){ int a = pact[tok0 + t]; v = emb[(size_t)a*EMBD + k]; }
    s_a2[t*168 + 128 + k] = f2bf(v);
  }
  __syncthreads();

  // -- P2: GEMM1 (N=256, 4 tiles/wave) -> acc regs; in-reg LN stats --
  f32x4 acc[4];
  {
    short8 af[4];
    #pragma unroll
    for (int ks = 0; ks < 4; ks++)
      af[ks] = *(const short8*)&s_obs[cn*136 + ks*32 + q*8];
    #pragma unroll
    for (int nt = 0; nt < 4; nt++){
      const int n0 = (w*4 + nt) * 16;
      f32x4 a = {0.f,0.f,0.f,0.f};
      #pragma unroll
      for (int ks = 0; ks < 4; ks++){
        short8 bf = *(const short8*)&w1b[(size_t)(n0 + cn)*128 + ks*32 + q*8];
        a = MFMA(af[ks], bf, a);
      }
      float bv = b1[n0 + cn];
      #pragma unroll
      for (int r = 0; r < 4; r++) a[r] += bv;
      acc[nt] = a;
    }
    #pragma unroll
    for (int r = 0; r < 4; r++){
      float s = 0.f, s2 = 0.f;
      #pragma unroll
      for (int nt = 0; nt < 4; nt++){ float v = acc[nt][r]; s += v; s2 = fmaf(v, v, s2); }
      s += __shfl_xor(s, 1, 64); s2 += __shfl_xor(s2, 1, 64);
      s += __shfl_xor(s, 2, 64); s2 += __shfl_xor(s2, 2, 64);
      s += __shfl_xor(s, 4, 64); s2 += __shfl_xor(s2, 4, 64);
      s += __shfl_xor(s, 8, 64); s2 += __shfl_xor(s2, 8, 64);
      if (cn == 0) s_st[(q*4 + r)*4 + w] = make_float2(s, s2);
    }
  }
  __syncthreads();   // s_obs dead

  // -- P3: normalize(256) + silu -> s_e1 --
  {
    float mu[4], rs[4];
    #pragma unroll
    for (int r = 0; r < 4; r++){
      const int row = q*4 + r;
      float2 p0 = s_st[row*4+0], p1 = s_st[row*4+1];
      float2 p2 = s_st[row*4+2], p3 = s_st[row*4+3];
      float s = p0.x+p1.x+p2.x+p3.x, s2 = p0.y+p1.y+p2.y+p3.y;
      float m = s * (1.f/256.f);
      mu[r] = m;
      rs[r] = rsqrtf(s2 * (1.f/256.f) - m*m + 1e-5f);
    }
    #pragma unroll
    for (int nt = 0; nt < 4; nt++){
      const int col = (w*4 + nt)*16 + cn;
      float gg = g1[col], bbv = bb1[col];
      #pragma unroll
      for (int r = 0; r < 4; r++){
        float v = (acc[nt][r] - mu[r]) * rs[r] * gg + bbv;
        s_e1[(q*4 + r)*264 + col] = f2bf(silu_f(v));
      }
    }
  }
  __syncthreads();

  // -- P4: GEMM2 (K=256, N=128, 2 tiles/wave) -> acc2; stats --
  f32x4 acc2[2];
  {
    short8 af2[8];
    #pragma unroll
    for (int ks = 0; ks < 8; ks++)
      af2[ks] = *(const short8*)&s_e1[cn*264 + ks*32 + q*8];
    #pragma unroll
    for (int nt = 0; nt < 2; nt++){
      const int n0 = (w*2 + nt) * 16;
      f32x4 a = {0.f,0.f,0.f,0.f};
      #pragma unroll
      for (int ks = 0; ks < 8; ks++){
        short8 bf = *(const short8*)&w2b[(size_t)(n0 + cn)*256 + ks*32 + q*8];
        a = MFMA(af2[ks], bf, a);
      }
      float bv = b2[n0 + cn];
      #pragma unroll
      for (int r = 0; r < 4; r++) a[r] += bv;
      acc2[nt] = a;
    }
    #pragma unroll
    for (int r = 0; r < 4; r++){
      float s = 0.f, s2 = 0.f;
      #pragma unroll
      for (int nt = 0; nt < 2; nt++){ float v = acc2[nt][r]; s += v; s2 = fmaf(v, v, s2); }
      s += __shfl_xor(s, 1, 64); s2 += __shfl_xor(s2, 1, 64);
      s += __shfl_xor(s, 2, 64); s2 += __shfl_xor(s2, 2, 64);
      s += __shfl_xor(s, 4, 64); s2 += __shfl_xor(s2, 4, 64);
      s += __shfl_xor(s, 8, 64); s2 += __shfl_xor(s2, 8, 64);
      if (cn == 0) s_st[(q*4 + r)*4 + w] = make_float2(s, s2);
    }
  }
  __syncthreads();

  // -- P5: normalize(g2/bb2) -> s_a2 cols [0,128) --
  {
    float mu[4], rs[4];
    #pragma unroll
    for (int r = 0; r < 4; r++){
      const int row = q*4 + r;
      float2 p0 = s_st[row*4+0], p1 = s_st[row*4+1];
      float2 p2 = s_st[row*4+2], p3 = s_st[row*4+3];
      float s = p0.x+p1.x+p2.x+p3.x, s2 = p0.y+p1.y+p2.y+p3.y;
      float m = s * (1.f/128.f);
      mu[r] = m;
      rs[r] = rsqrtf(s2 * (1.f/128.f) - m*m + 1e-5f);
    }
    #pragma unroll
    for (int nt = 0; nt < 2; nt++){
      const int col = (w*2 + nt)*16 + cn;
      float gg = g2[col], bbv = bb2[col];
      #pragma unroll
      for (int r = 0; r < 4; r++){
        float v = (acc2[nt][r] - mu[r]) * rs[r] * gg + bbv;
        s_a2[(q*4 + r)*168 + col] = f2bf(v);
      }
    }
  }
  __syncthreads();

  // -- P6: proj GEMM (K=160) -> acc3; stats --
  f32x4 acc3[2];
  {
    short8 af3[5];
    #pragma unroll
    for (int ks = 0; ks < 5; ks++)
      af3[ks] = *(const short8*)&s_a2[cn*168 + ks*32 + q*8];
    #pragma unroll
    for (int nt = 0; nt < 2; nt++){
      const int n0 = (w*2 + nt) * 16;
      f32x4 a = {0.f,0.f,0.f,0.f};
      #pragma unroll
      for (int ks = 0; ks < 5; ks++){
        short8 bf = *(const short8*)&pwb[(size_t)(n0 + cn)*160 + ks*32 + q*8];
        a = MFMA(af3[ks], bf, a);
      }
      float bv = pb[n0 + cn];
      #pragma unroll
      for (int r = 0; r < 4; r++) a[r] += bv;
      acc3[nt] = a;
    }
    #pragma unroll
    for (int r = 0; r < 4; r++){
      float s = 0.f, s2 = 0.f;
      #pragma unroll
      for (int nt = 0; nt < 2; nt++){ float v = acc3[nt][r]; s += v; s2 = fmaf(v, v, s2); }
      s += __shfl_xor(s, 1, 64); s2 += __shfl_xor(s2, 1, 64);
      s += __shfl_xor(s, 2, 64); s2 += __shfl_xor(s2, 2, 64);
      s += __shfl_xor(s, 4, 64); s2 += __shfl_xor(s2, 4, 64);
      s += __shfl_xor(s, 8, 64); s2 += __shfl_xor(s2, 8, 64);
      if (cn == 0) s_st[(q*4 + r)*4 + w] = make_float2(s, s2);
    }
  }
  __syncthreads();

  // -- P7: normalize(pg/pbb)+silu -> acc3 + X; stats2 --
  {
    float mu[4], rs[4];
    #pragma unroll
    for (int r = 0; r < 4; r++){
      const int row = q*4 + r;
      float2 p0 = s_st[row*4+0], p1 = s_st[row*4+1];
      float2 p2 = s_st[row*4+2], p3 = s_st[row*4+3];
      float s = p0.x+p1.x+p2.x+p3.x, s2 = p0.y+p1.y+p2.y+p3.y;
      float m = s * (1.f/128.f);
      mu[r] = m;
      rs[r] = rsqrtf(s2 * (1.f/128.f) - m*m + 1e-5f);
    }
    float ps[4] = {0.f,0.f,0.f,0.f}, ps2[4] = {0.f,0.f,0.f,0.f};
    #pragma unroll
    for (int nt = 0; nt < 2; nt++){
      const int col = (w*2 + nt)*16 + cn;
      float gg = pg[col], bbv = pbb[col];
      #pragma unroll
      for (int r = 0; r < 4; r++){
        float v = (acc3[nt][r] - mu[r]) * rs[r] * gg + bbv;
        v = silu_f(v);
        acc3[nt][r] = v;
        X[(size_t)(tok0 + q*4 + r)*128 + col] = v;
        ps[r] += v; ps2[r] = fmaf(v, v, ps2[r]);
      }
    }
    #pragma unroll
    for (int r = 0; r < 4; r++){
      float s = ps[r], s2 = ps2[r];
      s += __shfl_xor(s, 1, 64); s2 += __shfl_xor(s2, 1, 64);
      s += __shfl_xor(s, 2, 64); s2 += __shfl_xor(s2, 2, 64);
      s += __shfl_xor(s, 4, 64); s2 += __shfl_xor(s2, 4, 64);
      s += __shfl_xor(s, 8, 64); s2 += __shfl_xor(s2, 8, 64);
      if (cn == 0) s_st2[(q*4 + r)*4 + w] = make_float2(s, s2);
    }
  }
  __syncthreads();

  // -- P8: mamba LN (lng/lnb) -> s_a2 cols [0,128) --
  {
    float mu[4], rs[4];
    #pragma unroll
    for (int r = 0; r < 4; r++){
      const int row = q*4 + r;
      float2 p0 = s_st2[row*4+0], p1 = s_st2[row*4+1];
      float2 p2 = s_st2[row*4+2], p3 = s_st2[row*4+3];
      float s = p0.x+p1.x+p2.x+p3.x, s2 = p0.y+p1.y+p2.y+p3.y;
      float m = s * (1.f/128.f);
      mu[r] = m;
      rs[r] = rsqrtf(s2 * (1.f/128.f) - m*m + 1e-5f);
    }
    #pragma unroll
    for (int nt = 0; nt < 2; nt++){
      const int col = (w*2 + nt)*16 + cn;
      float gg = lng[col], bbv = lnb[col];
      #pragma unroll
      for (int r = 0; r < 4; r++){
        float v = (acc3[nt][r] - mu[r]) * rs[r] * gg + bbv;
        s_a2[(q*4 + r)*168 + col] = f2bf(v);
      }
    }
  }
  __syncthreads();

  // -- P9: wig GEMM (N=256, 4 tiles/wave) --
  {
    short8 af[4];
    #pragma unroll
    for (int ks = 0; ks < 4; ks++)
      af[ks] = *(const short8*)&s_a2[cn*168 + ks*32 + q*8];
    #pragma unroll
    for (int i = 0; i < 4; i++){
      const int n0 = (w*4 + i) * 16;
      f32x4 a = {0.f,0.f,0.f,0.f};
      #pragma unroll
      for (int ks = 0; ks < 4; ks++){
        short8 bf = *(const short8*)&wigb[(size_t)(n0 + cn)*128 + ks*32 + q*8];
        a = MFMA(af[ks], bf, a);
      }
      if (n0 < 128){
        #pragma unroll
        for (int r = 0; r < 4; r++){
          int tr = q*4 + r;
          ushort_t bb = f2bf(a[r]);
          XINb[(size_t)(tok0 + tr)*128 + n0 + cn] = bb;
          s_xin[tr*136 + n0 + cn] = bb;
        }
      } else {
        #pragma unroll
        for (int r = 0; r < 4; r++){
          int tr = q*4 + r;
          Zb[(size_t)(tok0 + tr)*128 + (n0 - 128) + cn] = f2bf(a[r]);
        }
      }
    }
  }
  __syncthreads();

  // -- P10: wdbc GEMM (N=144, nt=w..9 step 4) --
  {
    short8 af2[4];
    #pragma unroll
    for (int ks = 0; ks < 4; ks++)
      af2[ks] = *(const short8*)&s_xin[cn*136 + ks*32 + q*8];
    for (int nt = w; nt < 9; nt += 4){
      const int n0 = nt * 16;
      f32x4 a = {0.f,0.f,0.f,0.f};
      #pragma unroll
      for (int ks = 0; ks < 4; ks++){
        short8 bf = *(const short8*)&wdbcb[(size_t)(n0 + cn)*128 + ks*32 + q*8];
        a = MFMA(af2[ks], bf, a);
      }
      const int col = n0 + cn;
      if (col < 128){
        float bd = bdt[col];
        #pragma unroll
        for (int r = 0; r < 4; r++){
          int tr = q*4 + r;
          ushort_t dv = f2bf(softplus_f(a[r] + bd));
          DTb[(size_t)(tok0 + tr)*128 + col] = dv;
          s_dt[tr*136 + col] = dv;
        }
      } else if (col < 136){
        #pragma unroll
        for (int r = 0; r < 4; r++){
          int tr = q*4 + r;
          ushort_t bb = f2bf(a[r]);
          BTu[(size_t)(tok0 + tr)*8 + (col - 128)] = bb;
          s_btc[tr*8 + (col - 128)] = bb;
        }
      } else {
        #pragma unroll
        for (int r = 0; r < 4; r++)
          CTu[(size_t)(tok0 + q*4 + r)*8 + (col - 136)] = f2bf(a[r]);
      }
    }
  }
  __syncthreads();

  // -- P11: phase A (layer 0): thread=(d, s-half), 4 states, 16 tokens --
  {
    const int d = tid & 127, sh = tid >> 7;
    float A2c[4], hh[4], pp[4];
    #pragma unroll
    for (int j = 0; j < 4; j++){
      A2c[j] = -__expf(alog0[d*8 + sh*4 + j]) * LOG2E;
      hh[j] = 0.f; pp[j] = 1.f;
    }
    #pragma unroll 4
    for (int t = 0; t < 16; t++){
      float dt = b2f(s_dt[t*136 + d]);
      float wv = dt * b2f(s_xin[t*136 + d]);
      #pragma unroll
      for (int j = 0; j < 4; j++){
        float dA = exp2f(dt * A2c[j]);
        hh[j] = fmaf(dA, hh[j], wv * b2f(s_btc[t*8 + sh*4 + j]));
        pp[j] *= dA;
      }
    }
    const size_t o = ((size_t)bidx*SSEG + ch)*1024 + d*8 + sh*4;
    #pragma unroll
    for (int j = 0; j < 4; j++){ HLOC[o+j] = hh[j]; PPR[o+j] = pp[j]; }
  }
}

// ---- k_carry: HL[b,ch] := exclusive prefix (in place); prefetch-all then chain ----
__global__ __launch_bounds__(256) void k_carry(
    float* __restrict__ HL, const float* __restrict__ PP,
    const float* __restrict__ h0g)
{
  const int idx = blockIdx.x*256 + threadIdx.x;
  const size_t base = (size_t)(idx >> 10) * (SSEG*1024) + (idx & 1023);
  float hl[SSEG], pp[SSEG];
  #pragma unroll
  for (int ch = 0; ch < SSEG; ch++){
    hl[ch] = HL[base + (size_t)ch*1024];
    pp[ch] = PP[base + (size_t)ch*1024];
  }
  float h = h0g[idx];
  #pragma unroll
  for (int ch = 0; ch < SSEG; ch++){
    HL[base + (size_t)ch*1024] = h;
    h = fmaf(pp[ch], h, hl[ch]);
  }
}

// ======== phase B over 16 tokens: scan(+z/silu/D inline) + wout + residual + LN stats ====
// LDS (bytes):
//  [0,4096) s_dtS ; [4096,8192) s_xiS ; [8192,12288) s_zS   [dead after scan]
//  [0,8320)      s_x f32 16x130 (wout out; aliases staging)
//  [0,4352)      s_xin bf16 (wig out, late) ; [4352,8704) s_dt2 (wdbc out, late)
//  [12288,16640) s_a bf16 16x136
//  [16640,16896) s_bt ; [16896,17152) s_ct  (s_btc reuses s_bt late)
//  [17152,17664) s_st float2[16][4]
#define SMB 17664

__device__ __forceinline__ void phaseB16(
    const ushort_t* DTb, const ushort_t* XINb, const ushort_t* Zb,
    const ushort_t* BTu, const ushort_t* CTu,
    const float* __restrict__ alog, const float* __restrict__ HLpre,
    const float* __restrict__ dpar, const ushort_t* __restrict__ woutb,
    float* __restrict__ X, char* sm, int b, int seg, int tid)
{
  ushort_t* s_dtS = (ushort_t*)sm;
  ushort_t* s_xiS = (ushort_t*)(sm + 4096);
  ushort_t* s_zS  = (ushort_t*)(sm + 8192);
  float*    s_x   = (float*)sm;
  ushort_t* s_a   = (ushort_t*)(sm + 12288);
  ushort_t* s_bt  = (ushort_t*)(sm + 16640);
  ushort_t* s_ct  = (ushort_t*)(sm + 16896);
  float2*   s_st  = (float2*)(sm + 17152);

  const int lane = tid & 63, w = tid >> 6, q = lane >> 4, cn = lane & 15;
  const size_t segtok = (size_t)b*TT + seg*TSEG;

  // stage dt/xin/z (16x128 bf16 each = 256 uint4) + bt/ct
  ((uint4*)s_dtS)[tid] = ((const uint4*)(DTb  + segtok*128))[tid];
  ((uint4*)s_xiS)[tid] = ((const uint4*)(XINb + segtok*128))[tid];
  ((uint4*)s_zS )[tid] = ((const uint4*)(Zb   + segtok*128))[tid];
  if (tid < 64){
    ((unsigned*)s_bt)[tid] = ((const unsigned*)(BTu + segtok*8))[tid];
    ((unsigned*)s_ct)[tid] = ((const unsigned*)(CTu + segtok*8))[tid];
  }
  float A2[8], h[8], dp = 0.f;
  if (tid < 128){
    const int d = tid;
    const size_t o = ((size_t)b*SSEG + seg)*1024 + d*8;
    float4 h0v = *(const float4*)(HLpre + o);
    float4 h1v = *(const float4*)(HLpre + o + 4);
    h[0]=h0v.x; h[1]=h0v.y; h[2]=h0v.z; h[3]=h0v.w;
    h[4]=h1v.x; h[5]=h1v.y; h[6]=h1v.z; h[7]=h1v.w;
    dp = dpar[d];
    #pragma unroll
    for (int s = 0; s < 8; s++) A2[s] = -__expf(alog[d*8 + s]) * LOG2E;
  }
  __syncthreads();

  // scan with inline z-gate + D-skip: threads 0..127 (=d), 16 tokens
  if (tid < 128){
    const int d = tid;
    #pragma unroll 4
    for (int t = 0; t < 16; t++){
      float dt = b2f(s_dtS[t*128 + d]);
      float xi = b2f(s_xiS[t*128 + d]);
      float zv = b2f(s_zS [t*128 + d]);
      float wv = dt * xi;
      float y = 0.f;
      #pragma unroll
      for (int s = 0; s < 8; s++){
        float dA = exp2f(dt * A2[s]);
        h[s] = fmaf(dA, h[s], wv * b2f(s_bt[t*8 + s]));
        y = fmaf(h[s], b2f(s_ct[t*8 + s]), y);
      }
      float ssm = y * silu_f(zv) + xi * dp;
      s_a[t*136 + d] = f2bf(ssm);
    }
  }
  __syncthreads();   // staging dead; s_x writable

  // wout GEMM (N=128, 2 tiles/wave) + residual -> s_x + X; in-reg LN stats
  {
    short8 af[4];
    #pragma unroll
    for (int ks = 0; ks < 4; ks++)
      af[ks] = *(const short8*)&s_a[cn*136 + ks*32 + q*8];
    float ps[4] = {0.f,0.f,0.f,0.f}, ps2[4] = {0.f,0.f,0.f,0.f};
    #pragma unroll
    for (int i = 0; i < 2; i++){
      const int n0 = (w*2 + i) * 16;
      short8 bf[4];
      #pragma unroll
      for (int ks = 0; ks < 4; ks++)
        bf[ks] = *(const short8*)&woutb[(size_t)(n0+cn)*128 + ks*32 + q*8];
      f32x4 acc = {0.f,0.f,0.f,0.f};
      #pragma unroll
      for (int ks = 0; ks < 4; ks++) acc = MFMA(af[ks], bf[ks], acc);
      #pragma unroll
      for (int r = 0; r < 4; r++){
        const int tr = q*4 + r;
        const size_t g = (segtok + tr)*128 + n0 + cn;
        float xn = X[g] + acc[r];
        X[g] = xn;
        s_x[tr*130 + n0 + cn] = xn;
        ps[r] += xn; ps2[r] = fmaf(xn, xn, ps2[r]);
      }
    }
    #pragma unroll
    for (int r = 0; r < 4; r++){
      float s = ps[r], s2 = ps2[r];
      s += __shfl_xor(s, 1, 64); s2 += __shfl_xor(s2, 1, 64);
      s += __shfl_xor(s, 2, 64); s2 += __shfl_xor(s2, 2, 64);
      s += __shfl_xor(s, 4, 64); s2 += __shfl_xor(s2, 4, 64);
      s += __shfl_xor(s, 8, 64); s2 += __shfl_xor(s2, 8, 64);
      if (cn == 0) s_st[(q*4 + r)*4 + w] = make_float2(s, s2);
    }
  }
  __syncthreads();
}

// ---- k_scan2p: 16-token block; phaseB, LN, wig, wdbc, phaseA(next) ----
__global__ __launch_bounds__(256, 6) void k_scan2p(
    ushort_t* DTb, ushort_t* XINb, ushort_t* Zb,
    ushort_t* BTu, ushort_t* CTu,
    const float* __restrict__ alog, const float* __restrict__ HLpre,
    const float* __restrict__ dpar, const ushort_t* __restrict__ woutb,
    float* __restrict__ X,
    const float* __restrict__ lng, const float* __restrict__ lnb,
    const ushort_t* __restrict__ wigb, const ushort_t* __restrict__ wdbcb,
    const float* __restrict__ bdt,
    const float* __restrict__ alogn,
    float* __restrict__ HLo, float* __restrict__ PPo)
{
  __shared__ __align__(16) char sm[SMB];
  const int tid = threadIdx.x;
  float*    s_x   = (float*)sm;
  ushort_t* s_xin = (ushort_t*)sm;
  ushort_t* s_dt2 = (ushort_t*)(sm + 4352);
  ushort_t* s_a   = (ushort_t*)(sm + 12288);
  ushort_t* s_btc = (ushort_t*)(sm + 16640);
  float2*   s_st  = (float2*)(sm + 17152);

  const int b = blockIdx.x >> 5;
  const int seg = blockIdx.x & 31;
  const int lane = tid & 63, w = tid >> 6, q = lane >> 4, cn = lane & 15;
  const size_t segtok = (size_t)b*TT + seg*TSEG;

  phaseB16(DTb, XINb, Zb, BTu, CTu, alog, HLpre, dpar, woutb, X, sm, b, seg, tid);

  // P4: normalize (lng/lnb) -> s_a
  {
    const int d = tid & 127, half = tid >> 7;
    float g = lng[d], c0v = lnb[d];
    #pragma unroll
    for (int tt = 0; tt < 8; tt++){
      const int t = half*8 + tt;
      float2 p0 = s_st[t*4+0], p1 = s_st[t*4+1];
      float2 p2 = s_st[t*4+2], p3 = s_st[t*4+3];
      float ssum = p0.x+p1.x+p2.x+p3.x, ss2 = p0.y+p1.y+p2.y+p3.y;
      float mu = ssum * (1.f/128.f);
      float rs = rsqrtf(ss2 * (1.f/128.f) - mu*mu + 1e-5f);
      float v = (s_x[t*130 + d] - mu) * rs * g + c0v;
      s_a[t*136 + d] = f2bf(v);
    }
  }
  __syncthreads();

  // P5: wig GEMM (N=256, 4 tiles/wave); writes s_xin (aliases dead s_x) + XINb/Zb
  {
    short8 af[4];
    #pragma unroll
    for (int ks = 0; ks < 4; ks++)
      af[ks] = *(const short8*)&s_a[cn*136 + ks*32 + q*8];
    #pragma unroll
    for (int i = 0; i < 4; i++){
      const int n0 = (w*4 + i) * 16;
      short8 bf[4];
      #pragma unroll
      for (int ks = 0; ks < 4; ks++)
        bf[ks] = *(const short8*)&wigb[(size_t)(n0+cn)*128 + ks*32 + q*8];
      f32x4 acc = {0.f,0.f,0.f,0.f};
      #pragma unroll
      for (int ks = 0; ks < 4; ks++) acc = MFMA(af[ks], bf[ks], acc);
      if (n0 < 128){
        #pragma unroll
        for (int r = 0; r < 4; r++){
          const int tr = q*4 + r;
          ushort_t bb = f2bf(acc[r]);
          XINb[(segtok + tr)*128 + n0 + cn] = bb;
          s_xin[tr*136 + n0 + cn] = bb;
        }
      } else {
        #pragma unroll
        for (int r = 0; r < 4; r++){
          const int tr = q*4 + r;
          Zb[(segtok + tr)*128 + (n0-128) + cn] = f2bf(acc[r]);
        }
      }
    }
  }
  __syncthreads();

  // P6: wdbc GEMM; fills s_dt2 / s_btc
  {
    short8 af2[4];
    #pragma unroll
    for (int ks = 0; ks < 4; ks++)
      af2[ks] = *(const short8*)&s_xin[cn*136 + ks*32 + q*8];
    for (int nt = w; nt < 9; nt += 4){
      const int n0 = nt * 16;
      short8 bf[4];
      #pragma unroll
      for (int ks = 0; ks < 4; ks++)
        bf[ks] = *(const short8*)&wdbcb[(size_t)(n0+cn)*128 + ks*32 + q*8];
      f32x4 acc = {0.f,0.f,0.f,0.f};
      #pragma unroll
      for (int ks = 0; ks < 4; ks++) acc = MFMA(af2[ks], bf[ks], acc);
      const int col = n0 + cn;
      if (col < 128){
        float bd = bdt[col];
        #pragma unroll
        for (int r = 0; r < 4; r++){
          const int tr = q*4 + r;
          ushort_t dv = f2bf(softplus_f(acc[r] + bd));
          DTb[(segtok + tr)*128 + col] = dv;
          s_dt2[tr*136 + col] = dv;
        }
      } else if (col < 136){
        #pragma unroll
        for (int r = 0; r < 4; r++){
          const int tr = q*4 + r;
          ushort_t bb = f2bf(acc[r]);
          BTu[(segtok + tr)*8 + (col-128)] = bb;
          s_btc[tr*8 + (col-128)] = bb;
        }
      } else {
        #pragma unroll
        for (int r = 0; r < 4; r++)
          CTu[(segtok + q*4 + r)*8 + (col-136)] = f2bf(acc[r]);
      }
    }
  }
  __syncthreads();

  // P7: phase A (next layer): thread=(d, s-half), 4 states, 16 tokens
  {
    const int d = tid & 127, sh = tid >> 7;
    float A2n[4], hh[4], pp[4];
    #pragma unroll
    for (int j = 0; j < 4; j++){
      A2n[j] = -__expf(alogn[d*8 + sh*4 + j]) * LOG2E;
      hh[j] = 0.f; pp[j] = 1.f;
    }
    #pragma unroll 4
    for (int t = 0; t < 16; t++){
      float dt = b2f(s_dt2[t*136 + d]);
      float wv = dt * b2f(s_xin[t*136 + d]);
      #pragma unroll
      for (int j = 0; j < 4; j++){
        float dA = exp2f(dt * A2n[j]);
        hh[j] = fmaf(dA, hh[j], wv * b2f(s_btc[t*8 + sh*4 + j]));
        pp[j] *= dA;
      }
    }
    const size_t o = ((size_t)b*SSEG + seg)*1024 + d*8 + sh*4;
    #pragma unroll
    for (int j = 0; j < 4; j++){ HLo[o+j] = hh[j]; PPo[o+j] = pp[j]; }
  }
}

// ---- k_scan2h: 16-token block; phaseB, LNfn, pw1(+stats), LN+silu, pw2 ----
__global__ __launch_bounds__(256, 6) void k_scan2h(
    const ushort_t* DTb, const ushort_t* XINb, const ushort_t* Zb,
    const ushort_t* BTu, const ushort_t* CTu,
    const float* __restrict__ alog, const float* __restrict__ HLpre,
    const float* __restrict__ dpar, const ushort_t* __restrict__ woutb,
    float* __restrict__ X,
    const float* __restrict__ fng, const float* __restrict__ fnb,
    const ushort_t* __restrict__ pw1b, const float* __restrict__ pb1,
    const float* __restrict__ pg, const float* __restrict__ pbb,
    const ushort_t* __restrict__ pw2b, const float* __restrict__ pb2,
    float* __restrict__ out)
{
  __shared__ __align__(16) char sm[SMB];
  const int tid = threadIdx.x;
  float*    s_x  = (float*)sm;
  ushort_t* s_a  = (ushort_t*)(sm + 12288);
  float2*   s_st = (float2*)(sm + 17152);

  const int b = blockIdx.x >> 5;
  const int seg = blockIdx.x & 31;
  const int lane = tid & 63, w = tid >> 6, q = lane >> 4, cn = lane & 15;
  const size_t segtok = (size_t)b*TT + seg*TSEG;

  phaseB16((ushort_t*)DTb, (ushort_t*)XINb, (ushort_t*)Zb,
           (ushort_t*)BTu, (ushort_t*)CTu, alog, HLpre,
           dpar, woutb, X, sm, b, seg, tid);

  // P4: LN_fn -> s_a
  {
    const int d = tid & 127, half = tid >> 7;
    float g = fng[d], c0v = fnb[d];
    #pragma unroll
    for (int tt = 0; tt < 8; tt++){
      const int t = half*8 + tt;
      float2 p0 = s_st[t*4+0], p1 = s_st[t*4+1];
      float2 p2 = s_st[t*4+2], p3 = s_st[t*4+3];
      float ssum = p0.x+p1.x+p2.x+p3.x, ss2 = p0.y+p1.y+p2.y+p3.y;
      float mu = ssum * (1.f/128.f);
      float rs = rsqrtf(ss2 * (1.f/128.f) - mu*mu + 1e-5f);
      float v = (s_x[t*130 + d] - mu) * rs * g + c0v;
      s_a[t*136 + d] = f2bf(v);
    }
  }
  __syncthreads();

  // P5: pw1 GEMM (N=128, 2 tiles/wave) -> s_x (+bias); in-reg stats
  {
    short8 af[4];
    #pragma unroll
    for (int ks = 0; ks < 4; ks++)
      af[ks] = *(const short8*)&s_a[cn*136 + ks*32 + q*8];
    float ps[4] = {0.f,0.f,0.f,0.f}, ps2[4] = {0.f,0.f,0.f,0.f};
    #pragma unroll
    for (int i = 0; i < 2; i++){
      const int n0 = (w*2 + i) * 16;
      short8 bf[4];
      #pragma unroll
      for (int ks = 0; ks < 4; ks++)
        bf[ks] = *(const short8*)&pw1b[(size_t)(n0+cn)*128 + ks*32 + q*8];
      float bias = pb1[n0 + cn];
      f32x4 acc = {0.f,0.f,0.f,0.f};
      #pragma unroll
      for (int ks = 0; ks < 4; ks++) acc = MFMA(af[ks], bf[ks], acc);
      #pragma unroll
      for (int r = 0; r < 4; r++){
        float xv = acc[r] + bias;
        s_x[(q*4 + r)*130 + n0 + cn] = xv;
        ps[r] += xv; ps2[r] = fmaf(xv, xv, ps2[r]);
      }
    }
    #pragma unroll
    for (int r = 0; r < 4; r++){
      float s = ps[r], s2 = ps2[r];
      s += __shfl_xor(s, 1, 64); s2 += __shfl_xor(s2, 1, 64);
      s += __shfl_xor(s, 2, 64); s2 += __shfl_xor(s2, 2, 64);
      s += __shfl_xor(s, 4, 64); s2 += __shfl_xor(s2, 4, 64);
      s += __shfl_xor(s, 8, 64); s2 += __shfl_xor(s2, 8, 64);
      if (cn == 0) s_st[(q*4 + r)*4 + w] = make_float2(s, s2);
    }
  }
  __syncthreads();

  // P6: LN(pg/pbb)+silu -> s_a
  {
    const int d = tid & 127, half = tid >> 7;
    float g = pg[d], c0v = pbb[d];
    #pragma unroll
    for (int tt = 0; tt < 8; tt++){
      const int t = half*8 + tt;
      float2 p0 = s_st[t*4+0], p1 = s_st[t*4+1];
      float2 p2 = s_st[t*4+2], p3 = s_st[t*4+3];
      float ssum = p0.x+p1.x+p2.x+p3.x, ss2 = p0.y+p1.y+p2.y+p3.y;
      float mu = ssum * (1.f/128.f);
      float rs = rsqrtf(ss2 * (1.f/128.f) - mu*mu + 1e-5f);
      float v = (s_x[t*130 + d] - mu) * rs * g + c0v;
      s_a[t*136 + d] = f2bf(silu_f(v));
    }
  }
  __syncthreads();

  // P7: pw2 GEMM (N=32; waves 0,1; cols<19 stored)
  if (w < 2){
    short8 af[4];
    #pragma unroll
    for (int ks = 0; ks < 4; ks++)
      af[ks] = *(const short8*)&s_a[cn*136 + ks*32 + q*8];
    const int n0 = w * 16;
    short8 bf[4];
    #pragma unroll
    for (int ks = 0; ks < 4; ks++)
      bf[ks] = *(const short8*)&pw2b[(size_t)(n0+cn)*128 + ks*32 + q*8];
    const int col = n0 + cn;
    f32x4 acc = {0.f,0.f,0.f,0.f};
    #pragma unroll
    for (int ks = 0; ks < 4; ks++) acc = MFMA(af[ks], bf[ks], acc);
    if (col < NAD){
      float bias = pb2[col];
      #pragma unroll
      for (int r = 0; r < 4; r++)
        out[(segtok + q*4 + r)*NAD + col] = acc[r] + bias;
    }
  }
}

extern "C" void kernel_launch(void* const* d_in, const int* in_sizes, int n_in,
                              void* d_out, int out_size, void* d_ws, size_t ws_size,
                              hipStream_t stream) {
  const float* obs    = (const float*)d_in[0];
  const float* h0     = (const float*)d_in[1];
  const float* enc_w1 = (const float*)d_in[2];
  const float* enc_b1 = (const float*)d_in[3];
  const float* enc_g1 = (const float*)d_in[4];
  const float* enc_bb1= (const float*)d_in[5];
  const float* enc_w2 = (const float*)d_in[6];
  const float* enc_b2 = (const float*)d_in[7];
  const float* enc_g2 = (const float*)d_in[8];
  const float* enc_bb2= (const float*)d_in[9];
  const float* emb    = (const float*)d_in[10];
  const float* proj_w = (const float*)d_in[11];
  const float* proj_b = (const float*)d_in[12];
  const float* proj_g = (const float*)d_in[13];
  const float* proj_bb= (const float*)d_in[14];
  const float* m_ln_g = (const float*)d_in[15];
  const float* m_ln_b = (const float*)d_in[16];
  const float* m_w_ig = (const float*)d_in[17];
  const float* m_w_dt = (const float*)d_in[18];
  const float* m_b_dt = (const float*)d_in[19];
  const float* m_a_log= (const float*)d_in[20];
  const float* m_w_b  = (const float*)d_in[21];
  const float* m_w_c  = (const float*)d_in[22];
  const float* m_d    = (const float*)d_in[23];
  const float* m_w_out= (const float*)d_in[24];
  const float* fn_g   = (const float*)d_in[25];
  const float* fn_b   = (const float*)d_in[26];
  const float* pol_w1 = (const float*)d_in[27];
  const float* pol_b1 = (const float*)d_in[28];
  const float* pol_g  = (const float*)d_in[29];
  const float* pol_bb = (const float*)d_in[30];
  const float* pol_w2 = (const float*)d_in[31];
  const float* pol_b2 = (const float*)d_in[32];
  const int*   pact   = (const int*)d_in[33];

  float* ws  = (float*)d_ws;
  float* X    = ws;
  float* HLA  = X + (size_t)NTOK*128;
  float* PPA  = HLA + (size_t)BB*SSEG*1024;
  float* HLB  = PPA + (size_t)BB*SSEG*1024;
  float* PPB  = HLB + (size_t)BB*SSEG*1024;
  ushort_t* XINb = (ushort_t*)(PPB + (size_t)BB*SSEG*1024);
  ushort_t* Zb   = XINb + (size_t)NTOK*128;
  ushort_t* DTb  = Zb   + (size_t)NTOK*128;
  ushort_t* BTu  = DTb  + (size_t)NTOK*128;
  ushort_t* CTu  = BTu  + (size_t)NTOK*8;

  ushort_t* W1B   = CTu   + (size_t)NTOK*8;
  ushort_t* W2B   = W1B   + 256*128;
  ushort_t* PWB   = W2B   + 128*256;
  ushort_t* WIGB  = PWB   + 128*160;
  ushort_t* WDBCB = WIGB  + 3*256*128;
  ushort_t* WOUTB = WDBCB + 3*144*128;
  ushort_t* PW1B  = WOUTB + 3*128*128;
  ushort_t* PW2B  = PW1B  + 128*128;

  PJobs P;
  int nj = 0;
  auto add = [&](const float* src, ushort_t* dst, int N, int K, int Kpad, int rowofs, int Nw){
    P.j[nj].src = src; P.j[nj].dst = dst; P.j[nj].N = N; P.j[nj].K = K;
    P.j[nj].Kpad = Kpad; P.j[nj].rowofs = rowofs; P.j[nj].Nw = Nw; nj++;
  };
  add(enc_w1, W1B, 256, 115, 128, 0, 256);
  add(enc_w2, W2B, 128, 256, 256, 0, 128);
  add(proj_w, PWB, 128, 144, 160, 0, 128);
  for (int l = 0; l < NLD; l++)
    add(m_w_ig + (size_t)l*256*128, WIGB + (size_t)l*256*128, 256, 128, 128, 0, 256);
  for (int l = 0; l < NLD; l++){
    add(m_w_dt + (size_t)l*128*128, WDBCB + (size_t)l*144*128, 128, 128, 128, 0,   128);
    add(m_w_b  + (size_t)l*8*128,   WDBCB + (size_t)l*144*128,   8, 128, 128, 128,   8);
    add(m_w_c  + (size_t)l*8*128,   WDBCB + (size_t)l*144*128,   8, 128, 128, 136,   8);
  }
  for (int l = 0; l < NLD; l++)
    add(m_w_out + (size_t)l*128*128, WOUTB + (size_t)l*128*128, 128, 128, 128, 0, 128);
  add(pol_w1, PW1B, 128, 128, 128, 0, 128);
  add(pol_w2, PW2B,  19, 128, 128, 0,  32);

  k_prep<<<20*4, 256, 0, stream>>>(P);
  k_enc12p<<<NTOK/16, 256, 0, stream>>>(obs, W1B, enc_b1, enc_g1, enc_bb1,
      W2B, enc_b2, enc_g2, enc_bb2,
      emb, pact, PWB, proj_b, proj_g, proj_bb, X,
      m_ln_g, m_ln_b, WIGB, WDBCB, m_b_dt,
      XINb, Zb, DTb, BTu, CTu,
      m_a_log, HLA, PPA);

  const int carrygrid = BB*1024/256;   // 256 blocks
  const int scangrid  = NTOK/16;       // 2048 blocks x 256 thr

  // layer 0
  k_carry<<<carrygrid, 256, 0, stream>>>(HLA, PPA, h0);
  k_scan2p<<<scangrid, 256, 0, stream>>>(DTb, XINb, Zb, BTu, CTu,
      m_a_log, HLA, m_d, WOUTB, X,
      m_ln_g + 128, m_ln_b + 128,
      WIGB + (size_t)256*128, WDBCB + (size_t)144*128, m_b_dt + 128,
      m_a_log + 1024, HLB, PPB);
  // layer 1
  k_carry<<<carrygrid, 256, 0, stream>>>(HLB, PPB, h0 + (size_t)BB*1024);
  k_scan2p<<<scangrid, 256, 0, stream>>>(DTb, XINb, Zb, BTu, CTu,
      m_a_log + 1024, HLB, m_d + 128, WOUTB + (size_t)128*128, X,
      m_ln_g + 256, m_ln_b + 256,
      WIGB + (size_t)2*256*128, WDBCB + (size_t)2*144*128, m_b_dt + 256,
      m_a_log + 2048, HLA, PPA);
  // layer 2
  k_carry<<<carrygrid, 256, 0, stream>>>(HLA, PPA, h0 + (size_t)2*BB*1024);
  k_scan2h<<<scangrid, 256, 0, stream>>>(DTb, XINb, Zb, BTu, CTu,
      m_a_log + 2048, HLA, m_d + 256, WOUTB + (size_t)2*128*128, X,
      fn_g, fn_b, PW1B, pol_b1, pol_g, pol_bb, PW2B, pol_b2,
      (float*)d_out);
}